// Round 6
// baseline (48119.733 us; speedup 1.0000x reference)
//
#include <hip/hip_runtime.h>

#define T_    300
#define B_    16
#define S_    160
#define NMEL_ 80
#define PRE_  256
#define ENC_  512
#define ATT_  128
#define DIM_  1024

#define XST1  1288     // P1 tile stride (mel 256 + h0 1024 + pad 8); rows end at 20600
#define XST2  520      // P2 align tile stride (ends 8320)
#define XST3  1032     // P3 h0 tile stride (ends 16504)
#define WOFF  16512    // attn blocks: weff copy [16512..20608) — above P2/P3 staging reach
#define WLDS  20608    // compute blocks: pinned Wih1 rows, 16x1024 = 16384 floats
#define AOFF  36992    // attn blocks: persistent arrays (cum_p, projx, wscs)
#define XTOT  38848    // dynamic LDS floats (155.4 KB)
#define BARWORDS 17408

typedef unsigned int u32;

__device__ __forceinline__ float fexp2f(float x) { return __builtin_amdgcn_exp2f(x); }
__device__ __forceinline__ float fsigf(float x)  { return 1.0f / (1.0f + fexp2f(-1.442695041f * x)); }
__device__ __forceinline__ float ftanhf(float x) {
  float xc = fminf(fmaxf(x, -15.0f), 15.0f);
  float e = fexp2f(2.885390082f * xc);
  return (e - 1.0f) / (e + 1.0f);
}

// ---- system-scope (LLC) accessors. waitcnt lives INSIDE each asm block so the
// register allocator never sees a pending-load destination (R3 bug).
__device__ __forceinline__ float4 ld1q_sys(const float* p) {
  float4 v;
  asm volatile("global_load_dwordx4 %0, %1, off sc0 sc1\n\ts_waitcnt vmcnt(0)"
               : "=v"(v) : "v"(p) : "memory");
  return v;
}
__device__ __forceinline__ void ld4q_sys(const float* p0, const float* p1,
                                         const float* p2, const float* p3,
                                         float4& a, float4& b, float4& c, float4& d) {
  asm volatile(
      "global_load_dwordx4 %0, %4, off sc0 sc1\n\t"
      "global_load_dwordx4 %1, %5, off sc0 sc1\n\t"
      "global_load_dwordx4 %2, %6, off sc0 sc1\n\t"
      "global_load_dwordx4 %3, %7, off sc0 sc1\n\t"
      "s_waitcnt vmcnt(0)"
      : "=&v"(a), "=&v"(b), "=&v"(c), "=&v"(d)
      : "v"(p0), "v"(p1), "v"(p2), "v"(p3) : "memory");
}
__device__ __forceinline__ void ld8q_sys(const float* p0,const float* p1,const float* p2,const float* p3,
                                         const float* p4,const float* p5,const float* p6,const float* p7,
                                         float4& a,float4& b,float4& c,float4& d,
                                         float4& e,float4& f,float4& g,float4& h) {
  asm volatile(
      "global_load_dwordx4 %0, %8, off sc0 sc1\n\t"
      "global_load_dwordx4 %1, %9, off sc0 sc1\n\t"
      "global_load_dwordx4 %2, %10, off sc0 sc1\n\t"
      "global_load_dwordx4 %3, %11, off sc0 sc1\n\t"
      "global_load_dwordx4 %4, %12, off sc0 sc1\n\t"
      "global_load_dwordx4 %5, %13, off sc0 sc1\n\t"
      "global_load_dwordx4 %6, %14, off sc0 sc1\n\t"
      "global_load_dwordx4 %7, %15, off sc0 sc1\n\t"
      "s_waitcnt vmcnt(0)"
      : "=&v"(a),"=&v"(b),"=&v"(c),"=&v"(d),"=&v"(e),"=&v"(f),"=&v"(g),"=&v"(h)
      : "v"(p0),"v"(p1),"v"(p2),"v"(p3),"v"(p4),"v"(p5),"v"(p6),"v"(p7)
      : "memory");
}
__device__ __forceinline__ void st_sys(float* p, float v) {
  asm volatile("global_store_dword %0, %1, off sc0 sc1" :: "v"(p), "v"(v) : "memory");
}
__device__ __forceinline__ u32 ld_sys_u32(const u32* p) {
  u32 r;
  asm volatile("global_load_dword %0, %1, off sc0 sc1\n\ts_waitcnt vmcnt(0)"
               : "=v"(r) : "v"(p) : "memory");
  return r;
}
__device__ __forceinline__ void st_sys_u32(u32* p, u32 v) {
  asm volatile("global_store_dword %0, %1, off sc0 sc1" :: "v"(p), "v"(v) : "memory");
}

// ---- tree-arrival / flat-release barrier: 16 groups x 16 blocks for arrival
// (spreads atomic contention), single top release word everyone polls.
__device__ __forceinline__ void gridbar(u32* bar, int tid, int blk, u32 ep) {
  asm volatile("s_waitcnt vmcnt(0)" ::: "memory");   // drain this wave's sc stores
  __syncthreads();
  if (tid == 0) {
    const int g = blk & 15;
    u32* cnt  = bar + g*1024;
    u32* tcnt = bar + 16384;
    u32* trel = bar + 16384 + 64;
    const u32 tgt = ep*16u + 15u;
    u32 old = __hip_atomic_fetch_add(cnt, 1u, __ATOMIC_RELAXED, __HIP_MEMORY_SCOPE_AGENT);
    if (old == tgt) {
      u32 told = __hip_atomic_fetch_add(tcnt, 1u, __ATOMIC_RELAXED, __HIP_MEMORY_SCOPE_AGENT);
      if (told == tgt) {
        st_sys_u32(trel, ep + 1u);
      } else {
        while (ld_sys_u32(trel) != ep + 1u) __builtin_amdgcn_s_sleep(2);
      }
    } else {
      while (ld_sys_u32(trel) != ep + 1u) __builtin_amdgcn_s_sleep(2);
    }
  }
  __syncthreads();
}

// ---- wave-64 sum via DPP (VALU pipe, zero DS ops).
// row_shr scan within each 16-lane row -> row sums in lanes 15/31/47/63;
// row_bcast:15 (+rows 1,3) then row_bcast:31 (+row 3) -> total in lane 63.
#define DPP_ADD(v, ctrl, rmask) do { \
  int _t = __builtin_amdgcn_update_dpp(0, __float_as_int(v), (ctrl), (rmask), 0xf, false); \
  (v) += __int_as_float(_t); } while (0)

#define REDUCE64(v) do { \
  DPP_ADD(v, 0x111, 0xf); \
  DPP_ADD(v, 0x112, 0xf); \
  DPP_ADD(v, 0x114, 0xf); \
  DPP_ADD(v, 0x118, 0xf); \
  DPP_ADD(v, 0x142, 0xa); \
  DPP_ADD(v, 0x143, 0x8); } while (0)

// ---------------- prenet
__launch_bounds__(256)
__global__ void prenet_kernel(const float* __restrict__ mels,
                              const float* __restrict__ pW1, const float* __restrict__ pb1,
                              const float* __restrict__ pW2, const float* __restrict__ pb2,
                              float* __restrict__ melpre) {
  __shared__ float mcol[NMEL_];
  __shared__ float pcol[PRE_];
  const int b = blockIdx.x / 30;
  const int tbase = (blockIdx.x % 30) * 10;
  const int tid = threadIdx.x;
  for (int f = 0; f < 10; ++f) {
    const int t = tbase + f;
    if (tid < NMEL_) mcol[tid] = (t == 0) ? 0.0f : mels[(b*NMEL_ + tid)*T_ + (t-1)];
    __syncthreads();
    {
      float a1 = pb1[tid];
      const float* w1 = pW1 + tid*NMEL_;
      for (int m = 0; m < NMEL_; ++m) a1 += w1[m]*mcol[m];
      pcol[tid] = fmaxf(a1, 0.0f);
    }
    __syncthreads();
    {
      float a2 = pb2[tid];
      const float* w2 = pW2 + tid*PRE_;
      for (int d = 0; d < PRE_; d += 4) {
        const float4 wv = *(const float4*)(w2 + d);
        a2 += wv.x*pcol[d] + wv.y*pcol[d+1] + wv.z*pcol[d+2] + wv.w*pcol[d+3];
      }
      melpre[(t*B_ + b)*PRE_ + tid] = fmaxf(a2, 0.0f);
    }
    __syncthreads();
  }
}

// ---------------- init: h states, Weff, barrier region
__launch_bounds__(256)
__global__ void init_kernel(const float* __restrict__ h0,
                            const float* __restrict__ conv1, const float* __restrict__ conv2,
                            float* __restrict__ h1buf, float* __restrict__ h0st,
                            float* __restrict__ weff, u32* __restrict__ bar) {
  const int idx = blockIdx.x*256 + threadIdx.x;
  if (idx < B_*DIM_) {
    const int j = idx & (DIM_-1);
    h0st[idx]  = h0[j];
    h1buf[idx] = h0[DIM_ + j];
  } else if (idx < B_*DIM_ + ATT_*32) {
    const int r = idx - B_*DIM_;
    const int a = r >> 5, k = r & 31;
    float acc = 0.0f;
    if (k < 31) {
      for (int l = 0; l < 32; ++l) acc += conv2[a*32 + l]*conv1[l*31 + k];
    }
    weff[r] = acc;
  } else if (idx < B_*DIM_ + ATT_*32 + BARWORDS) {
    bar[idx - (B_*DIM_ + ATT_*32)] = 0u;
  }
}

// ---------------- l_enc
__launch_bounds__(256)
__global__ void lenc_kernel(const float* __restrict__ enc, const float* __restrict__ Wt,
                            float* __restrict__ lencb) {
  __shared__ float es[4*ENC_];
  const int b = blockIdx.x / 40;
  const int s0 = (blockIdx.x % 40) * 4;
  const int tid = threadIdx.x;
  for (int idx = tid; idx < 4*ENC_; idx += 256) es[idx] = enc[(b*S_ + s0)*ENC_ + idx];
  __syncthreads();
  const int a = tid & 127, sh = tid >> 7;
  const float* w = Wt + a*ENC_;
  for (int p = 0; p < 2; ++p) {
    const int sl = sh*2 + p;
    const float* e = es + sl*ENC_;
    float acc = 0.0f;
    for (int j = 0; j < ENC_; j += 4) {
      const float4 wv = *(const float4*)(w + j);
      acc += wv.x*e[j] + wv.y*e[j+1] + wv.z*e[j+2] + wv.w*e[j+3];
    }
    lencb[(b*S_ + s0 + sl)*ATT_ + a] = acc;
  }
}

// ---------------- persistent decoder
// block blk owns j-columns j0=blk*4 in P2/P3 (LSTM assembly + activation).
// P1: blk<16 attention + projection of step t-1; blk>=16: gates0-pre &
//     gates1-pre. P2: align part of gates0 + LSTM0 -> h0st.
// P3: Wih1@h0 + LSTM1 -> h1buf. Compute blocks read their Wih1 rows from an
//     LDS-pinned copy (loaded once; 64 KB); attn blocks stream Wih1.
// LDS overlays (per-block, role-dependent):
//   compute: x-tile [0..20608) | wP3 [20608..36992)
//   attn:    staging [0..16512) + P1-transient {q_s,spf,score_s,attn_s} at [0..1088)
//            | weff [16512..20608) | cum_p/projx/wscs [36992..38848)
// __launch_bounds__(512, 1): the (512,2) and bare (512) forms both capped the
// allocator at 128 VGPRs on this toolchain -> acc[5][8]+staging spilled to
// scratch every step (WRITE_SIZE ~8 GB/dispatch = spill stores). The ",1"
// form (1 block/CU; the 8-wave workgroup itself bounds allocation at 256)
// gives the 256-VGPR budget. Grid is 256 blocks on 256 CUs, so 1 block/CU
// costs nothing.
__launch_bounds__(512, 1)
__global__ void decoder_kernel(
    const float* __restrict__ melpre, const float* __restrict__ lencb,
    const float* __restrict__ weff,
    float* __restrict__ h1buf, float* __restrict__ albuf, float* __restrict__ h0st,
    float* __restrict__ g0pre, float* __restrict__ g1pre, u32* __restrict__ bar,
    const float* __restrict__ enc, const int* __restrict__ tlen,
    const float* __restrict__ Wq, const float* __restrict__ wsc,
    const float* __restrict__ Wih0, const float* __restrict__ Whh0,
    const float* __restrict__ bih0, const float* __restrict__ bhh0,
    const float* __restrict__ Wih1, const float* __restrict__ Whh1,
    const float* __restrict__ bih1, const float* __restrict__ bhh1,
    const float* __restrict__ c0in, const float* __restrict__ projW, const float* __restrict__ projb,
    float* __restrict__ out_mel, float* __restrict__ out_stop, float* __restrict__ out_attn)
{
  extern __shared__ float xt[];
  __shared__ float red_s[1];
  __shared__ float gv[256];    // P2/P3 GEMV reduction
  __shared__ float gv0[256];   // gates0 pre (own rows), persists P1->P2
  __shared__ float gv1[256];   // gates1 pre (own rows), persists P1->P3

  // attn-block overlays into dynamic LDS (compute blocks never touch these)
  float* const q_s     = xt;                 // [128]  P1 transient
  float* const spf     = xt + 128;           // [640]  P1 transient (scores, proj)
  float* const score_s = xt + 768;           // [160]  P1 transient
  float* const attn_s  = xt + 928;           // [160]  P1 transient
  float* const cum_p   = xt + AOFF;          // [190]  persistent
  float* const projx   = xt + AOFF + 192;    // [1536] persistent within step
  float* const wscs    = xt + AOFF + 1728;   // [128]  persistent

  const int blk = blockIdx.x;
  const int tid = threadIdx.x;
  const int ks = tid & 63;
  const int bgb = ((tid >> 6) & 1)*8;
  const int rg = tid >> 7;
  const int j0 = blk*4;

  // per-block persistent cell state in registers (lanes tid<64)
  float c0r = 0.0f, c1r = 0.0f;
  if (tid < 64) {
    const int j = j0 + (tid >> 4);
    c0r = c0in[j];
    c1r = c0in[DIM_ + j];
  }
  int mylen = 0;
  if (blk < B_) {
    mylen = tlen[blk];
    for (int i = tid; i < S_ + 30; i += 512) cum_p[i] = 0.0f;
    for (int i = tid; i < 4096; i += 512) xt[WOFF + i] = weff[i];
    if (tid < ATT_) wscs[tid] = wsc[tid];
  } else {
    // pin this block's Wih1 rows (16 rows x 1024 cols) into LDS, chunked so
    // lane ks reads chunk c at [c*256 + ks*4] conflict-free in P3.
    // chunk c = (ri*4 + rg)*4 + q, row = ri*1024 + j0 + rg, cols q*256..+255.
    for (int i = tid; i < 4096; i += 512) {
      const int c = i >> 6, l = i & 63;
      const int ri = c >> 4, rgw = (c >> 2) & 3, q = c & 3;
      *(float4*)(xt + WLDS + c*256 + l*4) =
          *(const float4*)(Wih1 + (ri*1024 + j0 + rgw)*1024 + q*256 + l*4);
    }
  }
  __syncthreads();

  u32 ep = 0;

  for (int t = 0; t < T_; ++t) {
    const int prev = t & 1;
    const int cur = prev ^ 1;

    //====================== P1 ======================
    if (blk < B_) {
      const int b = blk;
      // stage [h1prev | alignprev] into projx (used for q and proj below)
      if (tid < 256) {
        float4 v = ld1q_sys(h1buf + prev*B_*DIM_ + b*DIM_ + tid*4);
        *(float4*)(projx + tid*4) = v;
      } else if (tid < 384) {
        const int j = tid - 256;
        float4 v = ld1q_sys(albuf + prev*B_*ENC_ + b*ENC_ + j*4);
        *(float4*)(projx + 1024 + j*4) = v;
      }
      __syncthreads();
      // q = h1prev @ Wq^T
      {
        const int a = tid & 127, part = tid >> 7;
        const float* hp = projx + part*256;
        const float* wq = Wq + a*DIM_ + part*256;
        float acc = 0.0f;
        for (int j = 0; j < 256; j += 4) {
          const float4 wv = *(const float4*)(wq + j);
          const float4 hv = *(const float4*)(hp + j);
          acc += wv.x*hv.x + wv.y*hv.y + wv.z*hv.z + wv.w*hv.w;
        }
        spf[a*4 + part] = acc;
      }
      __syncthreads();
      if (tid < ATT_) q_s[tid] = spf[tid*4] + spf[tid*4+1] + spf[tid*4+2] + spf[tid*4+3];
      __syncthreads();
      // scores
      {
        const int sl = tid & 127, ag = tid >> 7;
        #pragma unroll
        for (int p = 0; p < 2; ++p) {
          const int s = sl + p*128;
          if (s < S_) {
            float cw[31];
            #pragma unroll
            for (int k = 0; k < 31; ++k) cw[k] = cum_p[s + k];
            const float* le = lencb + (b*S_ + s)*ATT_ + ag*32;
            float ps = 0.0f;
            for (int i = 0; i < 32; ++i) {
              const int a = ag*32 + i;
              const float* wk = xt + WOFF + a*32;
              float loc = 0.0f;
              #pragma unroll
              for (int k = 0; k < 31; ++k) loc += wk[k]*cw[k];
              ps += wscs[a]*ftanhf(q_s[a] + le[i] + loc);
            }
            spf[s*4 + ag] = ps;
          }
        }
      }
      __syncthreads();
      if (tid < S_) {
        float sc = spf[tid*4] + spf[tid*4+1] + spf[tid*4+2] + spf[tid*4+3];
        if (tid >= mylen) sc = -1.0e30f;
        score_s[tid] = sc;
      }
      __syncthreads();
      if (tid < 64) {
        float m = -1.0e30f;
        for (int i = tid; i < S_; i += 64) m = fmaxf(m, score_s[i]);
        #pragma unroll
        for (int o = 32; o > 0; o >>= 1) m = fmaxf(m, __shfl_xor(m, o, 64));
        float sum = 0.0f;
        for (int i = tid; i < S_; i += 64) {
          const float e = fexp2f(1.442695041f*(score_s[i] - m));
          score_s[i] = e;
          sum += e;
        }
        #pragma unroll
        for (int o = 32; o > 0; o >>= 1) sum += __shfl_xor(sum, o, 64);
        if (tid == 0) red_s[0] = sum;
      }
      __syncthreads();
      {
        const float inv = 1.0f / red_s[0];
        if (tid < S_) {
          const float av = score_s[tid]*inv;
          attn_s[tid] = av;
          cum_p[15 + tid] += av;
          out_attn[(b*S_ + tid)*T_ + t] = av;
        }
      }
      __syncthreads();
      // align = attn @ enc  -> albuf[cur] (sc)
      {
        const float* eb = enc + (b*S_)*ENC_ + tid;
        float acc = 0.0f;
        for (int s = 0; s < S_; ++s) acc += attn_s[s]*eb[s*ENC_];
        st_sys(albuf + cur*B_*ENC_ + b*ENC_ + tid, acc);
      }
      // projection of step t-1 (inputs are in projx).
      if (t > 0) {
        const int o = tid >> 2, part = tid & 3;
        if (o < 81) {
          const float* w = projW + o*1536;
          const int jb = part*384;
          float acc2 = 0.0f;
          for (int j = jb; j < jb + 384; j += 4) {
            const float4 wv = *(const float4*)(w + j);
            const float4 xv = *(const float4*)(projx + j);
            acc2 += wv.x*xv.x + wv.y*xv.y + wv.z*xv.z + wv.w*xv.w;
          }
          spf[o*4 + part] = acc2;
        }
        __syncthreads();
        if (tid < 81) {
          const float v = projb[tid] + spf[tid*4] + spf[tid*4+1] + spf[tid*4+2] + spf[tid*4+3];
          if (tid < 80) out_mel[(b*NMEL_ + tid)*T_ + (t-1)] = v;
          else          out_stop[b*T_ + (t-1)] = v;
        }
      }
    } else {
      const bool hg0 = (blk >= 16 && blk < 80);
      const bool hg1 = (blk >= 80 && blk < 144);
      const int jx0 = blk - 16;
      const int jx1 = blk - 80;
      // ---- stage [mel | h0prev] tile
      for (int i = tid; i < 1024; i += 512) {
        float4 v = *(const float4*)(melpre + t*4096 + i*4);
        *(float4*)(xt + (i>>6)*XST1 + (i&63)*4) = v;
      }
      {
        float4 r0,r1,r2,r3,r4,r5,r6,r7;
        ld8q_sys(h0st + tid*4, h0st + (tid+512)*4, h0st + (tid+1024)*4, h0st + (tid+1536)*4,
                 h0st + (tid+2048)*4, h0st + (tid+2560)*4, h0st + (tid+3072)*4, h0st + (tid+3584)*4,
                 r0,r1,r2,r3,r4,r5,r6,r7);
        *(float4*)(xt + ((tid       )>>8)*XST1 + 256 + ((tid       )&255)*4) = r0;
        *(float4*)(xt + ((tid + 512 )>>8)*XST1 + 256 + ((tid + 512 )&255)*4) = r1;
        *(float4*)(xt + ((tid + 1024)>>8)*XST1 + 256 + ((tid + 1024)&255)*4) = r2;
        *(float4*)(xt + ((tid + 1536)>>8)*XST1 + 256 + ((tid + 1536)&255)*4) = r3;
        *(float4*)(xt + ((tid + 2048)>>8)*XST1 + 256 + ((tid + 2048)&255)*4) = r4;
        *(float4*)(xt + ((tid + 2560)>>8)*XST1 + 256 + ((tid + 2560)&255)*4) = r5;
        *(float4*)(xt + ((tid + 3072)>>8)*XST1 + 256 + ((tid + 3072)&255)*4) = r6;
        *(float4*)(xt + ((tid + 3584)>>8)*XST1 + 256 + ((tid + 3584)&255)*4) = r7;
      }
      __syncthreads();
      // ---- GEMV-a: gates0 pre = Wih0[:, :256]@mel + Whh0@h0prev (+biases)
      {
        const int nr = hg0 ? 5 : 4;
        int nrow[5];
        #pragma unroll
        for (int ri = 0; ri < 4; ++ri) nrow[ri] = ri*1024 + j0 + rg;
        nrow[4] = rg*1024 + ((jx0 < 64) ? jx0 : 0);
        float acc[5][8];
        #pragma unroll
        for (int ri = 0; ri < 5; ++ri)
          #pragma unroll
          for (int bi = 0; bi < 8; ++bi) acc[ri][bi] = 0.0f;
        { // mel chunk
          const int j = ks*4;
          float4 w4[5];
          #pragma unroll
          for (int ri = 0; ri < 5; ++ri)
            if (ri < nr) w4[ri] = *(const float4*)(Wih0 + nrow[ri]*768 + j);
          #pragma unroll
          for (int bi = 0; bi < 8; ++bi) {
            const float4 xv = *(const float4*)(xt + (bgb+bi)*XST1 + j);
            #pragma unroll
            for (int ri = 0; ri < 5; ++ri)
              if (ri < nr)
                acc[ri][bi] += w4[ri].x*xv.x + w4[ri].y*xv.y + w4[ri].z*xv.z + w4[ri].w*xv.w;
          }
        }
        #pragma unroll
        for (int q = 0; q < 4; ++q) { // h0 chunks
          const int j = q*256 + ks*4;
          float4 w4[5];
          #pragma unroll
          for (int ri = 0; ri < 5; ++ri)
            if (ri < nr) w4[ri] = *(const float4*)(Whh0 + nrow[ri]*1024 + j);
          #pragma unroll
          for (int bi = 0; bi < 8; ++bi) {
            const float4 xv = *(const float4*)(xt + (bgb+bi)*XST1 + 256 + j);
            #pragma unroll
            for (int ri = 0; ri < 5; ++ri)
              if (ri < nr)
                acc[ri][bi] += w4[ri].x*xv.x + w4[ri].y*xv.y + w4[ri].z*xv.z + w4[ri].w*xv.w;
          }
        }
        #pragma unroll
        for (int ri = 0; ri < 5; ++ri)
          if (ri < nr)
            #pragma unroll
            for (int bi = 0; bi < 8; ++bi) {
              float v = acc[ri][bi];
              REDUCE64(v);
              if (ks == 63) {
                const int n = nrow[ri];
                v += bih0[n] + bhh0[n];
                if (ri < 4) gv0[(ri*4 + rg)*16 + (bgb+bi)] = v;
                else        st_sys(g0pre + (bgb+bi)*256 + jx0*4 + rg, v);
              }
            }
      }
      __syncthreads();
      // ---- stage h1prev tile (waited batched LLC load)
      {
        const float* src = h1buf + prev*B_*DIM_;
        float4 r0,r1,r2,r3,r4,r5,r6,r7;
        ld8q_sys(src + tid*4, src + (tid+512)*4, src + (tid+1024)*4, src + (tid+1536)*4,
                 src + (tid+2048)*4, src + (tid+2560)*4, src + (tid+3072)*4, src + (tid+3584)*4,
                 r0,r1,r2,r3,r4,r5,r6,r7);
        *(float4*)(xt + ((tid       )>>8)*XST1 + ((tid       )&255)*4) = r0;
        *(float4*)(xt + ((tid + 512 )>>8)*XST1 + ((tid + 512 )&255)*4) = r1;
        *(float4*)(xt + ((tid + 1024)>>8)*XST1 + ((tid + 1024)&255)*4) = r2;
        *(float4*)(xt + ((tid + 1536)>>8)*XST1 + ((tid + 1536)&255)*4) = r3;
        *(float4*)(xt + ((tid + 2048)>>8)*XST1 + ((tid + 2048)&255)*4) = r4;
        *(float4*)(xt + ((tid + 2560)>>8)*XST1 + ((tid + 2560)&255)*4) = r5;
        *(float4*)(xt + ((tid + 3072)>>8)*XST1 + ((tid + 3072)&255)*4) = r6;
        *(float4*)(xt + ((tid + 3584)>>8)*XST1 + ((tid + 3584)&255)*4) = r7;
      }
      __syncthreads();
      // ---- GEMV-b: gates1 pre = Whh1@h1prev (+biases)
      {
        const int nr = hg1 ? 5 : 4;
        int nrow[5];
        #pragma unroll
        for (int ri = 0; ri < 4; ++ri) nrow[ri] = ri*1024 + j0 + rg;
        nrow[4] = rg*1024 + (hg1 ? jx1 : 0);
        float acc[5][8];
        #pragma unroll
        for (int ri = 0; ri < 5; ++ri)
          #pragma unroll
          for (int bi = 0; bi < 8; ++bi) acc[ri][bi] = 0.0f;
        #pragma unroll
        for (int q = 0; q < 4; ++q) {
          const int j = q*256 + ks*4;
          float4 w4[5];
          #pragma unroll
          for (int ri = 0; ri < 5; ++ri)
            if (ri < nr) w4[ri] = *(const float4*)(Whh1 + nrow[ri]*1024 + j);
          #pragma unroll
          for (int bi = 0; bi < 8; ++bi) {
            const float4 xv = *(const float4*)(xt + (bgb+bi)*XST1 + j);
            #pragma unroll
            for (int ri = 0; ri < 5; ++ri)
              if (ri < nr)
                acc[ri][bi] += w4[ri].x*xv.x + w4[ri].y*xv.y + w4[ri].z*xv.z + w4[ri].w*xv.w;
          }
        }
        #pragma unroll
        for (int ri = 0; ri < 5; ++ri)
          if (ri < nr)
            #pragma unroll
            for (int bi = 0; bi < 8; ++bi) {
              float v = acc[ri][bi];
              REDUCE64(v);
              if (ks == 63) {
                const int n = nrow[ri];
                v += bih1[n] + bhh1[n];
                if (ri < 4) gv1[(ri*4 + rg)*16 + (bgb+bi)] = v;
                else        st_sys(g1pre + (bgb+bi)*256 + jx1*4 + rg, v);
              }
            }
      }
    }
    gridbar(bar, tid, blk, ep); ++ep;

    //====================== P2: gates0 align part + LSTM0 ======================
    {
      { // stage align tile (waited)
        const float* src = albuf + cur*B_*ENC_;
        float4 r0,r1,r2,r3;
        ld4q_sys(src + tid*4, src + (tid+512)*4, src + (tid+1024)*4, src + (tid+1536)*4,
                 r0,r1,r2,r3);
        *(float4*)(xt + ((tid       )>>7)*XST2 + ((tid       )&127)*4) = r0;
        *(float4*)(xt + ((tid + 512 )>>7)*XST2 + ((tid + 512 )&127)*4) = r1;
        *(float4*)(xt + ((tid + 1024)>>7)*XST2 + ((tid + 1024)&127)*4) = r2;
        *(float4*)(xt + ((tid + 1536)>>7)*XST2 + ((tid + 1536)&127)*4) = r3;
      }
      __syncthreads();
      float acc[4][8];
      #pragma unroll
      for (int ri = 0; ri < 4; ++ri)
        #pragma unroll
        for (int bi = 0; bi < 8; ++bi) acc[ri][bi] = 0.0f;
      #pragma unroll
      for (int q = 0; q < 2; ++q) {
        const int j = q*256 + ks*4;
        float4 w4[4];
        #pragma unroll
        for (int ri = 0; ri < 4; ++ri)
          w4[ri] = *(const float4*)(Wih0 + (ri*1024 + j0 + rg)*768 + 256 + j);
        #pragma unroll
        for (int bi = 0; bi < 8; ++bi) {
          const float4 xv = *(const float4*)(xt + (bgb+bi)*XST2 + j);
          #pragma unroll
          for (int ri = 0; ri < 4; ++ri)
            acc[ri][bi] += w4[ri].x*xv.x + w4[ri].y*xv.y + w4[ri].z*xv.z + w4[ri].w*xv.w;
        }
      }
      #pragma unroll
      for (int ri = 0; ri < 4; ++ri)
        #pragma unroll
        for (int bi = 0; bi < 8; ++bi) {
          float v = acc[ri][bi];
          REDUCE64(v);
          if (ks == 63) gv[(rg*4 + ri)*16 + (bgb+bi)] = v;
        }
      __syncthreads();
      if (tid < 64) {
        const int jl = tid >> 4, bb = tid & 15;
        const int j = j0 + jl;
        float pi, pf, pg, po;
        if (blk < B_) {
          const float4 g4 = ld1q_sys(g0pre + bb*256 + j*4);
          pi = g4.x; pf = g4.y; pg = g4.z; po = g4.w;
        } else {
          pi = gv0[(0*4 + jl)*16 + bb];
          pf = gv0[(1*4 + jl)*16 + bb];
          pg = gv0[(2*4 + jl)*16 + bb];
          po = gv0[(3*4 + jl)*16 + bb];
        }
        const float gi = gv[(jl*4+0)*16 + bb] + pi;
        const float gf = gv[(jl*4+1)*16 + bb] + pf;
        const float gg = gv[(jl*4+2)*16 + bb] + pg;
        const float go = gv[(jl*4+3)*16 + bb] + po;
        const float cn = fsigf(gf)*c0r + fsigf(gi)*ftanhf(gg);
        const float hn = fsigf(go)*ftanhf(cn);
        c0r = cn;
        st_sys(h0st + bb*DIM_ + j, hn);
      }
    }
    gridbar(bar, tid, blk, ep); ++ep;

    //====================== P3: gates1 Wih1@h0 + LSTM1 ======================
    {
      { // stage h0 tile (waited batched)
        float4 r0,r1,r2,r3,r4,r5,r6,r7;
        ld8q_sys(h0st + tid*4, h0st + (tid+512)*4, h0st + (tid+1024)*4, h0st + (tid+1536)*4,
                 h0st + (tid+2048)*4, h0st + (tid+2560)*4, h0st + (tid+3072)*4, h0st + (tid+3584)*4,
                 r0,r1,r2,r3,r4,r5,r6,r7);
        *(float4*)(xt + ((tid       )>>8)*XST3 + ((tid       )&255)*4) = r0;
        *(float4*)(xt + ((tid + 512 )>>8)*XST3 + ((tid + 512 )&255)*4) = r1;
        *(float4*)(xt + ((tid + 1024)>>8)*XST3 + ((tid + 1024)&255)*4) = r2;
        *(float4*)(xt + ((tid + 1536)>>8)*XST3 + ((tid + 1536)&255)*4) = r3;
        *(float4*)(xt + ((tid + 2048)>>8)*XST3 + ((tid + 2048)&255)*4) = r4;
        *(float4*)(xt + ((tid + 2560)>>8)*XST3 + ((tid + 2560)&255)*4) = r5;
        *(float4*)(xt + ((tid + 3072)>>8)*XST3 + ((tid + 3072)&255)*4) = r6;
        *(float4*)(xt + ((tid + 3584)>>8)*XST3 + ((tid + 3584)&255)*4) = r7;
      }
      __syncthreads();
      float acc[4][8];
      #pragma unroll
      for (int ri = 0; ri < 4; ++ri)
        #pragma unroll
        for (int bi = 0; bi < 8; ++bi) acc[ri][bi] = 0.0f;
      #pragma unroll
      for (int q = 0; q < 4; ++q) {
        const int j = q*256 + ks*4;
        float4 w4[4];
        if (blk < B_) {
          #pragma unroll
          for (int ri = 0; ri < 4; ++ri)
            w4[ri] = *(const float4*)(Wih1 + (ri*1024 + j0 + rg)*1024 + j);
        } else {
          #pragma unroll
          for (int ri = 0; ri < 4; ++ri)
            w4[ri] = *(const float4*)(xt + WLDS + (((ri*4 + rg)*4 + q) << 8) + ks*4);
        }
        #pragma unroll
        for (int bi = 0; bi < 8; ++bi) {
          const float4 xv = *(const float4*)(xt + (bgb+bi)*XST3 + j);
          #pragma unroll
          for (int ri = 0; ri < 4; ++ri)
            acc[ri][bi] += w4[ri].x*xv.x + w4[ri].y*xv.y + w4[ri].z*xv.z + w4[ri].w*xv.w;
        }
      }
      #pragma unroll
      for (int ri = 0; ri < 4; ++ri)
        #pragma unroll
        for (int bi = 0; bi < 8; ++bi) {
          float v = acc[ri][bi];
          REDUCE64(v);
          if (ks == 63) gv[(rg*4 + ri)*16 + (bgb+bi)] = v;
        }
      __syncthreads();
      if (tid < 64) {
        const int jl = tid >> 4, bb = tid & 15;
        const int j = j0 + jl;
        float pi, pf, pg, po;
        if (blk < B_) {
          const float4 g4 = ld1q_sys(g1pre + bb*256 + j*4);
          pi = g4.x; pf = g4.y; pg = g4.z; po = g4.w;
        } else {
          pi = gv1[(0*4 + jl)*16 + bb];
          pf = gv1[(1*4 + jl)*16 + bb];
          pg = gv1[(2*4 + jl)*16 + bb];
          po = gv1[(3*4 + jl)*16 + bb];
        }
        const float gi = gv[(jl*4+0)*16 + bb] + pi;
        const float gf = gv[(jl*4+1)*16 + bb] + pf;
        const float gg = gv[(jl*4+2)*16 + bb] + pg;
        const float go = gv[(jl*4+3)*16 + bb] + po;
        const float cn = fsigf(gf)*c1r + fsigf(gi)*ftanhf(gg);
        const float hn = fsigf(go)*ftanhf(cn);
        c1r = cn;
        st_sys(h1buf + cur*B_*DIM_ + bb*DIM_ + j, hn);
      }
    }
    gridbar(bar, tid, blk, ep); ++ep;
  }

  // ---- tail projection for t = T_-1 (step-299 h1/align live in slot 0)
  if (blk < B_) {
    const int b = blk;
    if (tid < 256) {
      float4 v = ld1q_sys(h1buf + b*DIM_ + tid*4);
      *(float4*)(projx + tid*4) = v;
    } else if (tid < 384) {
      const int j = tid - 256;
      float4 v = ld1q_sys(albuf + b*ENC_ + j*4);
      *(float4*)(projx + 1024 + j*4) = v;
    }
    __syncthreads();
    const int o = tid >> 2, part = tid & 3;
    if (o < 81) {
      const float* w = projW + o*1536;
      const int jb = part*384;
      float acc = 0.0f;
      for (int j = jb; j < jb + 384; j += 4) {
        const float4 wv = *(const float4*)(w + j);
        const float4 xv = *(const float4*)(projx + j);
        acc += wv.x*xv.x + wv.y*xv.y + wv.z*xv.z + wv.w*xv.w;
      }
      spf[o*4 + part] = acc;
    }
    __syncthreads();
    if (tid < 81) {
      const float v = projb[tid] + spf[tid*4] + spf[tid*4+1] + spf[tid*4+2] + spf[tid*4+3];
      if (tid < 80) out_mel[(b*NMEL_ + tid)*T_ + (T_-1)] = v;
      else          out_stop[b*T_ + (T_-1)] = v;
    }
  }
}

extern "C" void kernel_launch(void* const* d_in, const int* in_sizes, int n_in,
                              void* d_out, int out_size, void* d_ws, size_t ws_size,
                              hipStream_t stream) {
  const float* mels  = (const float*)d_in[0];
  const float* enc   = (const float*)d_in[1];
  const int*   tlen  = (const int*)d_in[2];
  const float* Wt    = (const float*)d_in[3];
  const float* Wq    = (const float*)d_in[4];
  const float* wsc   = (const float*)d_in[5];
  const float* conv1 = (const float*)d_in[6];
  const float* conv2 = (const float*)d_in[7];
  const float* pW1   = (const float*)d_in[8];
  const float* pb1   = (const float*)d_in[9];
  const float* pW2   = (const float*)d_in[10];
  const float* pb2   = (const float*)d_in[11];
  const float* Wih0  = (const float*)d_in[12];
  const float* Whh0  = (const float*)d_in[13];
  const float* bih0  = (const float*)d_in[14];
  const float* bhh0  = (const float*)d_in[15];
  const float* Wih1  = (const float*)d_in[16];
  const float* Whh1  = (const float*)d_in[17];
  const float* bih1  = (const float*)d_in[18];
  const float* bhh1  = (const float*)d_in[19];
  const float* h0    = (const float*)d_in[20];
  const float* c0    = (const float*)d_in[21];
  const float* projW = (const float*)d_in[22];
  const float* projb = (const float*)d_in[23];

  float* ws     = (float*)d_ws;
  float* melpre = ws;                  // 300*16*256   = 1228800
  float* lencb  = melpre + 1228800;    // 16*160*128   = 327680
  float* weff   = lencb + 327680;      // 128*32       = 4096
  float* h1buf  = weff + 4096;         // 2*16*1024    = 32768
  float* albuf  = h1buf + 32768;       // 2*16*512     = 16384
  float* h0st   = albuf + 16384;       // 16*1024      = 16384
  float* g0pre  = h0st + 16384;        // 16*256       = 4096
  float* g1pre  = g0pre + 4096;        // 16*256       = 4096
  u32*   bar    = (u32*)(g1pre + 4096);// 17408 words

  float* out_mel  = (float*)d_out;
  float* out_stop = out_mel + 384000;
  float* out_attn = out_stop + 4800;

  prenet_kernel<<<dim3(480), dim3(256), 0, stream>>>(mels, pW1, pb1, pW2, pb2, melpre);
  init_kernel<<<dim3(160), dim3(256), 0, stream>>>(h0, conv1, conv2, h1buf, h0st, weff, bar);
  lenc_kernel<<<dim3(640), dim3(256), 0, stream>>>(enc, Wt, lencb);

  void* args[] = {
    (void*)&melpre, (void*)&lencb, (void*)&weff, (void*)&h1buf, (void*)&albuf, (void*)&h0st,
    (void*)&g0pre, (void*)&g1pre, (void*)&bar,
    (void*)&enc, (void*)&tlen, (void*)&Wq, (void*)&wsc,
    (void*)&Wih0, (void*)&Whh0, (void*)&bih0, (void*)&bhh0,
    (void*)&Wih1, (void*)&Whh1, (void*)&bih1, (void*)&bhh1,
    (void*)&c0, (void*)&projW, (void*)&projb,
    (void*)&out_mel, (void*)&out_stop, (void*)&out_attn
  };
  hipLaunchCooperativeKernel((const void*)decoder_kernel, dim3(256), dim3(512),
                             args, (unsigned int)(XTOT*sizeof(float)), stream);
}

// Round 7
// 47011.005 us; speedup vs baseline: 1.0236x; 1.0236x over previous
//
#include <hip/hip_runtime.h>

#define T_    300
#define B_    16
#define S_    160
#define NMEL_ 80
#define PRE_  256
#define ENC_  512
#define ATT_  128
#define DIM_  1024

#define XST1  1288     // P1 tile stride (mel 256 + h0 1024 + pad 8); rows end at 20600
#define XST2  520      // P2 align tile stride (ends 8320)
#define XST3  1032     // P3 h0 tile stride (ends 16504)
#define AOFF  16512    // attn blocks: persistent arrays (cum_p, projx, wscs) — above staging
#define WLDS  20608    // compute blocks: pinned Wih1 rows, 16x1024 = 16384 floats
#define XTOT  36992    // dynamic LDS floats (148 KB)
#define BARWORDS 17408

typedef unsigned int u32;

__device__ __forceinline__ float fexp2f(float x) { return __builtin_amdgcn_exp2f(x); }
__device__ __forceinline__ float fsigf(float x)  { return 1.0f / (1.0f + fexp2f(-1.442695041f * x)); }
__device__ __forceinline__ float ftanhf(float x) {
  float xc = fminf(fmaxf(x, -15.0f), 15.0f);
  float e = fexp2f(2.885390082f * xc);
  return (e - 1.0f) / (e + 1.0f);
}

// ---- system-scope (LLC) accessors. waitcnt lives INSIDE each asm block so the
// register allocator never sees a pending-load destination (R3 bug).
__device__ __forceinline__ float4 ld1q_sys(const float* p) {
  float4 v;
  asm volatile("global_load_dwordx4 %0, %1, off sc0 sc1\n\ts_waitcnt vmcnt(0)"
               : "=v"(v) : "v"(p) : "memory");
  return v;
}
__device__ __forceinline__ void ld4q_sys(const float* p0, const float* p1,
                                         const float* p2, const float* p3,
                                         float4& a, float4& b, float4& c, float4& d) {
  asm volatile(
      "global_load_dwordx4 %0, %4, off sc0 sc1\n\t"
      "global_load_dwordx4 %1, %5, off sc0 sc1\n\t"
      "global_load_dwordx4 %2, %6, off sc0 sc1\n\t"
      "global_load_dwordx4 %3, %7, off sc0 sc1\n\t"
      "s_waitcnt vmcnt(0)"
      : "=&v"(a), "=&v"(b), "=&v"(c), "=&v"(d)
      : "v"(p0), "v"(p1), "v"(p2), "v"(p3) : "memory");
}
__device__ __forceinline__ void ld8q_sys(const float* p0,const float* p1,const float* p2,const float* p3,
                                         const float* p4,const float* p5,const float* p6,const float* p7,
                                         float4& a,float4& b,float4& c,float4& d,
                                         float4& e,float4& f,float4& g,float4& h) {
  asm volatile(
      "global_load_dwordx4 %0, %8, off sc0 sc1\n\t"
      "global_load_dwordx4 %1, %9, off sc0 sc1\n\t"
      "global_load_dwordx4 %2, %10, off sc0 sc1\n\t"
      "global_load_dwordx4 %3, %11, off sc0 sc1\n\t"
      "global_load_dwordx4 %4, %12, off sc0 sc1\n\t"
      "global_load_dwordx4 %5, %13, off sc0 sc1\n\t"
      "global_load_dwordx4 %6, %14, off sc0 sc1\n\t"
      "global_load_dwordx4 %7, %15, off sc0 sc1\n\t"
      "s_waitcnt vmcnt(0)"
      : "=&v"(a),"=&v"(b),"=&v"(c),"=&v"(d),"=&v"(e),"=&v"(f),"=&v"(g),"=&v"(h)
      : "v"(p0),"v"(p1),"v"(p2),"v"(p3),"v"(p4),"v"(p5),"v"(p6),"v"(p7)
      : "memory");
}
__device__ __forceinline__ void st_sys(float* p, float v) {
  asm volatile("global_store_dword %0, %1, off sc0 sc1" :: "v"(p), "v"(v) : "memory");
}
__device__ __forceinline__ u32 ld_sys_u32(const u32* p) {
  u32 r;
  asm volatile("global_load_dword %0, %1, off sc0 sc1\n\ts_waitcnt vmcnt(0)"
               : "=v"(r) : "v"(p) : "memory");
  return r;
}
__device__ __forceinline__ void st_sys_u32(u32* p, u32 v) {
  asm volatile("global_store_dword %0, %1, off sc0 sc1" :: "v"(p), "v"(v) : "memory");
}

// ---- tree-arrival / wide-release barrier: 16 groups x 16 blocks arrival
// (spreads atomic contention). Top releaser writes 16 PER-GROUP release words
// (one per 4KB-spaced line) so each line has <=16 pollers instead of 240 —
// the single-trel hot line had a 240-reader storm delaying the release write
// and its detection.
__device__ __forceinline__ void gridbar(u32* bar, int tid, int blk, u32 ep) {
  asm volatile("s_waitcnt vmcnt(0)" ::: "memory");   // drain this wave's sc stores
  __syncthreads();
  if (tid == 0) {
    const int g = blk & 15;
    u32* cnt  = bar + g*1024;
    u32* grel = bar + g*1024 + 64;
    u32* tcnt = bar + 16384;
    const u32 tgt = ep*16u + 15u;
    u32 old = __hip_atomic_fetch_add(cnt, 1u, __ATOMIC_RELAXED, __HIP_MEMORY_SCOPE_AGENT);
    if (old == tgt) {
      u32 told = __hip_atomic_fetch_add(tcnt, 1u, __ATOMIC_RELAXED, __HIP_MEMORY_SCOPE_AGENT);
      if (told == tgt) {
        #pragma unroll
        for (int g2 = 0; g2 < 16; ++g2) st_sys_u32(bar + g2*1024 + 64, ep + 1u);
      } else {
        while (ld_sys_u32(grel) != ep + 1u) __builtin_amdgcn_s_sleep(1);
      }
    } else {
      while (ld_sys_u32(grel) != ep + 1u) __builtin_amdgcn_s_sleep(1);
    }
  }
  __syncthreads();
}

// ---- wave-64 sum via DPP (VALU pipe, zero DS ops).
#define DPP_ADD(v, ctrl, rmask) do { \
  int _t = __builtin_amdgcn_update_dpp(0, __float_as_int(v), (ctrl), (rmask), 0xf, false); \
  (v) += __int_as_float(_t); } while (0)

#define REDUCE64(v) do { \
  DPP_ADD(v, 0x111, 0xf); \
  DPP_ADD(v, 0x112, 0xf); \
  DPP_ADD(v, 0x114, 0xf); \
  DPP_ADD(v, 0x118, 0xf); \
  DPP_ADD(v, 0x142, 0xa); \
  DPP_ADD(v, 0x143, 0x8); } while (0)

// ---------------- prenet
__launch_bounds__(256)
__global__ void prenet_kernel(const float* __restrict__ mels,
                              const float* __restrict__ pW1, const float* __restrict__ pb1,
                              const float* __restrict__ pW2, const float* __restrict__ pb2,
                              float* __restrict__ melpre) {
  __shared__ float mcol[NMEL_];
  __shared__ float pcol[PRE_];
  const int b = blockIdx.x / 30;
  const int tbase = (blockIdx.x % 30) * 10;
  const int tid = threadIdx.x;
  for (int f = 0; f < 10; ++f) {
    const int t = tbase + f;
    if (tid < NMEL_) mcol[tid] = (t == 0) ? 0.0f : mels[(b*NMEL_ + tid)*T_ + (t-1)];
    __syncthreads();
    {
      float a1 = pb1[tid];
      const float* w1 = pW1 + tid*NMEL_;
      for (int m = 0; m < NMEL_; ++m) a1 += w1[m]*mcol[m];
      pcol[tid] = fmaxf(a1, 0.0f);
    }
    __syncthreads();
    {
      float a2 = pb2[tid];
      const float* w2 = pW2 + tid*PRE_;
      for (int d = 0; d < PRE_; d += 4) {
        const float4 wv = *(const float4*)(w2 + d);
        a2 += wv.x*pcol[d] + wv.y*pcol[d+1] + wv.z*pcol[d+2] + wv.w*pcol[d+3];
      }
      melpre[(t*B_ + b)*PRE_ + tid] = fmaxf(a2, 0.0f);
    }
    __syncthreads();
  }
}

// ---------------- init: h states, Weff, barrier region
__launch_bounds__(256)
__global__ void init_kernel(const float* __restrict__ h0,
                            const float* __restrict__ conv1, const float* __restrict__ conv2,
                            float* __restrict__ h1buf, float* __restrict__ h0st,
                            float* __restrict__ weff, u32* __restrict__ bar) {
  const int idx = blockIdx.x*256 + threadIdx.x;
  if (idx < B_*DIM_) {
    const int j = idx & (DIM_-1);
    h0st[idx]  = h0[j];
    h1buf[idx] = h0[DIM_ + j];
  } else if (idx < B_*DIM_ + ATT_*32) {
    const int r = idx - B_*DIM_;
    const int a = r >> 5, k = r & 31;
    float acc = 0.0f;
    if (k < 31) {
      for (int l = 0; l < 32; ++l) acc += conv2[a*32 + l]*conv1[l*31 + k];
    }
    weff[r] = acc;   // row tap 31 stays exactly 0 (used as padded FMA tap)
  } else if (idx < B_*DIM_ + ATT_*32 + BARWORDS) {
    bar[idx - (B_*DIM_ + ATT_*32)] = 0u;
  }
}

// ---------------- l_enc
__launch_bounds__(256)
__global__ void lenc_kernel(const float* __restrict__ enc, const float* __restrict__ Wt,
                            float* __restrict__ lencb) {
  __shared__ float es[4*ENC_];
  const int b = blockIdx.x / 40;
  const int s0 = (blockIdx.x % 40) * 4;
  const int tid = threadIdx.x;
  for (int idx = tid; idx < 4*ENC_; idx += 256) es[idx] = enc[(b*S_ + s0)*ENC_ + idx];
  __syncthreads();
  const int a = tid & 127, sh = tid >> 7;
  const float* w = Wt + a*ENC_;
  for (int p = 0; p < 2; ++p) {
    const int sl = sh*2 + p;
    const float* e = es + sl*ENC_;
    float acc = 0.0f;
    for (int j = 0; j < ENC_; j += 4) {
      const float4 wv = *(const float4*)(w + j);
      acc += wv.x*e[j] + wv.y*e[j+1] + wv.z*e[j+2] + wv.w*e[j+3];
    }
    lencb[(b*S_ + s0 + sl)*ATT_ + a] = acc;
  }
}

// ---------------- persistent decoder
// P1: blk<16 attention (score conv reads weff from GLOBAL float4 — L1-resident,
//     wave-uniform; the old per-tap LDS reads were ~17K ds_read_b32/block/step
//     on the single LDS pipe ≈ 35 us, the epoch-1 straggler);
//     blk>=16: gates0-pre & gates1-pre GEMVs.
// P2: align part of gates0 + LSTM0 -> h0st.
// P3: Wih1@h0 + LSTM1 -> h1buf; attn blocks also project step t-1 (spf static).
__launch_bounds__(512, 1)
__global__ void decoder_kernel(
    const float* __restrict__ melpre, const float* __restrict__ lencb,
    const float* __restrict__ weff,
    float* __restrict__ h1buf, float* __restrict__ albuf, float* __restrict__ h0st,
    float* __restrict__ g0pre, float* __restrict__ g1pre, u32* __restrict__ bar,
    const float* __restrict__ enc, const int* __restrict__ tlen,
    const float* __restrict__ Wq, const float* __restrict__ wsc,
    const float* __restrict__ Wih0, const float* __restrict__ Whh0,
    const float* __restrict__ bih0, const float* __restrict__ bhh0,
    const float* __restrict__ Wih1, const float* __restrict__ Whh1,
    const float* __restrict__ bih1, const float* __restrict__ bhh1,
    const float* __restrict__ c0in, const float* __restrict__ projW, const float* __restrict__ projb,
    float* __restrict__ out_mel, float* __restrict__ out_stop, float* __restrict__ out_attn)
{
  extern __shared__ float xt[];
  __shared__ float red_s[1];
  __shared__ float gv[256];    // P2/P3 GEMV reduction
  __shared__ float gv0[256];   // gates0 pre (own rows), persists P1->P2
  __shared__ float gv1[256];   // gates1 pre (own rows), persists P1->P3
  __shared__ float q_s[ATT_];
  __shared__ float spf[S_*4];  // P1 score partials; P3 proj partials
  __shared__ float score_s[S_];
  __shared__ float attn_s[S_];

  // attn-block persistent overlays in dynamic LDS, above P3 staging reach (16504)
  float* const cum_p = xt + AOFF;          // [190]
  float* const projx = xt + AOFF + 192;    // [1536]
  float* const wscs  = xt + AOFF + 1728;   // [128]

  const int blk = blockIdx.x;
  const int tid = threadIdx.x;
  const int ks = tid & 63;
  const int bgb = ((tid >> 6) & 1)*8;
  const int rg = tid >> 7;
  const int j0 = blk*4;

  float c0r = 0.0f, c1r = 0.0f;
  if (tid < 64) {
    const int j = j0 + (tid >> 4);
    c0r = c0in[j];
    c1r = c0in[DIM_ + j];
  }
  int mylen = 0;
  if (blk < B_) {
    mylen = tlen[blk];
    for (int i = tid; i < S_ + 30; i += 512) cum_p[i] = 0.0f;
    if (tid < ATT_) wscs[tid] = wsc[tid];
  } else {
    // pin this block's Wih1 rows (16 rows x 1024 cols) into LDS, chunked so
    // lane ks reads chunk c at [c*256 + ks*4] conflict-free in P3.
    for (int i = tid; i < 4096; i += 512) {
      const int c = i >> 6, l = i & 63;
      const int ri = c >> 4, rgw = (c >> 2) & 3, q = c & 3;
      *(float4*)(xt + WLDS + c*256 + l*4) =
          *(const float4*)(Wih1 + (ri*1024 + j0 + rgw)*1024 + q*256 + l*4);
    }
  }
  __syncthreads();

  u32 ep = 0;

  for (int t = 0; t < T_; ++t) {
    const int prev = t & 1;
    const int cur = prev ^ 1;

    //====================== P1 ======================
    if (blk < B_) {
      const int b = blk;
      // stage [h1prev | alignprev] into projx (used for q now, proj in P3)
      if (tid < 256) {
        float4 v = ld1q_sys(h1buf + prev*B_*DIM_ + b*DIM_ + tid*4);
        *(float4*)(projx + tid*4) = v;
      } else if (tid < 384) {
        const int j = tid - 256;
        float4 v = ld1q_sys(albuf + prev*B_*ENC_ + b*ENC_ + j*4);
        *(float4*)(projx + 1024 + j*4) = v;
      }
      __syncthreads();
      // q = h1prev @ Wq^T
      {
        const int a = tid & 127, part = tid >> 7;
        const float* hp = projx + part*256;
        const float* wq = Wq + a*DIM_ + part*256;
        float acc = 0.0f;
        for (int j = 0; j < 256; j += 4) {
          const float4 wv = *(const float4*)(wq + j);
          const float4 hv = *(const float4*)(hp + j);
          acc += wv.x*hv.x + wv.y*hv.y + wv.z*hv.z + wv.w*hv.w;
        }
        spf[a*4 + part] = acc;
      }
      __syncthreads();
      if (tid < ATT_) q_s[tid] = spf[tid*4] + spf[tid*4+1] + spf[tid*4+2] + spf[tid*4+3];
      __syncthreads();
      // scores: loc-conv taps read from GLOBAL weff (L1-resident, wave-uniform
      // addresses), cw in registers with a zero tail tap.
      {
        const int sl = tid & 127, ag = tid >> 7;
        const int a0 = ag*32;
        #pragma unroll
        for (int p = 0; p < 2; ++p) {
          const int s = sl + p*128;
          if (s < S_) {
            float cw[32];
            #pragma unroll
            for (int k = 0; k < 31; ++k) cw[k] = cum_p[s + k];
            cw[31] = 0.0f;
            const float* le = lencb + (b*S_ + s)*ATT_ + a0;
            const float* wr = weff + a0*32;
            float ps = 0.0f;
            for (int i4 = 0; i4 < 8; ++i4) {
              const float4 lev = *(const float4*)(le + i4*4);
              #pragma unroll
              for (int ii = 0; ii < 4; ++ii) {
                const int i = i4*4 + ii;
                const float4* wk4 = (const float4*)(wr + i*32);
                float loc = 0.0f;
                #pragma unroll
                for (int kq = 0; kq < 8; ++kq) {
                  const float4 wv = wk4[kq];
                  loc += wv.x*cw[kq*4+0] + wv.y*cw[kq*4+1] + wv.z*cw[kq*4+2] + wv.w*cw[kq*4+3];
                }
                const float lef = (ii==0)?lev.x:(ii==1)?lev.y:(ii==2)?lev.z:lev.w;
                ps += wscs[a0 + i]*ftanhf(q_s[a0 + i] + lef + loc);
              }
            }
            spf[s*4 + ag] = ps;
          }
        }
      }
      __syncthreads();
      if (tid < S_) {
        float sc = spf[tid*4] + spf[tid*4+1] + spf[tid*4+2] + spf[tid*4+3];
        if (tid >= mylen) sc = -1.0e30f;
        score_s[tid] = sc;
      }
      __syncthreads();
      if (tid < 64) {
        float m = -1.0e30f;
        for (int i = tid; i < S_; i += 64) m = fmaxf(m, score_s[i]);
        #pragma unroll
        for (int o = 32; o > 0; o >>= 1) m = fmaxf(m, __shfl_xor(m, o, 64));
        float sum = 0.0f;
        for (int i = tid; i < S_; i += 64) {
          const float e = fexp2f(1.442695041f*(score_s[i] - m));
          score_s[i] = e;
          sum += e;
        }
        #pragma unroll
        for (int o = 32; o > 0; o >>= 1) sum += __shfl_xor(sum, o, 64);
        if (tid == 0) red_s[0] = sum;
      }
      __syncthreads();
      {
        const float inv = 1.0f / red_s[0];
        if (tid < S_) {
          const float av = score_s[tid]*inv;
          attn_s[tid] = av;
          cum_p[15 + tid] += av;
          out_attn[(b*S_ + tid)*T_ + t] = av;
        }
      }
      __syncthreads();
      // align = attn @ enc  -> albuf[cur] (sc)
      {
        const float* eb = enc + (b*S_)*ENC_ + tid;
        float acc = 0.0f;
        for (int s = 0; s < S_; ++s) acc += attn_s[s]*eb[s*ENC_];
        st_sys(albuf + cur*B_*ENC_ + b*ENC_ + tid, acc);
      }
    } else {
      const bool hg0 = (blk >= 16 && blk < 80);
      const bool hg1 = (blk >= 80 && blk < 144);
      const int jx0 = blk - 16;
      const int jx1 = blk - 80;
      // ---- stage [mel | h0prev] tile
      for (int i = tid; i < 1024; i += 512) {
        float4 v = *(const float4*)(melpre + t*4096 + i*4);
        *(float4*)(xt + (i>>6)*XST1 + (i&63)*4) = v;
      }
      {
        float4 r0,r1,r2,r3,r4,r5,r6,r7;
        ld8q_sys(h0st + tid*4, h0st + (tid+512)*4, h0st + (tid+1024)*4, h0st + (tid+1536)*4,
                 h0st + (tid+2048)*4, h0st + (tid+2560)*4, h0st + (tid+3072)*4, h0st + (tid+3584)*4,
                 r0,r1,r2,r3,r4,r5,r6,r7);
        *(float4*)(xt + ((tid       )>>8)*XST1 + 256 + ((tid       )&255)*4) = r0;
        *(float4*)(xt + ((tid + 512 )>>8)*XST1 + 256 + ((tid + 512 )&255)*4) = r1;
        *(float4*)(xt + ((tid + 1024)>>8)*XST1 + 256 + ((tid + 1024)&255)*4) = r2;
        *(float4*)(xt + ((tid + 1536)>>8)*XST1 + 256 + ((tid + 1536)&255)*4) = r3;
        *(float4*)(xt + ((tid + 2048)>>8)*XST1 + 256 + ((tid + 2048)&255)*4) = r4;
        *(float4*)(xt + ((tid + 2560)>>8)*XST1 + 256 + ((tid + 2560)&255)*4) = r5;
        *(float4*)(xt + ((tid + 3072)>>8)*XST1 + 256 + ((tid + 3072)&255)*4) = r6;
        *(float4*)(xt + ((tid + 3584)>>8)*XST1 + 256 + ((tid + 3584)&255)*4) = r7;
      }
      __syncthreads();
      // ---- GEMV-a: gates0 pre = Wih0[:, :256]@mel + Whh0@h0prev (+biases)
      {
        const int nr = hg0 ? 5 : 4;
        int nrow[5];
        #pragma unroll
        for (int ri = 0; ri < 4; ++ri) nrow[ri] = ri*1024 + j0 + rg;
        nrow[4] = rg*1024 + ((jx0 < 64) ? jx0 : 0);
        float acc[5][8];
        #pragma unroll
        for (int ri = 0; ri < 5; ++ri)
          #pragma unroll
          for (int bi = 0; bi < 8; ++bi) acc[ri][bi] = 0.0f;
        { // mel chunk
          const int j = ks*4;
          float4 w4[5];
          #pragma unroll
          for (int ri = 0; ri < 5; ++ri)
            if (ri < nr) w4[ri] = *(const float4*)(Wih0 + nrow[ri]*768 + j);
          #pragma unroll
          for (int bi = 0; bi < 8; ++bi) {
            const float4 xv = *(const float4*)(xt + (bgb+bi)*XST1 + j);
            #pragma unroll
            for (int ri = 0; ri < 5; ++ri)
              if (ri < nr)
                acc[ri][bi] += w4[ri].x*xv.x + w4[ri].y*xv.y + w4[ri].z*xv.z + w4[ri].w*xv.w;
          }
        }
        #pragma unroll
        for (int q = 0; q < 4; ++q) { // h0 chunks
          const int j = q*256 + ks*4;
          float4 w4[5];
          #pragma unroll
          for (int ri = 0; ri < 5; ++ri)
            if (ri < nr) w4[ri] = *(const float4*)(Whh0 + nrow[ri]*1024 + j);
          #pragma unroll
          for (int bi = 0; bi < 8; ++bi) {
            const float4 xv = *(const float4*)(xt + (bgb+bi)*XST1 + 256 + j);
            #pragma unroll
            for (int ri = 0; ri < 5; ++ri)
              if (ri < nr)
                acc[ri][bi] += w4[ri].x*xv.x + w4[ri].y*xv.y + w4[ri].z*xv.z + w4[ri].w*xv.w;
          }
        }
        #pragma unroll
        for (int ri = 0; ri < 5; ++ri)
          if (ri < nr)
            #pragma unroll
            for (int bi = 0; bi < 8; ++bi) {
              float v = acc[ri][bi];
              REDUCE64(v);
              if (ks == 63) {
                const int n = nrow[ri];
                v += bih0[n] + bhh0[n];
                if (ri < 4) gv0[(ri*4 + rg)*16 + (bgb+bi)] = v;
                else        st_sys(g0pre + (bgb+bi)*256 + jx0*4 + rg, v);
              }
            }
      }
      __syncthreads();
      // ---- stage h1prev tile (waited batched LLC load)
      {
        const float* src = h1buf + prev*B_*DIM_;
        float4 r0,r1,r2,r3,r4,r5,r6,r7;
        ld8q_sys(src + tid*4, src + (tid+512)*4, src + (tid+1024)*4, src + (tid+1536)*4,
                 src + (tid+2048)*4, src + (tid+2560)*4, src + (tid+3072)*4, src + (tid+3584)*4,
                 r0,r1,r2,r3,r4,r5,r6,r7);
        *(float4*)(xt + ((tid       )>>8)*XST1 + ((tid       )&255)*4) = r0;
        *(float4*)(xt + ((tid + 512 )>>8)*XST1 + ((tid + 512 )&255)*4) = r1;
        *(float4*)(xt + ((tid + 1024)>>8)*XST1 + ((tid + 1024)&255)*4) = r2;
        *(float4*)(xt + ((tid + 1536)>>8)*XST1 + ((tid + 1536)&255)*4) = r3;
        *(float4*)(xt + ((tid + 2048)>>8)*XST1 + ((tid + 2048)&255)*4) = r4;
        *(float4*)(xt + ((tid + 2560)>>8)*XST1 + ((tid + 2560)&255)*4) = r5;
        *(float4*)(xt + ((tid + 3072)>>8)*XST1 + ((tid + 3072)&255)*4) = r6;
        *(float4*)(xt + ((tid + 3584)>>8)*XST1 + ((tid + 3584)&255)*4) = r7;
      }
      __syncthreads();
      // ---- GEMV-b: gates1 pre = Whh1@h1prev (+biases)
      {
        const int nr = hg1 ? 5 : 4;
        int nrow[5];
        #pragma unroll
        for (int ri = 0; ri < 4; ++ri) nrow[ri] = ri*1024 + j0 + rg;
        nrow[4] = rg*1024 + (hg1 ? jx1 : 0);
        float acc[5][8];
        #pragma unroll
        for (int ri = 0; ri < 5; ++ri)
          #pragma unroll
          for (int bi = 0; bi < 8; ++bi) acc[ri][bi] = 0.0f;
        #pragma unroll
        for (int q = 0; q < 4; ++q) {
          const int j = q*256 + ks*4;
          float4 w4[5];
          #pragma unroll
          for (int ri = 0; ri < 5; ++ri)
            if (ri < nr) w4[ri] = *(const float4*)(Whh1 + nrow[ri]*1024 + j);
          #pragma unroll
          for (int bi = 0; bi < 8; ++bi) {
            const float4 xv = *(const float4*)(xt + (bgb+bi)*XST1 + j);
            #pragma unroll
            for (int ri = 0; ri < 5; ++ri)
              if (ri < nr)
                acc[ri][bi] += w4[ri].x*xv.x + w4[ri].y*xv.y + w4[ri].z*xv.z + w4[ri].w*xv.w;
          }
        }
        #pragma unroll
        for (int ri = 0; ri < 5; ++ri)
          if (ri < nr)
            #pragma unroll
            for (int bi = 0; bi < 8; ++bi) {
              float v = acc[ri][bi];
              REDUCE64(v);
              if (ks == 63) {
                const int n = nrow[ri];
                v += bih1[n] + bhh1[n];
                if (ri < 4) gv1[(ri*4 + rg)*16 + (bgb+bi)] = v;
                else        st_sys(g1pre + (bgb+bi)*256 + jx1*4 + rg, v);
              }
            }
      }
    }
    gridbar(bar, tid, blk, ep); ++ep;

    //====================== P2: gates0 align part + LSTM0 ======================
    {
      { // stage align tile (waited)
        const float* src = albuf + cur*B_*ENC_;
        float4 r0,r1,r2,r3;
        ld4q_sys(src + tid*4, src + (tid+512)*4, src + (tid+1024)*4, src + (tid+1536)*4,
                 r0,r1,r2,r3);
        *(float4*)(xt + ((tid       )>>7)*XST2 + ((tid       )&127)*4) = r0;
        *(float4*)(xt + ((tid + 512 )>>7)*XST2 + ((tid + 512 )&127)*4) = r1;
        *(float4*)(xt + ((tid + 1024)>>7)*XST2 + ((tid + 1024)&127)*4) = r2;
        *(float4*)(xt + ((tid + 1536)>>7)*XST2 + ((tid + 1536)&127)*4) = r3;
      }
      __syncthreads();
      float acc[4][8];
      #pragma unroll
      for (int ri = 0; ri < 4; ++ri)
        #pragma unroll
        for (int bi = 0; bi < 8; ++bi) acc[ri][bi] = 0.0f;
      #pragma unroll
      for (int q = 0; q < 2; ++q) {
        const int j = q*256 + ks*4;
        float4 w4[4];
        #pragma unroll
        for (int ri = 0; ri < 4; ++ri)
          w4[ri] = *(const float4*)(Wih0 + (ri*1024 + j0 + rg)*768 + 256 + j);
        #pragma unroll
        for (int bi = 0; bi < 8; ++bi) {
          const float4 xv = *(const float4*)(xt + (bgb+bi)*XST2 + j);
          #pragma unroll
          for (int ri = 0; ri < 4; ++ri)
            acc[ri][bi] += w4[ri].x*xv.x + w4[ri].y*xv.y + w4[ri].z*xv.z + w4[ri].w*xv.w;
        }
      }
      #pragma unroll
      for (int ri = 0; ri < 4; ++ri)
        #pragma unroll
        for (int bi = 0; bi < 8; ++bi) {
          float v = acc[ri][bi];
          REDUCE64(v);
          if (ks == 63) gv[(rg*4 + ri)*16 + (bgb+bi)] = v;
        }
      __syncthreads();
      if (tid < 64) {
        const int jl = tid >> 4, bb = tid & 15;
        const int j = j0 + jl;
        float pi, pf, pg, po;
        if (blk < B_) {
          const float4 g4 = ld1q_sys(g0pre + bb*256 + j*4);
          pi = g4.x; pf = g4.y; pg = g4.z; po = g4.w;
        } else {
          pi = gv0[(0*4 + jl)*16 + bb];
          pf = gv0[(1*4 + jl)*16 + bb];
          pg = gv0[(2*4 + jl)*16 + bb];
          po = gv0[(3*4 + jl)*16 + bb];
        }
        const float gi = gv[(jl*4+0)*16 + bb] + pi;
        const float gf = gv[(jl*4+1)*16 + bb] + pf;
        const float gg = gv[(jl*4+2)*16 + bb] + pg;
        const float go = gv[(jl*4+3)*16 + bb] + po;
        const float cn = fsigf(gf)*c0r + fsigf(gi)*ftanhf(gg);
        const float hn = fsigf(go)*ftanhf(cn);
        c0r = cn;
        st_sys(h0st + bb*DIM_ + j, hn);
      }
    }
    gridbar(bar, tid, blk, ep); ++ep;

    //====================== P3: gates1 Wih1@h0 + LSTM1 (+proj for attn blocks) ======================
    {
      { // stage h0 tile (waited batched)
        float4 r0,r1,r2,r3,r4,r5,r6,r7;
        ld8q_sys(h0st + tid*4, h0st + (tid+512)*4, h0st + (tid+1024)*4, h0st + (tid+1536)*4,
                 h0st + (tid+2048)*4, h0st + (tid+2560)*4, h0st + (tid+3072)*4, h0st + (tid+3584)*4,
                 r0,r1,r2,r3,r4,r5,r6,r7);
        *(float4*)(xt + ((tid       )>>8)*XST3 + ((tid       )&255)*4) = r0;
        *(float4*)(xt + ((tid + 512 )>>8)*XST3 + ((tid + 512 )&255)*4) = r1;
        *(float4*)(xt + ((tid + 1024)>>8)*XST3 + ((tid + 1024)&255)*4) = r2;
        *(float4*)(xt + ((tid + 1536)>>8)*XST3 + ((tid + 1536)&255)*4) = r3;
        *(float4*)(xt + ((tid + 2048)>>8)*XST3 + ((tid + 2048)&255)*4) = r4;
        *(float4*)(xt + ((tid + 2560)>>8)*XST3 + ((tid + 2560)&255)*4) = r5;
        *(float4*)(xt + ((tid + 3072)>>8)*XST3 + ((tid + 3072)&255)*4) = r6;
        *(float4*)(xt + ((tid + 3584)>>8)*XST3 + ((tid + 3584)&255)*4) = r7;
      }
      __syncthreads();
      float acc[4][8];
      #pragma unroll
      for (int ri = 0; ri < 4; ++ri)
        #pragma unroll
        for (int bi = 0; bi < 8; ++bi) acc[ri][bi] = 0.0f;
      #pragma unroll
      for (int q = 0; q < 4; ++q) {
        const int j = q*256 + ks*4;
        float4 w4[4];
        if (blk < B_) {
          #pragma unroll
          for (int ri = 0; ri < 4; ++ri)
            w4[ri] = *(const float4*)(Wih1 + (ri*1024 + j0 + rg)*1024 + j);
        } else {
          #pragma unroll
          for (int ri = 0; ri < 4; ++ri)
            w4[ri] = *(const float4*)(xt + WLDS + (((ri*4 + rg)*4 + q) << 8) + ks*4);
        }
        #pragma unroll
        for (int bi = 0; bi < 8; ++bi) {
          const float4 xv = *(const float4*)(xt + (bgb+bi)*XST3 + j);
          #pragma unroll
          for (int ri = 0; ri < 4; ++ri)
            acc[ri][bi] += w4[ri].x*xv.x + w4[ri].y*xv.y + w4[ri].z*xv.z + w4[ri].w*xv.w;
        }
      }
      #pragma unroll
      for (int ri = 0; ri < 4; ++ri)
        #pragma unroll
        for (int bi = 0; bi < 8; ++bi) {
          float v = acc[ri][bi];
          REDUCE64(v);
          if (ks == 63) gv[(rg*4 + ri)*16 + (bgb+bi)] = v;
        }
      __syncthreads();
      if (tid < 64) {
        const int jl = tid >> 4, bb = tid & 15;
        const int j = j0 + jl;
        float pi, pf, pg, po;
        if (blk < B_) {
          const float4 g4 = ld1q_sys(g1pre + bb*256 + j*4);
          pi = g4.x; pf = g4.y; pg = g4.z; po = g4.w;
        } else {
          pi = gv1[(0*4 + jl)*16 + bb];
          pf = gv1[(1*4 + jl)*16 + bb];
          pg = gv1[(2*4 + jl)*16 + bb];
          po = gv1[(3*4 + jl)*16 + bb];
        }
        const float gi = gv[(jl*4+0)*16 + bb] + pi;
        const float gf = gv[(jl*4+1)*16 + bb] + pf;
        const float gg = gv[(jl*4+2)*16 + bb] + pg;
        const float go = gv[(jl*4+3)*16 + bb] + po;
        const float cn = fsigf(gf)*c1r + fsigf(gi)*ftanhf(gg);
        const float hn = fsigf(go)*ftanhf(cn);
        c1r = cn;
        st_sys(h1buf + cur*B_*DIM_ + bb*DIM_ + j, hn);
      }
      // projection of step t-1 (attn blocks; inputs staged in projx during P1)
      if (blk < B_ && t > 0) {
        const int b = blk;
        const int o = tid >> 2, part = tid & 3;
        if (o < 81) {
          const float* w = projW + o*1536;
          const int jb = part*384;
          float acc2 = 0.0f;
          for (int j = jb; j < jb + 384; j += 4) {
            const float4 wv = *(const float4*)(w + j);
            const float4 xv = *(const float4*)(projx + j);
            acc2 += wv.x*xv.x + wv.y*xv.y + wv.z*xv.z + wv.w*xv.w;
          }
          spf[o*4 + part] = acc2;
        }
        __syncthreads();
        if (tid < 81) {
          const float v = projb[tid] + spf[tid*4] + spf[tid*4+1] + spf[tid*4+2] + spf[tid*4+3];
          if (tid < 80) out_mel[(b*NMEL_ + tid)*T_ + (t-1)] = v;
          else          out_stop[b*T_ + (t-1)] = v;
        }
      }
    }
    gridbar(bar, tid, blk, ep); ++ep;
  }

  // ---- tail projection for t = T_-1 (step-299 h1/align live in slot 0)
  if (blk < B_) {
    const int b = blk;
    if (tid < 256) {
      float4 v = ld1q_sys(h1buf + b*DIM_ + tid*4);
      *(float4*)(projx + tid*4) = v;
    } else if (tid < 384) {
      const int j = tid - 256;
      float4 v = ld1q_sys(albuf + b*ENC_ + j*4);
      *(float4*)(projx + 1024 + j*4) = v;
    }
    __syncthreads();
    const int o = tid >> 2, part = tid & 3;
    if (o < 81) {
      const float* w = projW + o*1536;
      const int jb = part*384;
      float acc = 0.0f;
      for (int j = jb; j < jb + 384; j += 4) {
        const float4 wv = *(const float4*)(w + j);
        const float4 xv = *(const float4*)(projx + j);
        acc += wv.x*xv.x + wv.y*xv.y + wv.z*xv.z + wv.w*xv.w;
      }
      spf[o*4 + part] = acc;
    }
    __syncthreads();
    if (tid < 81) {
      const float v = projb[tid] + spf[tid*4] + spf[tid*4+1] + spf[tid*4+2] + spf[tid*4+3];
      if (tid < 80) out_mel[(b*NMEL_ + tid)*T_ + (T_-1)] = v;
      else          out_stop[b*T_ + (T_-1)] = v;
    }
  }
}

extern "C" void kernel_launch(void* const* d_in, const int* in_sizes, int n_in,
                              void* d_out, int out_size, void* d_ws, size_t ws_size,
                              hipStream_t stream) {
  const float* mels  = (const float*)d_in[0];
  const float* enc   = (const float*)d_in[1];
  const int*   tlen  = (const int*)d_in[2];
  const float* Wt    = (const float*)d_in[3];
  const float* Wq    = (const float*)d_in[4];
  const float* wsc   = (const float*)d_in[5];
  const float* conv1 = (const float*)d_in[6];
  const float* conv2 = (const float*)d_in[7];
  const float* pW1   = (const float*)d_in[8];
  const float* pb1   = (const float*)d_in[9];
  const float* pW2   = (const float*)d_in[10];
  const float* pb2   = (const float*)d_in[11];
  const float* Wih0  = (const float*)d_in[12];
  const float* Whh0  = (const float*)d_in[13];
  const float* bih0  = (const float*)d_in[14];
  const float* bhh0  = (const float*)d_in[15];
  const float* Wih1  = (const float*)d_in[16];
  const float* Whh1  = (const float*)d_in[17];
  const float* bih1  = (const float*)d_in[18];
  const float* bhh1  = (const float*)d_in[19];
  const float* h0    = (const float*)d_in[20];
  const float* c0    = (const float*)d_in[21];
  const float* projW = (const float*)d_in[22];
  const float* projb = (const float*)d_in[23];

  float* ws     = (float*)d_ws;
  float* melpre = ws;                  // 300*16*256   = 1228800
  float* lencb  = melpre + 1228800;    // 16*160*128   = 327680
  float* weff   = lencb + 327680;      // 128*32       = 4096
  float* h1buf  = weff + 4096;         // 2*16*1024    = 32768
  float* albuf  = h1buf + 32768;       // 2*16*512     = 16384
  float* h0st   = albuf + 16384;       // 16*1024      = 16384
  float* g0pre  = h0st + 16384;        // 16*256       = 4096
  float* g1pre  = g0pre + 4096;        // 16*256       = 4096
  u32*   bar    = (u32*)(g1pre + 4096);// 17408 words

  float* out_mel  = (float*)d_out;
  float* out_stop = out_mel + 384000;
  float* out_attn = out_stop + 4800;

  prenet_kernel<<<dim3(480), dim3(256), 0, stream>>>(mels, pW1, pb1, pW2, pb2, melpre);
  init_kernel<<<dim3(160), dim3(256), 0, stream>>>(h0, conv1, conv2, h1buf, h0st, weff, bar);
  lenc_kernel<<<dim3(640), dim3(256), 0, stream>>>(enc, Wt, lencb);

  void* args[] = {
    (void*)&melpre, (void*)&lencb, (void*)&weff, (void*)&h1buf, (void*)&albuf, (void*)&h0st,
    (void*)&g0pre, (void*)&g1pre, (void*)&bar,
    (void*)&enc, (void*)&tlen, (void*)&Wq, (void*)&wsc,
    (void*)&Wih0, (void*)&Whh0, (void*)&bih0, (void*)&bhh0,
    (void*)&Wih1, (void*)&Whh1, (void*)&bih1, (void*)&bhh1,
    (void*)&c0, (void*)&projW, (void*)&projb,
    (void*)&out_mel, (void*)&out_stop, (void*)&out_attn
  };
  hipLaunchCooperativeKernel((const void*)decoder_kernel, dim3(256), dim3(512),
                             args, (unsigned int)(XTOT*sizeof(float)), stream);
}

// Round 8
// 44839.722 us; speedup vs baseline: 1.0731x; 1.0484x over previous
//
#include <hip/hip_runtime.h>

#define T_    300
#define B_    16
#define S_    160
#define NMEL_ 80
#define PRE_  256
#define ENC_  512
#define ATT_  128
#define DIM_  1024

#define XST1  1288     // P1 tile stride (mel 256 + h0 1024 + pad 8); rows end at 20600
#define XST2  520      // P2 align tile stride (ends 8320)
#define XST3  1032     // P3 h0 tile stride (ends 16504)
#define AOFF  16512    // attn blocks: persistent arrays (cum_p, projx, wscs) — above staging
#define WLDS  20608    // compute blocks: pinned bf16 Wih1+Whh1 (2 x 16 rows x 1024 = 64 KB)
#define XTOT  36992    // dynamic LDS floats (148 KB)
#define BARWORDS 17408

typedef unsigned int u32;
typedef unsigned short u16;

__device__ __forceinline__ float fexp2f(float x) { return __builtin_amdgcn_exp2f(x); }
__device__ __forceinline__ float fsigf(float x)  { return 1.0f / (1.0f + fexp2f(-1.442695041f * x)); }
__device__ __forceinline__ float ftanhf(float x) {
  float xc = fminf(fmaxf(x, -15.0f), 15.0f);
  float e = fexp2f(2.885390082f * xc);
  return (e - 1.0f) / (e + 1.0f);
}

// ---- bf16 helpers. Weights-only bf16 with RNE conversion (unbiased); the
// upper-half elements unpack with a single AND (bf16 == high half of fp32).
__device__ __forceinline__ u16 f2bf(float f) {
  u32 b = __float_as_uint(f);
  return (u16)((b + 0x7fffu + ((b >> 16) & 1u)) >> 16);
}
__device__ __forceinline__ float4 bf4(const u16* p) {
  const uint2 u = *(const uint2*)p;
  float4 w;
  w.x = __uint_as_float(u.x << 16);
  w.y = __uint_as_float(u.x & 0xffff0000u);
  w.z = __uint_as_float(u.y << 16);
  w.w = __uint_as_float(u.y & 0xffff0000u);
  return w;
}

// ---- system-scope (LLC) accessors. waitcnt lives INSIDE each asm block so the
// register allocator never sees a pending-load destination (R3 bug).
__device__ __forceinline__ float4 ld1q_sys(const float* p) {
  float4 v;
  asm volatile("global_load_dwordx4 %0, %1, off sc0 sc1\n\ts_waitcnt vmcnt(0)"
               : "=v"(v) : "v"(p) : "memory");
  return v;
}
__device__ __forceinline__ void ld4q_sys(const float* p0, const float* p1,
                                         const float* p2, const float* p3,
                                         float4& a, float4& b, float4& c, float4& d) {
  asm volatile(
      "global_load_dwordx4 %0, %4, off sc0 sc1\n\t"
      "global_load_dwordx4 %1, %5, off sc0 sc1\n\t"
      "global_load_dwordx4 %2, %6, off sc0 sc1\n\t"
      "global_load_dwordx4 %3, %7, off sc0 sc1\n\t"
      "s_waitcnt vmcnt(0)"
      : "=&v"(a), "=&v"(b), "=&v"(c), "=&v"(d)
      : "v"(p0), "v"(p1), "v"(p2), "v"(p3) : "memory");
}
__device__ __forceinline__ void ld8q_sys(const float* p0,const float* p1,const float* p2,const float* p3,
                                         const float* p4,const float* p5,const float* p6,const float* p7,
                                         float4& a,float4& b,float4& c,float4& d,
                                         float4& e,float4& f,float4& g,float4& h) {
  asm volatile(
      "global_load_dwordx4 %0, %8, off sc0 sc1\n\t"
      "global_load_dwordx4 %1, %9, off sc0 sc1\n\t"
      "global_load_dwordx4 %2, %10, off sc0 sc1\n\t"
      "global_load_dwordx4 %3, %11, off sc0 sc1\n\t"
      "global_load_dwordx4 %4, %12, off sc0 sc1\n\t"
      "global_load_dwordx4 %5, %13, off sc0 sc1\n\t"
      "global_load_dwordx4 %6, %14, off sc0 sc1\n\t"
      "global_load_dwordx4 %7, %15, off sc0 sc1\n\t"
      "s_waitcnt vmcnt(0)"
      : "=&v"(a),"=&v"(b),"=&v"(c),"=&v"(d),"=&v"(e),"=&v"(f),"=&v"(g),"=&v"(h)
      : "v"(p0),"v"(p1),"v"(p2),"v"(p3),"v"(p4),"v"(p5),"v"(p6),"v"(p7)
      : "memory");
}
__device__ __forceinline__ void st_sys(float* p, float v) {
  asm volatile("global_store_dword %0, %1, off sc0 sc1" :: "v"(p), "v"(v) : "memory");
}
__device__ __forceinline__ u32 ld_sys_u32(const u32* p) {
  u32 r;
  asm volatile("global_load_dword %0, %1, off sc0 sc1\n\ts_waitcnt vmcnt(0)"
               : "=v"(r) : "v"(p) : "memory");
  return r;
}
__device__ __forceinline__ void st_sys_u32(u32* p, u32 v) {
  asm volatile("global_store_dword %0, %1, off sc0 sc1" :: "v"(p), "v"(v) : "memory");
}

// ---- tree-arrival / wide-release barrier: 16 groups x 16 blocks arrival;
// top releaser writes 16 per-group release words (<=16 pollers per line).
__device__ __forceinline__ void gridbar(u32* bar, int tid, int blk, u32 ep) {
  asm volatile("s_waitcnt vmcnt(0)" ::: "memory");   // drain this wave's sc stores
  __syncthreads();
  if (tid == 0) {
    const int g = blk & 15;
    u32* cnt  = bar + g*1024;
    u32* grel = bar + g*1024 + 64;
    u32* tcnt = bar + 16384;
    const u32 tgt = ep*16u + 15u;
    u32 old = __hip_atomic_fetch_add(cnt, 1u, __ATOMIC_RELAXED, __HIP_MEMORY_SCOPE_AGENT);
    if (old == tgt) {
      u32 told = __hip_atomic_fetch_add(tcnt, 1u, __ATOMIC_RELAXED, __HIP_MEMORY_SCOPE_AGENT);
      if (told == tgt) {
        #pragma unroll
        for (int g2 = 0; g2 < 16; ++g2) st_sys_u32(bar + g2*1024 + 64, ep + 1u);
      } else {
        while (ld_sys_u32(grel) != ep + 1u) __builtin_amdgcn_s_sleep(1);
      }
    } else {
      while (ld_sys_u32(grel) != ep + 1u) __builtin_amdgcn_s_sleep(1);
    }
  }
  __syncthreads();
}

// ---- wave-64 sum via DPP (VALU pipe, zero DS ops).
#define DPP_ADD(v, ctrl, rmask) do { \
  int _t = __builtin_amdgcn_update_dpp(0, __float_as_int(v), (ctrl), (rmask), 0xf, false); \
  (v) += __int_as_float(_t); } while (0)

#define REDUCE64(v) do { \
  DPP_ADD(v, 0x111, 0xf); \
  DPP_ADD(v, 0x112, 0xf); \
  DPP_ADD(v, 0x114, 0xf); \
  DPP_ADD(v, 0x118, 0xf); \
  DPP_ADD(v, 0x142, 0xa); \
  DPP_ADD(v, 0x143, 0x8); } while (0)

// ---------------- prenet
__launch_bounds__(256)
__global__ void prenet_kernel(const float* __restrict__ mels,
                              const float* __restrict__ pW1, const float* __restrict__ pb1,
                              const float* __restrict__ pW2, const float* __restrict__ pb2,
                              float* __restrict__ melpre) {
  __shared__ float mcol[NMEL_];
  __shared__ float pcol[PRE_];
  const int b = blockIdx.x / 30;
  const int tbase = (blockIdx.x % 30) * 10;
  const int tid = threadIdx.x;
  for (int f = 0; f < 10; ++f) {
    const int t = tbase + f;
    if (tid < NMEL_) mcol[tid] = (t == 0) ? 0.0f : mels[(b*NMEL_ + tid)*T_ + (t-1)];
    __syncthreads();
    {
      float a1 = pb1[tid];
      const float* w1 = pW1 + tid*NMEL_;
      for (int m = 0; m < NMEL_; ++m) a1 += w1[m]*mcol[m];
      pcol[tid] = fmaxf(a1, 0.0f);
    }
    __syncthreads();
    {
      float a2 = pb2[tid];
      const float* w2 = pW2 + tid*PRE_;
      for (int d = 0; d < PRE_; d += 4) {
        const float4 wv = *(const float4*)(w2 + d);
        a2 += wv.x*pcol[d] + wv.y*pcol[d+1] + wv.z*pcol[d+2] + wv.w*pcol[d+3];
      }
      melpre[(t*B_ + b)*PRE_ + tid] = fmaxf(a2, 0.0f);
    }
    __syncthreads();
  }
}

// ---------------- init: h states, Weff, barrier region
__launch_bounds__(256)
__global__ void init_kernel(const float* __restrict__ h0,
                            const float* __restrict__ conv1, const float* __restrict__ conv2,
                            float* __restrict__ h1buf, float* __restrict__ h0st,
                            float* __restrict__ weff, u32* __restrict__ bar) {
  const int idx = blockIdx.x*256 + threadIdx.x;
  if (idx < B_*DIM_) {
    const int j = idx & (DIM_-1);
    h0st[idx]  = h0[j];
    h1buf[idx] = h0[DIM_ + j];
  } else if (idx < B_*DIM_ + ATT_*32) {
    const int r = idx - B_*DIM_;
    const int a = r >> 5, k = r & 31;
    float acc = 0.0f;
    if (k < 31) {
      for (int l = 0; l < 32; ++l) acc += conv2[a*32 + l]*conv1[l*31 + k];
    }
    weff[r] = acc;   // row tap 31 stays exactly 0 (used as padded FMA tap)
  } else if (idx < B_*DIM_ + ATT_*32 + BARWORDS) {
    bar[idx - (B_*DIM_ + ATT_*32)] = 0u;
  }
}

// ---------------- weight conversion fp32 -> bf16 (RNE)
__launch_bounds__(256)
__global__ void wcvt_kernel(const float* __restrict__ Wih0, const float* __restrict__ Whh0,
                            const float* __restrict__ Wih1, const float* __restrict__ Whh1,
                            u16* __restrict__ Wih0h, u16* __restrict__ Whh0h,
                            u16* __restrict__ Wih1h, u16* __restrict__ Whh1h) {
  const int n0 = 4096*768, n1 = 4096*1024;
  const int stride = gridDim.x*256;
  for (int i = blockIdx.x*256 + threadIdx.x; i < n0; i += stride) Wih0h[i] = f2bf(Wih0[i]);
  for (int i = blockIdx.x*256 + threadIdx.x; i < n1; i += stride) {
    Whh0h[i] = f2bf(Whh0[i]);
    Wih1h[i] = f2bf(Wih1[i]);
    Whh1h[i] = f2bf(Whh1[i]);
  }
}

// ---------------- l_enc
__launch_bounds__(256)
__global__ void lenc_kernel(const float* __restrict__ enc, const float* __restrict__ Wt,
                            float* __restrict__ lencb) {
  __shared__ float es[4*ENC_];
  const int b = blockIdx.x / 40;
  const int s0 = (blockIdx.x % 40) * 4;
  const int tid = threadIdx.x;
  for (int idx = tid; idx < 4*ENC_; idx += 256) es[idx] = enc[(b*S_ + s0)*ENC_ + idx];
  __syncthreads();
  const int a = tid & 127, sh = tid >> 7;
  const float* w = Wt + a*ENC_;
  for (int p = 0; p < 2; ++p) {
    const int sl = sh*2 + p;
    const float* e = es + sl*ENC_;
    float acc = 0.0f;
    for (int j = 0; j < ENC_; j += 4) {
      const float4 wv = *(const float4*)(w + j);
      acc += wv.x*e[j] + wv.y*e[j+1] + wv.z*e[j+2] + wv.w*e[j+3];
    }
    lencb[(b*S_ + s0 + sl)*ATT_ + a] = acc;
  }
}

// ---------------- persistent decoder
// All four LSTM weight matrices are bf16 (RNE). Compute blocks pin their
// Wih1+Whh1 rows in 64 KB of LDS; the remaining streamed bf16 weights
// (Wih0-mel, Whh0, P2 align cols, proxy rows) have a per-XCD footprint of
// ~2.1 MB < 4 MB L2 -> L2-resident after step 1. This removes the ~63 MB/step
// fp32 weight stream over the L2<->L3 fabric that dominated the step time
// (FETCH_SIZE 24 GB/dispatch = 80 MB/step ~= the fp32 weight working set).
__launch_bounds__(512, 1)
__global__ void decoder_kernel(
    const float* __restrict__ melpre, const float* __restrict__ lencb,
    const float* __restrict__ weff,
    float* __restrict__ h1buf, float* __restrict__ albuf, float* __restrict__ h0st,
    float* __restrict__ g0pre, float* __restrict__ g1pre, u32* __restrict__ bar,
    const float* __restrict__ enc, const int* __restrict__ tlen,
    const float* __restrict__ Wq, const float* __restrict__ wsc,
    const u16* __restrict__ Wih0h, const u16* __restrict__ Whh0h,
    const u16* __restrict__ Wih1h, const u16* __restrict__ Whh1h,
    const float* __restrict__ bih0, const float* __restrict__ bhh0,
    const float* __restrict__ bih1, const float* __restrict__ bhh1,
    const float* __restrict__ c0in, const float* __restrict__ projW, const float* __restrict__ projb,
    float* __restrict__ out_mel, float* __restrict__ out_stop, float* __restrict__ out_attn)
{
  extern __shared__ float xt[];
  __shared__ float red_s[1];
  __shared__ float gv[256];    // P2/P3 GEMV reduction
  __shared__ float gv0[256];   // gates0 pre (own rows), persists P1->P2
  __shared__ float gv1[256];   // gates1 pre (own rows), persists P1->P3
  __shared__ float q_s[ATT_];
  __shared__ float spf[S_*4];  // P1 score partials; P3 proj partials
  __shared__ float score_s[S_];
  __shared__ float attn_s[S_];

  // attn-block persistent overlays in dynamic LDS, above P3 staging reach (16504)
  float* const cum_p = xt + AOFF;          // [190]
  float* const projx = xt + AOFF + 192;    // [1536]
  float* const wscs  = xt + AOFF + 1728;   // [128]
  u16* const wl = (u16*)(xt + WLDS);       // compute blocks: 128 chunks x 256 bf16

  const int blk = blockIdx.x;
  const int tid = threadIdx.x;
  const int ks = tid & 63;
  const int bgb = ((tid >> 6) & 1)*8;
  const int rg = tid >> 7;
  const int j0 = blk*4;

  float c0r = 0.0f, c1r = 0.0f;
  if (tid < 64) {
    const int j = j0 + (tid >> 4);
    c0r = c0in[j];
    c1r = c0in[DIM_ + j];
  }
  int mylen = 0;
  if (blk < B_) {
    mylen = tlen[blk];
    for (int i = tid; i < S_ + 30; i += 512) cum_p[i] = 0.0f;
    if (tid < ATT_) wscs[tid] = wsc[tid];
  } else {
    // pin this block's Wih1 (chunks 0..63) and Whh1 (chunks 64..127) rows,
    // bf16, chunked so lane ks reads chunk c at [c*256 + ks*4] (8B) in P3/GEMV-b.
    // chunk cm = (ri*4 + rg)*4 + q, row = ri*1024 + j0 + rg, cols q*256..+255.
    for (int i = tid; i < 8192; i += 512) {
      const int c = i >> 6, l = i & 63;
      const int m = c >> 6, cm = c & 63;
      const int ri = cm >> 4, rgw = (cm >> 2) & 3, q = cm & 3;
      const u16* src = (m ? Whh1h : Wih1h) + (ri*1024 + j0 + rgw)*1024 + q*256 + l*4;
      *(uint2*)(wl + c*256 + l*4) = *(const uint2*)src;
    }
  }
  __syncthreads();

  u32 ep = 0;

  for (int t = 0; t < T_; ++t) {
    const int prev = t & 1;
    const int cur = prev ^ 1;

    //====================== P1 ======================
    if (blk < B_) {
      const int b = blk;
      // stage [h1prev | alignprev] into projx (used for q now, proj in P3)
      if (tid < 256) {
        float4 v = ld1q_sys(h1buf + prev*B_*DIM_ + b*DIM_ + tid*4);
        *(float4*)(projx + tid*4) = v;
      } else if (tid < 384) {
        const int j = tid - 256;
        float4 v = ld1q_sys(albuf + prev*B_*ENC_ + b*ENC_ + j*4);
        *(float4*)(projx + 1024 + j*4) = v;
      }
      __syncthreads();
      // q = h1prev @ Wq^T
      {
        const int a = tid & 127, part = tid >> 7;
        const float* hp = projx + part*256;
        const float* wq = Wq + a*DIM_ + part*256;
        float acc = 0.0f;
        for (int j = 0; j < 256; j += 4) {
          const float4 wv = *(const float4*)(wq + j);
          const float4 hv = *(const float4*)(hp + j);
          acc += wv.x*hv.x + wv.y*hv.y + wv.z*hv.z + wv.w*hv.w;
        }
        spf[a*4 + part] = acc;
      }
      __syncthreads();
      if (tid < ATT_) q_s[tid] = spf[tid*4] + spf[tid*4+1] + spf[tid*4+2] + spf[tid*4+3];
      __syncthreads();
      // scores: loc-conv taps from GLOBAL weff (L1-resident, wave-uniform)
      {
        const int sl = tid & 127, ag = tid >> 7;
        const int a0 = ag*32;
        #pragma unroll
        for (int p = 0; p < 2; ++p) {
          const int s = sl + p*128;
          if (s < S_) {
            float cw[32];
            #pragma unroll
            for (int k = 0; k < 31; ++k) cw[k] = cum_p[s + k];
            cw[31] = 0.0f;
            const float* le = lencb + (b*S_ + s)*ATT_ + a0;
            const float* wr = weff + a0*32;
            float ps = 0.0f;
            for (int i4 = 0; i4 < 8; ++i4) {
              const float4 lev = *(const float4*)(le + i4*4);
              #pragma unroll
              for (int ii = 0; ii < 4; ++ii) {
                const int i = i4*4 + ii;
                const float4* wk4 = (const float4*)(wr + i*32);
                float loc = 0.0f;
                #pragma unroll
                for (int kq = 0; kq < 8; ++kq) {
                  const float4 wv = wk4[kq];
                  loc += wv.x*cw[kq*4+0] + wv.y*cw[kq*4+1] + wv.z*cw[kq*4+2] + wv.w*cw[kq*4+3];
                }
                const float lef = (ii==0)?lev.x:(ii==1)?lev.y:(ii==2)?lev.z:lev.w;
                ps += wscs[a0 + i]*ftanhf(q_s[a0 + i] + lef + loc);
              }
            }
            spf[s*4 + ag] = ps;
          }
        }
      }
      __syncthreads();
      if (tid < S_) {
        float sc = spf[tid*4] + spf[tid*4+1] + spf[tid*4+2] + spf[tid*4+3];
        if (tid >= mylen) sc = -1.0e30f;
        score_s[tid] = sc;
      }
      __syncthreads();
      if (tid < 64) {
        float m = -1.0e30f;
        for (int i = tid; i < S_; i += 64) m = fmaxf(m, score_s[i]);
        #pragma unroll
        for (int o = 32; o > 0; o >>= 1) m = fmaxf(m, __shfl_xor(m, o, 64));
        float sum = 0.0f;
        for (int i = tid; i < S_; i += 64) {
          const float e = fexp2f(1.442695041f*(score_s[i] - m));
          score_s[i] = e;
          sum += e;
        }
        #pragma unroll
        for (int o = 32; o > 0; o >>= 1) sum += __shfl_xor(sum, o, 64);
        if (tid == 0) red_s[0] = sum;
      }
      __syncthreads();
      {
        const float inv = 1.0f / red_s[0];
        if (tid < S_) {
          const float av = score_s[tid]*inv;
          attn_s[tid] = av;
          cum_p[15 + tid] += av;
          out_attn[(b*S_ + tid)*T_ + t] = av;
        }
      }
      __syncthreads();
      // align = attn @ enc  -> albuf[cur] (sc)
      {
        const float* eb = enc + (b*S_)*ENC_ + tid;
        float acc = 0.0f;
        for (int s = 0; s < S_; ++s) acc += attn_s[s]*eb[s*ENC_];
        st_sys(albuf + cur*B_*ENC_ + b*ENC_ + tid, acc);
      }
    } else {
      const bool hg0 = (blk >= 16 && blk < 80);
      const bool hg1 = (blk >= 80 && blk < 144);
      const int jx0 = blk - 16;
      const int jx1 = blk - 80;
      // ---- stage [mel | h0prev] tile
      for (int i = tid; i < 1024; i += 512) {
        float4 v = *(const float4*)(melpre + t*4096 + i*4);
        *(float4*)(xt + (i>>6)*XST1 + (i&63)*4) = v;
      }
      {
        float4 r0,r1,r2,r3,r4,r5,r6,r7;
        ld8q_sys(h0st + tid*4, h0st + (tid+512)*4, h0st + (tid+1024)*4, h0st + (tid+1536)*4,
                 h0st + (tid+2048)*4, h0st + (tid+2560)*4, h0st + (tid+3072)*4, h0st + (tid+3584)*4,
                 r0,r1,r2,r3,r4,r5,r6,r7);
        *(float4*)(xt + ((tid       )>>8)*XST1 + 256 + ((tid       )&255)*4) = r0;
        *(float4*)(xt + ((tid + 512 )>>8)*XST1 + 256 + ((tid + 512 )&255)*4) = r1;
        *(float4*)(xt + ((tid + 1024)>>8)*XST1 + 256 + ((tid + 1024)&255)*4) = r2;
        *(float4*)(xt + ((tid + 1536)>>8)*XST1 + 256 + ((tid + 1536)&255)*4) = r3;
        *(float4*)(xt + ((tid + 2048)>>8)*XST1 + 256 + ((tid + 2048)&255)*4) = r4;
        *(float4*)(xt + ((tid + 2560)>>8)*XST1 + 256 + ((tid + 2560)&255)*4) = r5;
        *(float4*)(xt + ((tid + 3072)>>8)*XST1 + 256 + ((tid + 3072)&255)*4) = r6;
        *(float4*)(xt + ((tid + 3584)>>8)*XST1 + 256 + ((tid + 3584)&255)*4) = r7;
      }
      __syncthreads();
      // ---- GEMV-a: gates0 pre = Wih0[:, :256]@mel + Whh0@h0prev (+biases), bf16 weights
      {
        const int nr = hg0 ? 5 : 4;
        int nrow[5];
        #pragma unroll
        for (int ri = 0; ri < 4; ++ri) nrow[ri] = ri*1024 + j0 + rg;
        nrow[4] = rg*1024 + ((jx0 < 64) ? jx0 : 0);
        float acc[5][8];
        #pragma unroll
        for (int ri = 0; ri < 5; ++ri)
          #pragma unroll
          for (int bi = 0; bi < 8; ++bi) acc[ri][bi] = 0.0f;
        { // mel chunk
          const int j = ks*4;
          float4 w4[5];
          #pragma unroll
          for (int ri = 0; ri < 5; ++ri)
            if (ri < nr) w4[ri] = bf4(Wih0h + nrow[ri]*768 + j);
          #pragma unroll
          for (int bi = 0; bi < 8; ++bi) {
            const float4 xv = *(const float4*)(xt + (bgb+bi)*XST1 + j);
            #pragma unroll
            for (int ri = 0; ri < 5; ++ri)
              if (ri < nr)
                acc[ri][bi] += w4[ri].x*xv.x + w4[ri].y*xv.y + w4[ri].z*xv.z + w4[ri].w*xv.w;
          }
        }
        #pragma unroll
        for (int q = 0; q < 4; ++q) { // h0 chunks
          const int j = q*256 + ks*4;
          float4 w4[5];
          #pragma unroll
          for (int ri = 0; ri < 5; ++ri)
            if (ri < nr) w4[ri] = bf4(Whh0h + nrow[ri]*1024 + j);
          #pragma unroll
          for (int bi = 0; bi < 8; ++bi) {
            const float4 xv = *(const float4*)(xt + (bgb+bi)*XST1 + 256 + j);
            #pragma unroll
            for (int ri = 0; ri < 5; ++ri)
              if (ri < nr)
                acc[ri][bi] += w4[ri].x*xv.x + w4[ri].y*xv.y + w4[ri].z*xv.z + w4[ri].w*xv.w;
          }
        }
        #pragma unroll
        for (int ri = 0; ri < 5; ++ri)
          if (ri < nr)
            #pragma unroll
            for (int bi = 0; bi < 8; ++bi) {
              float v = acc[ri][bi];
              REDUCE64(v);
              if (ks == 63) {
                const int n = nrow[ri];
                v += bih0[n] + bhh0[n];
                if (ri < 4) gv0[(ri*4 + rg)*16 + (bgb+bi)] = v;
                else        st_sys(g0pre + (bgb+bi)*256 + jx0*4 + rg, v);
              }
            }
      }
      __syncthreads();
      // ---- stage h1prev tile (waited batched LLC load)
      {
        const float* src = h1buf + prev*B_*DIM_;
        float4 r0,r1,r2,r3,r4,r5,r6,r7;
        ld8q_sys(src + tid*4, src + (tid+512)*4, src + (tid+1024)*4, src + (tid+1536)*4,
                 src + (tid+2048)*4, src + (tid+2560)*4, src + (tid+3072)*4, src + (tid+3584)*4,
                 r0,r1,r2,r3,r4,r5,r6,r7);
        *(float4*)(xt + ((tid       )>>8)*XST1 + ((tid       )&255)*4) = r0;
        *(float4*)(xt + ((tid + 512 )>>8)*XST1 + ((tid + 512 )&255)*4) = r1;
        *(float4*)(xt + ((tid + 1024)>>8)*XST1 + ((tid + 1024)&255)*4) = r2;
        *(float4*)(xt + ((tid + 1536)>>8)*XST1 + ((tid + 1536)&255)*4) = r3;
        *(float4*)(xt + ((tid + 2048)>>8)*XST1 + ((tid + 2048)&255)*4) = r4;
        *(float4*)(xt + ((tid + 2560)>>8)*XST1 + ((tid + 2560)&255)*4) = r5;
        *(float4*)(xt + ((tid + 3072)>>8)*XST1 + ((tid + 3072)&255)*4) = r6;
        *(float4*)(xt + ((tid + 3584)>>8)*XST1 + ((tid + 3584)&255)*4) = r7;
      }
      __syncthreads();
      // ---- GEMV-b: gates1 pre = Whh1@h1prev (+biases); rows 0..3 from LDS-pinned bf16
      {
        const int nr = hg1 ? 5 : 4;
        const int nprox = rg*1024 + (hg1 ? jx1 : 0);
        float acc[5][8];
        #pragma unroll
        for (int ri = 0; ri < 5; ++ri)
          #pragma unroll
          for (int bi = 0; bi < 8; ++bi) acc[ri][bi] = 0.0f;
        #pragma unroll
        for (int q = 0; q < 4; ++q) {
          const int j = q*256 + ks*4;
          float4 w4[5];
          #pragma unroll
          for (int ri = 0; ri < 4; ++ri)
            w4[ri] = bf4(wl + (64 + (ri*4 + rg)*4 + q)*256 + ks*4);
          if (nr == 5) w4[4] = bf4(Whh1h + nprox*1024 + j);
          #pragma unroll
          for (int bi = 0; bi < 8; ++bi) {
            const float4 xv = *(const float4*)(xt + (bgb+bi)*XST1 + j);
            #pragma unroll
            for (int ri = 0; ri < 5; ++ri)
              if (ri < nr)
                acc[ri][bi] += w4[ri].x*xv.x + w4[ri].y*xv.y + w4[ri].z*xv.z + w4[ri].w*xv.w;
          }
        }
        #pragma unroll
        for (int ri = 0; ri < 5; ++ri)
          if (ri < nr)
            #pragma unroll
            for (int bi = 0; bi < 8; ++bi) {
              float v = acc[ri][bi];
              REDUCE64(v);
              if (ks == 63) {
                const int n = (ri < 4) ? (ri*1024 + j0 + rg) : nprox;
                v += bih1[n] + bhh1[n];
                if (ri < 4) gv1[(ri*4 + rg)*16 + (bgb+bi)] = v;
                else        st_sys(g1pre + (bgb+bi)*256 + jx1*4 + rg, v);
              }
            }
      }
    }
    gridbar(bar, tid, blk, ep); ++ep;

    //====================== P2: gates0 align part + LSTM0 ======================
    {
      { // stage align tile (waited)
        const float* src = albuf + cur*B_*ENC_;
        float4 r0,r1,r2,r3;
        ld4q_sys(src + tid*4, src + (tid+512)*4, src + (tid+1024)*4, src + (tid+1536)*4,
                 r0,r1,r2,r3);
        *(float4*)(xt + ((tid       )>>7)*XST2 + ((tid       )&127)*4) = r0;
        *(float4*)(xt + ((tid + 512 )>>7)*XST2 + ((tid + 512 )&127)*4) = r1;
        *(float4*)(xt + ((tid + 1024)>>7)*XST2 + ((tid + 1024)&127)*4) = r2;
        *(float4*)(xt + ((tid + 1536)>>7)*XST2 + ((tid + 1536)&127)*4) = r3;
      }
      __syncthreads();
      float acc[4][8];
      #pragma unroll
      for (int ri = 0; ri < 4; ++ri)
        #pragma unroll
        for (int bi = 0; bi < 8; ++bi) acc[ri][bi] = 0.0f;
      #pragma unroll
      for (int q = 0; q < 2; ++q) {
        const int j = q*256 + ks*4;
        float4 w4[4];
        #pragma unroll
        for (int ri = 0; ri < 4; ++ri)
          w4[ri] = bf4(Wih0h + (ri*1024 + j0 + rg)*768 + 256 + j);
        #pragma unroll
        for (int bi = 0; bi < 8; ++bi) {
          const float4 xv = *(const float4*)(xt + (bgb+bi)*XST2 + j);
          #pragma unroll
          for (int ri = 0; ri < 4; ++ri)
            acc[ri][bi] += w4[ri].x*xv.x + w4[ri].y*xv.y + w4[ri].z*xv.z + w4[ri].w*xv.w;
        }
      }
      #pragma unroll
      for (int ri = 0; ri < 4; ++ri)
        #pragma unroll
        for (int bi = 0; bi < 8; ++bi) {
          float v = acc[ri][bi];
          REDUCE64(v);
          if (ks == 63) gv[(rg*4 + ri)*16 + (bgb+bi)] = v;
        }
      __syncthreads();
      if (tid < 64) {
        const int jl = tid >> 4, bb = tid & 15;
        const int j = j0 + jl;
        float pi, pf, pg, po;
        if (blk < B_) {
          const float4 g4 = ld1q_sys(g0pre + bb*256 + j*4);
          pi = g4.x; pf = g4.y; pg = g4.z; po = g4.w;
        } else {
          pi = gv0[(0*4 + jl)*16 + bb];
          pf = gv0[(1*4 + jl)*16 + bb];
          pg = gv0[(2*4 + jl)*16 + bb];
          po = gv0[(3*4 + jl)*16 + bb];
        }
        const float gi = gv[(jl*4+0)*16 + bb] + pi;
        const float gf = gv[(jl*4+1)*16 + bb] + pf;
        const float gg = gv[(jl*4+2)*16 + bb] + pg;
        const float go = gv[(jl*4+3)*16 + bb] + po;
        const float cn = fsigf(gf)*c0r + fsigf(gi)*ftanhf(gg);
        const float hn = fsigf(go)*ftanhf(cn);
        c0r = cn;
        st_sys(h0st + bb*DIM_ + j, hn);
      }
    }
    gridbar(bar, tid, blk, ep); ++ep;

    //====================== P3: gates1 Wih1@h0 + LSTM1 (+proj for attn blocks) ======================
    {
      { // stage h0 tile (waited batched)
        float4 r0,r1,r2,r3,r4,r5,r6,r7;
        ld8q_sys(h0st + tid*4, h0st + (tid+512)*4, h0st + (tid+1024)*4, h0st + (tid+1536)*4,
                 h0st + (tid+2048)*4, h0st + (tid+2560)*4, h0st + (tid+3072)*4, h0st + (tid+3584)*4,
                 r0,r1,r2,r3,r4,r5,r6,r7);
        *(float4*)(xt + ((tid       )>>8)*XST3 + ((tid       )&255)*4) = r0;
        *(float4*)(xt + ((tid + 512 )>>8)*XST3 + ((tid + 512 )&255)*4) = r1;
        *(float4*)(xt + ((tid + 1024)>>8)*XST3 + ((tid + 1024)&255)*4) = r2;
        *(float4*)(xt + ((tid + 1536)>>8)*XST3 + ((tid + 1536)&255)*4) = r3;
        *(float4*)(xt + ((tid + 2048)>>8)*XST3 + ((tid + 2048)&255)*4) = r4;
        *(float4*)(xt + ((tid + 2560)>>8)*XST3 + ((tid + 2560)&255)*4) = r5;
        *(float4*)(xt + ((tid + 3072)>>8)*XST3 + ((tid + 3072)&255)*4) = r6;
        *(float4*)(xt + ((tid + 3584)>>8)*XST3 + ((tid + 3584)&255)*4) = r7;
      }
      __syncthreads();
      float acc[4][8];
      #pragma unroll
      for (int ri = 0; ri < 4; ++ri)
        #pragma unroll
        for (int bi = 0; bi < 8; ++bi) acc[ri][bi] = 0.0f;
      #pragma unroll
      for (int q = 0; q < 4; ++q) {
        const int j = q*256 + ks*4;
        float4 w4[4];
        if (blk < B_) {
          #pragma unroll
          for (int ri = 0; ri < 4; ++ri)
            w4[ri] = bf4(Wih1h + (ri*1024 + j0 + rg)*1024 + j);
        } else {
          #pragma unroll
          for (int ri = 0; ri < 4; ++ri)
            w4[ri] = bf4(wl + (((ri*4 + rg)*4 + q) << 8) + ks*4);
        }
        #pragma unroll
        for (int bi = 0; bi < 8; ++bi) {
          const float4 xv = *(const float4*)(xt + (bgb+bi)*XST3 + j);
          #pragma unroll
          for (int ri = 0; ri < 4; ++ri)
            acc[ri][bi] += w4[ri].x*xv.x + w4[ri].y*xv.y + w4[ri].z*xv.z + w4[ri].w*xv.w;
        }
      }
      #pragma unroll
      for (int ri = 0; ri < 4; ++ri)
        #pragma unroll
        for (int bi = 0; bi < 8; ++bi) {
          float v = acc[ri][bi];
          REDUCE64(v);
          if (ks == 63) gv[(rg*4 + ri)*16 + (bgb+bi)] = v;
        }
      __syncthreads();
      if (tid < 64) {
        const int jl = tid >> 4, bb = tid & 15;
        const int j = j0 + jl;
        float pi, pf, pg, po;
        if (blk < B_) {
          const float4 g4 = ld1q_sys(g1pre + bb*256 + j*4);
          pi = g4.x; pf = g4.y; pg = g4.z; po = g4.w;
        } else {
          pi = gv1[(0*4 + jl)*16 + bb];
          pf = gv1[(1*4 + jl)*16 + bb];
          pg = gv1[(2*4 + jl)*16 + bb];
          po = gv1[(3*4 + jl)*16 + bb];
        }
        const float gi = gv[(jl*4+0)*16 + bb] + pi;
        const float gf = gv[(jl*4+1)*16 + bb] + pf;
        const float gg = gv[(jl*4+2)*16 + bb] + pg;
        const float go = gv[(jl*4+3)*16 + bb] + po;
        const float cn = fsigf(gf)*c1r + fsigf(gi)*ftanhf(gg);
        const float hn = fsigf(go)*ftanhf(cn);
        c1r = cn;
        st_sys(h1buf + cur*B_*DIM_ + bb*DIM_ + j, hn);
      }
      // projection of step t-1 (attn blocks; inputs staged in projx during P1)
      if (blk < B_ && t > 0) {
        const int b = blk;
        const int o = tid >> 2, part = tid & 3;
        if (o < 81) {
          const float* w = projW + o*1536;
          const int jb = part*384;
          float acc2 = 0.0f;
          for (int j = jb; j < jb + 384; j += 4) {
            const float4 wv = *(const float4*)(w + j);
            const float4 xv = *(const float4*)(projx + j);
            acc2 += wv.x*xv.x + wv.y*xv.y + wv.z*xv.z + wv.w*xv.w;
          }
          spf[o*4 + part] = acc2;
        }
        __syncthreads();
        if (tid < 81) {
          const float v = projb[tid] + spf[tid*4] + spf[tid*4+1] + spf[tid*4+2] + spf[tid*4+3];
          if (tid < 80) out_mel[(b*NMEL_ + tid)*T_ + (t-1)] = v;
          else          out_stop[b*T_ + (t-1)] = v;
        }
      }
    }
    gridbar(bar, tid, blk, ep); ++ep;
  }

  // ---- tail projection for t = T_-1 (step-299 h1/align live in slot 0)
  if (blk < B_) {
    const int b = blk;
    if (tid < 256) {
      float4 v = ld1q_sys(h1buf + b*DIM_ + tid*4);
      *(float4*)(projx + tid*4) = v;
    } else if (tid < 384) {
      const int j = tid - 256;
      float4 v = ld1q_sys(albuf + b*ENC_ + j*4);
      *(float4*)(projx + 1024 + j*4) = v;
    }
    __syncthreads();
    const int o = tid >> 2, part = tid & 3;
    if (o < 81) {
      const float* w = projW + o*1536;
      const int jb = part*384;
      float acc = 0.0f;
      for (int j = jb; j < jb + 384; j += 4) {
        const float4 wv = *(const float4*)(w + j);
        const float4 xv = *(const float4*)(projx + j);
        acc += wv.x*xv.x + wv.y*xv.y + wv.z*xv.z + wv.w*xv.w;
      }
      spf[o*4 + part] = acc;
    }
    __syncthreads();
    if (tid < 81) {
      const float v = projb[tid] + spf[tid*4] + spf[tid*4+1] + spf[tid*4+2] + spf[tid*4+3];
      if (tid < 80) out_mel[(b*NMEL_ + tid)*T_ + (T_-1)] = v;
      else          out_stop[b*T_ + (T_-1)] = v;
    }
  }
}

extern "C" void kernel_launch(void* const* d_in, const int* in_sizes, int n_in,
                              void* d_out, int out_size, void* d_ws, size_t ws_size,
                              hipStream_t stream) {
  const float* mels  = (const float*)d_in[0];
  const float* enc   = (const float*)d_in[1];
  const int*   tlen  = (const int*)d_in[2];
  const float* Wt    = (const float*)d_in[3];
  const float* Wq    = (const float*)d_in[4];
  const float* wsc   = (const float*)d_in[5];
  const float* conv1 = (const float*)d_in[6];
  const float* conv2 = (const float*)d_in[7];
  const float* pW1   = (const float*)d_in[8];
  const float* pb1   = (const float*)d_in[9];
  const float* pW2   = (const float*)d_in[10];
  const float* pb2   = (const float*)d_in[11];
  const float* Wih0  = (const float*)d_in[12];
  const float* Whh0  = (const float*)d_in[13];
  const float* bih0  = (const float*)d_in[14];
  const float* bhh0  = (const float*)d_in[15];
  const float* Wih1  = (const float*)d_in[16];
  const float* Whh1  = (const float*)d_in[17];
  const float* bih1  = (const float*)d_in[18];
  const float* bhh1  = (const float*)d_in[19];
  const float* h0    = (const float*)d_in[20];
  const float* c0    = (const float*)d_in[21];
  const float* projW = (const float*)d_in[22];
  const float* projb = (const float*)d_in[23];

  float* ws     = (float*)d_ws;
  float* melpre = ws;                  // 300*16*256   = 1228800
  float* lencb  = melpre + 1228800;    // 16*160*128   = 327680
  float* weff   = lencb + 327680;      // 128*32       = 4096
  float* h1buf  = weff + 4096;         // 2*16*1024    = 32768
  float* albuf  = h1buf + 32768;       // 2*16*512     = 16384
  float* h0st   = albuf + 16384;       // 16*1024      = 16384
  float* g0pre  = h0st + 16384;        // 16*256       = 4096
  float* g1pre  = g0pre + 4096;        // 16*256       = 4096
  u32*   bar    = (u32*)(g1pre + 4096);// 17408 words
  u16*   Wih0h  = (u16*)(bar + BARWORDS);      // 4096*768  bf16
  u16*   Whh0h  = Wih0h + 4096*768;            // 4096*1024 bf16
  u16*   Wih1h  = Whh0h + 4096*1024;           // 4096*1024 bf16
  u16*   Whh1h  = Wih1h + 4096*1024;           // 4096*1024 bf16  (~38 MB ws total)

  float* out_mel  = (float*)d_out;
  float* out_stop = out_mel + 384000;
  float* out_attn = out_stop + 4800;

  prenet_kernel<<<dim3(480), dim3(256), 0, stream>>>(mels, pW1, pb1, pW2, pb2, melpre);
  init_kernel<<<dim3(160), dim3(256), 0, stream>>>(h0, conv1, conv2, h1buf, h0st, weff, bar);
  wcvt_kernel<<<dim3(2048), dim3(256), 0, stream>>>(Wih0, Whh0, Wih1, Whh1,
                                                    Wih0h, Whh0h, Wih1h, Whh1h);
  lenc_kernel<<<dim3(640), dim3(256), 0, stream>>>(enc, Wt, lencb);

  void* args[] = {
    (void*)&melpre, (void*)&lencb, (void*)&weff, (void*)&h1buf, (void*)&albuf, (void*)&h0st,
    (void*)&g0pre, (void*)&g1pre, (void*)&bar,
    (void*)&enc, (void*)&tlen, (void*)&Wq, (void*)&wsc,
    (void*)&Wih0h, (void*)&Whh0h, (void*)&Wih1h, (void*)&Whh1h,
    (void*)&bih0, (void*)&bhh0, (void*)&bih1, (void*)&bhh1,
    (void*)&c0, (void*)&projW, (void*)&projb,
    (void*)&out_mel, (void*)&out_stop, (void*)&out_attn
  };
  hipLaunchCooperativeKernel((const void*)decoder_kernel, dim3(256), dim3(512),
                             args, (unsigned int)(XTOT*sizeof(float)), stream);
}

// Round 9
// 41716.266 us; speedup vs baseline: 1.1535x; 1.0749x over previous
//
#include <hip/hip_runtime.h>

#define T_    300
#define B_    16
#define S_    160
#define NMEL_ 80
#define PRE_  256
#define ENC_  512
#define ATT_  128
#define DIM_  1024

#define XST1  1288     // P1 tile stride (mel 256 + h0 1024 + pad 8); rows end at 20600
#define XST2  520      // P2 align tile stride (ends 8320)
#define XST3  1032     // P3 h0 tile stride (ends 16504)
#define AOFF  16512    // attn blocks: persistent arrays (cum_p, projx, wscs) — above staging
#define WLDS  20608    // compute blocks: pinned bf16 Wih1+Whh1 (2 x 16 rows x 1024 = 64 KB)
#define XTOT  36992    // dynamic LDS floats (148 KB)
#define BARWORDS 17408

// rotation depths: every step writes a FRESH slot so consumer L2/L1 lines are
// cold -> plain cached reads pull fresh data from LLC (where sc1 stores land);
// 32 blocks/XCD then share one L2 copy instead of 32 LLC round-trips each.
#define HSLOT (B_*DIM_)   // 16384 floats / slot (h0st, h1buf)
#define ASLOT (B_*ENC_)   // 8192 floats / slot (albuf)

typedef unsigned int u32;
typedef unsigned short u16;

__device__ __forceinline__ float fexp2f(float x) { return __builtin_amdgcn_exp2f(x); }
__device__ __forceinline__ float fsigf(float x)  { return 1.0f / (1.0f + fexp2f(-1.442695041f * x)); }
__device__ __forceinline__ float ftanhf(float x) {
  float xc = fminf(fmaxf(x, -15.0f), 15.0f);
  float e = fexp2f(2.885390082f * xc);
  return (e - 1.0f) / (e + 1.0f);
}

// ---- bf16 helpers (weights-only bf16, RNE).
__device__ __forceinline__ u16 f2bf(float f) {
  u32 b = __float_as_uint(f);
  return (u16)((b + 0x7fffu + ((b >> 16) & 1u)) >> 16);
}
__device__ __forceinline__ float4 bf4(const u16* p) {
  const uint2 u = *(const uint2*)p;
  float4 w;
  w.x = __uint_as_float(u.x << 16);
  w.y = __uint_as_float(u.x & 0xffff0000u);
  w.z = __uint_as_float(u.y << 16);
  w.w = __uint_as_float(u.y & 0xffff0000u);
  return w;
}

// ---- system-scope (LLC) accessors: WRITES must be sc1 (visible at LLC for
// other XCDs' cold-miss reads); barrier words must be sc both ways.
__device__ __forceinline__ float4 ld1q_sys(const float* p) {
  float4 v;
  asm volatile("global_load_dwordx4 %0, %1, off sc0 sc1\n\ts_waitcnt vmcnt(0)"
               : "=v"(v) : "v"(p) : "memory");
  return v;
}
__device__ __forceinline__ void st_sys(float* p, float v) {
  asm volatile("global_store_dword %0, %1, off sc0 sc1" :: "v"(p), "v"(v) : "memory");
}
__device__ __forceinline__ u32 ld_sys_u32(const u32* p) {
  u32 r;
  asm volatile("global_load_dword %0, %1, off sc0 sc1\n\ts_waitcnt vmcnt(0)"
               : "=v"(r) : "v"(p) : "memory");
  return r;
}
__device__ __forceinline__ void st_sys_u32(u32* p, u32 v) {
  asm volatile("global_store_dword %0, %1, off sc0 sc1" :: "v"(p), "v"(v) : "memory");
}

// ---- tree-arrival / wide-release barrier: 16 groups x 16 blocks arrival;
// top releaser writes 16 per-group release words (<=16 pollers per line).
__device__ __forceinline__ void gridbar(u32* bar, int tid, int blk, u32 ep) {
  asm volatile("s_waitcnt vmcnt(0)" ::: "memory");   // drain this wave's sc stores
  __syncthreads();
  if (tid == 0) {
    const int g = blk & 15;
    u32* cnt  = bar + g*1024;
    u32* grel = bar + g*1024 + 64;
    u32* tcnt = bar + 16384;
    const u32 tgt = ep*16u + 15u;
    u32 old = __hip_atomic_fetch_add(cnt, 1u, __ATOMIC_RELAXED, __HIP_MEMORY_SCOPE_AGENT);
    if (old == tgt) {
      u32 told = __hip_atomic_fetch_add(tcnt, 1u, __ATOMIC_RELAXED, __HIP_MEMORY_SCOPE_AGENT);
      if (told == tgt) {
        #pragma unroll
        for (int g2 = 0; g2 < 16; ++g2) st_sys_u32(bar + g2*1024 + 64, ep + 1u);
      } else {
        while (ld_sys_u32(grel) != ep + 1u) __builtin_amdgcn_s_sleep(1);
      }
    } else {
      while (ld_sys_u32(grel) != ep + 1u) __builtin_amdgcn_s_sleep(1);
    }
  }
  __syncthreads();
}

// ---- wave-64 sum via DPP (VALU pipe, zero DS ops).
#define DPP_ADD(v, ctrl, rmask) do { \
  int _t = __builtin_amdgcn_update_dpp(0, __float_as_int(v), (ctrl), (rmask), 0xf, false); \
  (v) += __int_as_float(_t); } while (0)

#define REDUCE64(v) do { \
  DPP_ADD(v, 0x111, 0xf); \
  DPP_ADD(v, 0x112, 0xf); \
  DPP_ADD(v, 0x114, 0xf); \
  DPP_ADD(v, 0x118, 0xf); \
  DPP_ADD(v, 0x142, 0xa); \
  DPP_ADD(v, 0x143, 0x8); } while (0)

// ---------------- prenet
__launch_bounds__(256)
__global__ void prenet_kernel(const float* __restrict__ mels,
                              const float* __restrict__ pW1, const float* __restrict__ pb1,
                              const float* __restrict__ pW2, const float* __restrict__ pb2,
                              float* __restrict__ melpre) {
  __shared__ float mcol[NMEL_];
  __shared__ float pcol[PRE_];
  const int b = blockIdx.x / 30;
  const int tbase = (blockIdx.x % 30) * 10;
  const int tid = threadIdx.x;
  for (int f = 0; f < 10; ++f) {
    const int t = tbase + f;
    if (tid < NMEL_) mcol[tid] = (t == 0) ? 0.0f : mels[(b*NMEL_ + tid)*T_ + (t-1)];
    __syncthreads();
    {
      float a1 = pb1[tid];
      const float* w1 = pW1 + tid*NMEL_;
      for (int m = 0; m < NMEL_; ++m) a1 += w1[m]*mcol[m];
      pcol[tid] = fmaxf(a1, 0.0f);
    }
    __syncthreads();
    {
      float a2 = pb2[tid];
      const float* w2 = pW2 + tid*PRE_;
      for (int d = 0; d < PRE_; d += 4) {
        const float4 wv = *(const float4*)(w2 + d);
        a2 += wv.x*pcol[d] + wv.y*pcol[d+1] + wv.z*pcol[d+2] + wv.w*pcol[d+3];
      }
      melpre[(t*B_ + b)*PRE_ + tid] = fmaxf(a2, 0.0f);
    }
    __syncthreads();
  }
}

// ---------------- init: h states (slot 0), Weff, barrier region
__launch_bounds__(256)
__global__ void init_kernel(const float* __restrict__ h0,
                            const float* __restrict__ conv1, const float* __restrict__ conv2,
                            float* __restrict__ h1buf, float* __restrict__ h0st,
                            float* __restrict__ weff, u32* __restrict__ bar) {
  const int idx = blockIdx.x*256 + threadIdx.x;
  if (idx < B_*DIM_) {
    const int j = idx & (DIM_-1);
    h0st[idx]  = h0[j];
    h1buf[idx] = h0[DIM_ + j];
  } else if (idx < B_*DIM_ + ATT_*32) {
    const int r = idx - B_*DIM_;
    const int a = r >> 5, k = r & 31;
    float acc = 0.0f;
    if (k < 31) {
      for (int l = 0; l < 32; ++l) acc += conv2[a*32 + l]*conv1[l*31 + k];
    }
    weff[r] = acc;   // row tap 31 stays exactly 0 (used as padded FMA tap)
  } else if (idx < B_*DIM_ + ATT_*32 + BARWORDS) {
    bar[idx - (B_*DIM_ + ATT_*32)] = 0u;
  }
}

// ---------------- weight conversion fp32 -> bf16 (RNE)
__launch_bounds__(256)
__global__ void wcvt_kernel(const float* __restrict__ Wih0, const float* __restrict__ Whh0,
                            const float* __restrict__ Wih1, const float* __restrict__ Whh1,
                            u16* __restrict__ Wih0h, u16* __restrict__ Whh0h,
                            u16* __restrict__ Wih1h, u16* __restrict__ Whh1h) {
  const int n0 = 4096*768, n1 = 4096*1024;
  const int stride = gridDim.x*256;
  for (int i = blockIdx.x*256 + threadIdx.x; i < n0; i += stride) Wih0h[i] = f2bf(Wih0[i]);
  for (int i = blockIdx.x*256 + threadIdx.x; i < n1; i += stride) {
    Whh0h[i] = f2bf(Whh0[i]);
    Wih1h[i] = f2bf(Wih1[i]);
    Whh1h[i] = f2bf(Whh1[i]);
  }
}

// ---------------- l_enc
__launch_bounds__(256)
__global__ void lenc_kernel(const float* __restrict__ enc, const float* __restrict__ Wt,
                            float* __restrict__ lencb) {
  __shared__ float es[4*ENC_];
  const int b = blockIdx.x / 40;
  const int s0 = (blockIdx.x % 40) * 4;
  const int tid = threadIdx.x;
  for (int idx = tid; idx < 4*ENC_; idx += 256) es[idx] = enc[(b*S_ + s0)*ENC_ + idx];
  __syncthreads();
  const int a = tid & 127, sh = tid >> 7;
  const float* w = Wt + a*ENC_;
  for (int p = 0; p < 2; ++p) {
    const int sl = sh*2 + p;
    const float* e = es + sl*ENC_;
    float acc = 0.0f;
    for (int j = 0; j < ENC_; j += 4) {
      const float4 wv = *(const float4*)(w + j);
      acc += wv.x*e[j] + wv.y*e[j+1] + wv.z*e[j+2] + wv.w*e[j+3];
    }
    lencb[(b*S_ + s0 + sl)*ATT_ + a] = acc;
  }
}

// ---------------- persistent decoder
// State (h0st/h1buf/albuf) rotates: step t writes slot t+1 (albuf: slot t) via
// sc1 stores (LLC-visible); readers use PLAIN cached loads — slot addresses are
// cold in every consumer L1/L2, so the first reader per XCD cold-misses to the
// LLC and caches the line; the other 31 blocks on that XCD hit L2. This removes
// the 57 MB/step system-scope staging stream (= FETCH_SIZE wall in r8).
// GEMV-a/b are batch-split into two halves (acc[5][4]) to fit 128 VGPR without
// scratch spills (r8 WRITE_SIZE = 22 MB/step of spill stores).
__launch_bounds__(512, 1)
__global__ void decoder_kernel(
    const float* __restrict__ melpre, const float* __restrict__ lencb,
    const float* __restrict__ weff,
    float* __restrict__ h1buf, float* __restrict__ albuf, float* __restrict__ h0st,
    float* __restrict__ g0pre, float* __restrict__ g1pre, u32* __restrict__ bar,
    const float* __restrict__ enc, const int* __restrict__ tlen,
    const float* __restrict__ Wq, const float* __restrict__ wsc,
    const u16* __restrict__ Wih0h, const u16* __restrict__ Whh0h,
    const u16* __restrict__ Wih1h, const u16* __restrict__ Whh1h,
    const float* __restrict__ bih0, const float* __restrict__ bhh0,
    const float* __restrict__ bih1, const float* __restrict__ bhh1,
    const float* __restrict__ c0in, const float* __restrict__ projW, const float* __restrict__ projb,
    float* __restrict__ out_mel, float* __restrict__ out_stop, float* __restrict__ out_attn)
{
  extern __shared__ float xt[];
  __shared__ float red_s[1];
  __shared__ float gv[256];    // P2/P3 GEMV reduction
  __shared__ float gv0[256];   // gates0 pre (own rows), persists P1->P2
  __shared__ float gv1[256];   // gates1 pre (own rows), persists P1->P3
  __shared__ float q_s[ATT_];
  __shared__ float spf[S_*4];  // P1 score partials; P3 proj partials
  __shared__ float score_s[S_];
  __shared__ float attn_s[S_];

  // attn-block persistent overlays in dynamic LDS, above P3 staging reach (16504)
  float* const cum_p = xt + AOFF;          // [190]
  float* const projx = xt + AOFF + 192;    // [1536]
  float* const wscs  = xt + AOFF + 1728;   // [128]
  u16* const wl = (u16*)(xt + WLDS);       // compute blocks: 128 chunks x 256 bf16

  const int blk = blockIdx.x;
  const int tid = threadIdx.x;
  const int ks = tid & 63;
  const int bgb = ((tid >> 6) & 1)*8;
  const int rg = tid >> 7;
  const int j0 = blk*4;

  float c0r = 0.0f, c1r = 0.0f;
  if (tid < 64) {
    const int j = j0 + (tid >> 4);
    c0r = c0in[j];
    c1r = c0in[DIM_ + j];
  }
  int mylen = 0;
  if (blk < B_) {
    mylen = tlen[blk];
    for (int i = tid; i < S_ + 30; i += 512) cum_p[i] = 0.0f;
    if (tid < ATT_) wscs[tid] = wsc[tid];
  } else {
    // pin this block's Wih1 (chunks 0..63) and Whh1 (chunks 64..127) rows,
    // bf16, chunked so lane ks reads chunk c at [c*256 + ks*4] (8B).
    for (int i = tid; i < 8192; i += 512) {
      const int c = i >> 6, l = i & 63;
      const int m = c >> 6, cm = c & 63;
      const int ri = cm >> 4, rgw = (cm >> 2) & 3, q = cm & 3;
      const u16* src = (m ? Whh1h : Wih1h) + (ri*1024 + j0 + rgw)*1024 + q*256 + l*4;
      *(uint2*)(wl + c*256 + l*4) = *(const uint2*)src;
    }
  }
  __syncthreads();

  u32 ep = 0;

  for (int t = 0; t < T_; ++t) {
    //====================== P1 ======================
    if (blk < B_) {
      const int b = blk;
      // stage [h1(t) | align(t-1)] into projx (plain cached loads; slots cold)
      if (tid < 256) {
        *(float4*)(projx + tid*4) =
            *(const float4*)(h1buf + t*HSLOT + b*DIM_ + tid*4);
      } else if (tid < 384) {
        const int j = tid - 256;
        const int ap = (t > 0) ? (t-1) : 0;   // t=0 value unused (proj guarded)
        *(float4*)(projx + 1024 + j*4) =
            *(const float4*)(albuf + ap*ASLOT + b*ENC_ + j*4);
      }
      __syncthreads();
      // q = h1prev @ Wq^T
      {
        const int a = tid & 127, part = tid >> 7;
        const float* hp = projx + part*256;
        const float* wq = Wq + a*DIM_ + part*256;
        float acc = 0.0f;
        for (int j = 0; j < 256; j += 4) {
          const float4 wv = *(const float4*)(wq + j);
          const float4 hv = *(const float4*)(hp + j);
          acc += wv.x*hv.x + wv.y*hv.y + wv.z*hv.z + wv.w*hv.w;
        }
        spf[a*4 + part] = acc;
      }
      __syncthreads();
      if (tid < ATT_) q_s[tid] = spf[tid*4] + spf[tid*4+1] + spf[tid*4+2] + spf[tid*4+3];
      __syncthreads();
      // scores: loc-conv taps from GLOBAL weff (L1-resident, wave-uniform)
      {
        const int sl = tid & 127, ag = tid >> 7;
        const int a0 = ag*32;
        #pragma unroll
        for (int p = 0; p < 2; ++p) {
          const int s = sl + p*128;
          if (s < S_) {
            float cw[32];
            #pragma unroll
            for (int k = 0; k < 31; ++k) cw[k] = cum_p[s + k];
            cw[31] = 0.0f;
            const float* le = lencb + (b*S_ + s)*ATT_ + a0;
            const float* wr = weff + a0*32;
            float ps = 0.0f;
            for (int i4 = 0; i4 < 8; ++i4) {
              const float4 lev = *(const float4*)(le + i4*4);
              #pragma unroll
              for (int ii = 0; ii < 4; ++ii) {
                const int i = i4*4 + ii;
                const float4* wk4 = (const float4*)(wr + i*32);
                float loc = 0.0f;
                #pragma unroll
                for (int kq = 0; kq < 8; ++kq) {
                  const float4 wv = wk4[kq];
                  loc += wv.x*cw[kq*4+0] + wv.y*cw[kq*4+1] + wv.z*cw[kq*4+2] + wv.w*cw[kq*4+3];
                }
                const float lef = (ii==0)?lev.x:(ii==1)?lev.y:(ii==2)?lev.z:lev.w;
                ps += wscs[a0 + i]*ftanhf(q_s[a0 + i] + lef + loc);
              }
            }
            spf[s*4 + ag] = ps;
          }
        }
      }
      __syncthreads();
      if (tid < S_) {
        float sc = spf[tid*4] + spf[tid*4+1] + spf[tid*4+2] + spf[tid*4+3];
        if (tid >= mylen) sc = -1.0e30f;
        score_s[tid] = sc;
      }
      __syncthreads();
      if (tid < 64) {
        float m = -1.0e30f;
        for (int i = tid; i < S_; i += 64) m = fmaxf(m, score_s[i]);
        #pragma unroll
        for (int o = 32; o > 0; o >>= 1) m = fmaxf(m, __shfl_xor(m, o, 64));
        float sum = 0.0f;
        for (int i = tid; i < S_; i += 64) {
          const float e = fexp2f(1.442695041f*(score_s[i] - m));
          score_s[i] = e;
          sum += e;
        }
        #pragma unroll
        for (int o = 32; o > 0; o >>= 1) sum += __shfl_xor(sum, o, 64);
        if (tid == 0) red_s[0] = sum;
      }
      __syncthreads();
      {
        const float inv = 1.0f / red_s[0];
        if (tid < S_) {
          const float av = score_s[tid]*inv;
          attn_s[tid] = av;
          cum_p[15 + tid] += av;
          out_attn[(b*S_ + tid)*T_ + t] = av;
        }
      }
      __syncthreads();
      // align = attn @ enc -> albuf slot t (sc1 write)
      {
        const float* eb = enc + (b*S_)*ENC_ + tid;
        float acc = 0.0f;
        for (int s = 0; s < S_; ++s) acc += attn_s[s]*eb[s*ENC_];
        st_sys(albuf + t*ASLOT + b*ENC_ + tid, acc);
      }
    } else {
      const bool hg0 = (blk >= 16 && blk < 80);
      const bool hg1 = (blk >= 80 && blk < 144);
      const int jx0 = blk - 16;
      const int jx1 = blk - 80;
      // ---- stage [mel | h0(t-1)=slot t] tile (plain loads; slot warm in this
      // XCD's L2 from P3 of step t-1)
      for (int i = tid; i < 1024; i += 512) {
        float4 v = *(const float4*)(melpre + t*4096 + i*4);
        *(float4*)(xt + (i>>6)*XST1 + (i&63)*4) = v;
      }
      {
        const float* src = h0st + t*HSLOT;
        float4 r[8];
        #pragma unroll
        for (int u = 0; u < 8; ++u) r[u] = *(const float4*)(src + (tid + u*512)*4);
        #pragma unroll
        for (int u = 0; u < 8; ++u) {
          const int i = tid + u*512;
          *(float4*)(xt + (i>>8)*XST1 + 256 + (i&255)*4) = r[u];
        }
      }
      __syncthreads();
      // ---- GEMV-a: gates0 pre = Wih0[:, :256]@mel + Whh0@h0prev (+biases)
      // batch-split into 2 halves of 4 to stay under 128 VGPR (no spills).
      {
        const int nr = hg0 ? 5 : 4;
        int nrow[5];
        #pragma unroll
        for (int ri = 0; ri < 4; ++ri) nrow[ri] = ri*1024 + j0 + rg;
        nrow[4] = rg*1024 + ((jx0 < 64) ? jx0 : 0);
        #pragma unroll
        for (int hf = 0; hf < 2; ++hf) {
          const int b0 = bgb + hf*4;
          float acc[5][4];
          #pragma unroll
          for (int ri = 0; ri < 5; ++ri)
            #pragma unroll
            for (int bi = 0; bi < 4; ++bi) acc[ri][bi] = 0.0f;
          { // mel chunk
            const int j = ks*4;
            float4 w4[5];
            #pragma unroll
            for (int ri = 0; ri < 5; ++ri)
              if (ri < nr) w4[ri] = bf4(Wih0h + nrow[ri]*768 + j);
            #pragma unroll
            for (int bi = 0; bi < 4; ++bi) {
              const float4 xv = *(const float4*)(xt + (b0+bi)*XST1 + j);
              #pragma unroll
              for (int ri = 0; ri < 5; ++ri)
                if (ri < nr)
                  acc[ri][bi] += w4[ri].x*xv.x + w4[ri].y*xv.y + w4[ri].z*xv.z + w4[ri].w*xv.w;
            }
          }
          #pragma unroll
          for (int q = 0; q < 4; ++q) { // h0 chunks
            const int j = q*256 + ks*4;
            float4 w4[5];
            #pragma unroll
            for (int ri = 0; ri < 5; ++ri)
              if (ri < nr) w4[ri] = bf4(Whh0h + nrow[ri]*1024 + j);
            #pragma unroll
            for (int bi = 0; bi < 4; ++bi) {
              const float4 xv = *(const float4*)(xt + (b0+bi)*XST1 + 256 + j);
              #pragma unroll
              for (int ri = 0; ri < 5; ++ri)
                if (ri < nr)
                  acc[ri][bi] += w4[ri].x*xv.x + w4[ri].y*xv.y + w4[ri].z*xv.z + w4[ri].w*xv.w;
            }
          }
          #pragma unroll
          for (int ri = 0; ri < 5; ++ri)
            if (ri < nr)
              #pragma unroll
              for (int bi = 0; bi < 4; ++bi) {
                float v = acc[ri][bi];
                REDUCE64(v);
                if (ks == 63) {
                  const int n = nrow[ri];
                  v += bih0[n] + bhh0[n];
                  if (ri < 4) gv0[(ri*4 + rg)*16 + (b0+bi)] = v;
                  else        st_sys(g0pre + (b0+bi)*256 + jx0*4 + rg, v);
                }
              }
        }
      }
      __syncthreads();
      // ---- stage h1(t) = slot t (plain loads)
      {
        const float* src = h1buf + t*HSLOT;
        float4 r[8];
        #pragma unroll
        for (int u = 0; u < 8; ++u) r[u] = *(const float4*)(src + (tid + u*512)*4);
        #pragma unroll
        for (int u = 0; u < 8; ++u) {
          const int i = tid + u*512;
          *(float4*)(xt + (i>>8)*XST1 + (i&255)*4) = r[u];
        }
      }
      __syncthreads();
      // ---- GEMV-b: gates1 pre = Whh1@h1prev (+biases); rows 0..3 from LDS bf16
      {
        const int nr = hg1 ? 5 : 4;
        const int nprox = rg*1024 + (hg1 ? jx1 : 0);
        #pragma unroll
        for (int hf = 0; hf < 2; ++hf) {
          const int b0 = bgb + hf*4;
          float acc[5][4];
          #pragma unroll
          for (int ri = 0; ri < 5; ++ri)
            #pragma unroll
            for (int bi = 0; bi < 4; ++bi) acc[ri][bi] = 0.0f;
          #pragma unroll
          for (int q = 0; q < 4; ++q) {
            const int j = q*256 + ks*4;
            float4 w4[5];
            #pragma unroll
            for (int ri = 0; ri < 4; ++ri)
              w4[ri] = bf4(wl + (64 + (ri*4 + rg)*4 + q)*256 + ks*4);
            if (nr == 5) w4[4] = bf4(Whh1h + nprox*1024 + j);
            #pragma unroll
            for (int bi = 0; bi < 4; ++bi) {
              const float4 xv = *(const float4*)(xt + (b0+bi)*XST1 + j);
              #pragma unroll
              for (int ri = 0; ri < 5; ++ri)
                if (ri < nr)
                  acc[ri][bi] += w4[ri].x*xv.x + w4[ri].y*xv.y + w4[ri].z*xv.z + w4[ri].w*xv.w;
            }
          }
          #pragma unroll
          for (int ri = 0; ri < 5; ++ri)
            if (ri < nr)
              #pragma unroll
              for (int bi = 0; bi < 4; ++bi) {
                float v = acc[ri][bi];
                REDUCE64(v);
                if (ks == 63) {
                  const int n = (ri < 4) ? (ri*1024 + j0 + rg) : nprox;
                  v += bih1[n] + bhh1[n];
                  if (ri < 4) gv1[(ri*4 + rg)*16 + (b0+bi)] = v;
                  else        st_sys(g1pre + (b0+bi)*256 + jx1*4 + rg, v);
                }
              }
        }
      }
    }
    gridbar(bar, tid, blk, ep); ++ep;

    //====================== P2: gates0 align part + LSTM0 ======================
    {
      { // stage align slot t (plain loads; cold -> LLC -> L2-shared)
        const float* src = albuf + t*ASLOT;
        float4 r[4];
        #pragma unroll
        for (int u = 0; u < 4; ++u) r[u] = *(const float4*)(src + (tid + u*512)*4);
        #pragma unroll
        for (int u = 0; u < 4; ++u) {
          const int i = tid + u*512;
          *(float4*)(xt + (i>>7)*XST2 + (i&127)*4) = r[u];
        }
      }
      __syncthreads();
      float acc[4][8];
      #pragma unroll
      for (int ri = 0; ri < 4; ++ri)
        #pragma unroll
        for (int bi = 0; bi < 8; ++bi) acc[ri][bi] = 0.0f;
      #pragma unroll
      for (int q = 0; q < 2; ++q) {
        const int j = q*256 + ks*4;
        float4 w4[4];
        #pragma unroll
        for (int ri = 0; ri < 4; ++ri)
          w4[ri] = bf4(Wih0h + (ri*1024 + j0 + rg)*768 + 256 + j);
        #pragma unroll
        for (int bi = 0; bi < 8; ++bi) {
          const float4 xv = *(const float4*)(xt + (bgb+bi)*XST2 + j);
          #pragma unroll
          for (int ri = 0; ri < 4; ++ri)
            acc[ri][bi] += w4[ri].x*xv.x + w4[ri].y*xv.y + w4[ri].z*xv.z + w4[ri].w*xv.w;
        }
      }
      #pragma unroll
      for (int ri = 0; ri < 4; ++ri)
        #pragma unroll
        for (int bi = 0; bi < 8; ++bi) {
          float v = acc[ri][bi];
          REDUCE64(v);
          if (ks == 63) gv[(rg*4 + ri)*16 + (bgb+bi)] = v;
        }
      __syncthreads();
      if (tid < 64) {
        const int jl = tid >> 4, bb = tid & 15;
        const int j = j0 + jl;
        float pi, pf, pg, po;
        if (blk < B_) {
          const float4 g4 = ld1q_sys(g0pre + bb*256 + j*4);
          pi = g4.x; pf = g4.y; pg = g4.z; po = g4.w;
        } else {
          pi = gv0[(0*4 + jl)*16 + bb];
          pf = gv0[(1*4 + jl)*16 + bb];
          pg = gv0[(2*4 + jl)*16 + bb];
          po = gv0[(3*4 + jl)*16 + bb];
        }
        const float gi = gv[(jl*4+0)*16 + bb] + pi;
        const float gf = gv[(jl*4+1)*16 + bb] + pf;
        const float gg = gv[(jl*4+2)*16 + bb] + pg;
        const float go = gv[(jl*4+3)*16 + bb] + po;
        const float cn = fsigf(gf)*c0r + fsigf(gi)*ftanhf(gg);
        const float hn = fsigf(go)*ftanhf(cn);
        c0r = cn;
        st_sys(h0st + (t+1)*HSLOT + bb*DIM_ + j, hn);   // h0(t) -> slot t+1
      }
    }
    gridbar(bar, tid, blk, ep); ++ep;

    //====================== P3: gates1 Wih1@h0 + LSTM1 (+proj for attn blocks) ======================
    {
      { // stage h0(t) = slot t+1 (plain loads; cold -> LLC -> L2-shared)
        const float* src = h0st + (t+1)*HSLOT;
        float4 r[8];
        #pragma unroll
        for (int u = 0; u < 8; ++u) r[u] = *(const float4*)(src + (tid + u*512)*4);
        #pragma unroll
        for (int u = 0; u < 8; ++u) {
          const int i = tid + u*512;
          *(float4*)(xt + (i>>8)*XST3 + (i&255)*4) = r[u];
        }
      }
      __syncthreads();
      float acc[4][8];
      #pragma unroll
      for (int ri = 0; ri < 4; ++ri)
        #pragma unroll
        for (int bi = 0; bi < 8; ++bi) acc[ri][bi] = 0.0f;
      #pragma unroll
      for (int q = 0; q < 4; ++q) {
        const int j = q*256 + ks*4;
        float4 w4[4];
        if (blk < B_) {
          #pragma unroll
          for (int ri = 0; ri < 4; ++ri)
            w4[ri] = bf4(Wih1h + (ri*1024 + j0 + rg)*1024 + j);
        } else {
          #pragma unroll
          for (int ri = 0; ri < 4; ++ri)
            w4[ri] = bf4(wl + (((ri*4 + rg)*4 + q) << 8) + ks*4);
        }
        #pragma unroll
        for (int bi = 0; bi < 8; ++bi) {
          const float4 xv = *(const float4*)(xt + (bgb+bi)*XST3 + j);
          #pragma unroll
          for (int ri = 0; ri < 4; ++ri)
            acc[ri][bi] += w4[ri].x*xv.x + w4[ri].y*xv.y + w4[ri].z*xv.z + w4[ri].w*xv.w;
        }
      }
      #pragma unroll
      for (int ri = 0; ri < 4; ++ri)
        #pragma unroll
        for (int bi = 0; bi < 8; ++bi) {
          float v = acc[ri][bi];
          REDUCE64(v);
          if (ks == 63) gv[(rg*4 + ri)*16 + (bgb+bi)] = v;
        }
      __syncthreads();
      if (tid < 64) {
        const int jl = tid >> 4, bb = tid & 15;
        const int j = j0 + jl;
        float pi, pf, pg, po;
        if (blk < B_) {
          const float4 g4 = ld1q_sys(g1pre + bb*256 + j*4);
          pi = g4.x; pf = g4.y; pg = g4.z; po = g4.w;
        } else {
          pi = gv1[(0*4 + jl)*16 + bb];
          pf = gv1[(1*4 + jl)*16 + bb];
          pg = gv1[(2*4 + jl)*16 + bb];
          po = gv1[(3*4 + jl)*16 + bb];
        }
        const float gi = gv[(jl*4+0)*16 + bb] + pi;
        const float gf = gv[(jl*4+1)*16 + bb] + pf;
        const float gg = gv[(jl*4+2)*16 + bb] + pg;
        const float go = gv[(jl*4+3)*16 + bb] + po;
        const float cn = fsigf(gf)*c1r + fsigf(gi)*ftanhf(gg);
        const float hn = fsigf(go)*ftanhf(cn);
        c1r = cn;
        st_sys(h1buf + (t+1)*HSLOT + bb*DIM_ + j, hn);  // h1(t) -> slot t+1
      }
      // projection of step t-1 (attn blocks; inputs staged in projx during P1)
      if (blk < B_ && t > 0) {
        const int b = blk;
        const int o = tid >> 2, part = tid & 3;
        if (o < 81) {
          const float* w = projW + o*1536;
          const int jb = part*384;
          float acc2 = 0.0f;
          for (int j = jb; j < jb + 384; j += 4) {
            const float4 wv = *(const float4*)(w + j);
            const float4 xv = *(const float4*)(projx + j);
            acc2 += wv.x*xv.x + wv.y*xv.y + wv.z*xv.z + wv.w*xv.w;
          }
          spf[o*4 + part] = acc2;
        }
        __syncthreads();
        if (tid < 81) {
          const float v = projb[tid] + spf[tid*4] + spf[tid*4+1] + spf[tid*4+2] + spf[tid*4+3];
          if (tid < 80) out_mel[(b*NMEL_ + tid)*T_ + (t-1)] = v;
          else          out_stop[b*T_ + (t-1)] = v;
        }
      }
    }
    gridbar(bar, tid, blk, ep); ++ep;
  }

  // ---- tail projection for t = T_-1 (h1 slot 300, align slot 299)
  if (blk < B_) {
    const int b = blk;
    if (tid < 256) {
      *(float4*)(projx + tid*4) =
          *(const float4*)(h1buf + 300*HSLOT + b*DIM_ + tid*4);
    } else if (tid < 384) {
      const int j = tid - 256;
      *(float4*)(projx + 1024 + j*4) =
          *(const float4*)(albuf + 299*ASLOT + b*ENC_ + j*4);
    }
    __syncthreads();
    const int o = tid >> 2, part = tid & 3;
    if (o < 81) {
      const float* w = projW + o*1536;
      const int jb = part*384;
      float acc = 0.0f;
      for (int j = jb; j < jb + 384; j += 4) {
        const float4 wv = *(const float4*)(w + j);
        const float4 xv = *(const float4*)(projx + j);
        acc += wv.x*xv.x + wv.y*xv.y + wv.z*xv.z + wv.w*xv.w;
      }
      spf[o*4 + part] = acc;
    }
    __syncthreads();
    if (tid < 81) {
      const float v = projb[tid] + spf[tid*4] + spf[tid*4+1] + spf[tid*4+2] + spf[tid*4+3];
      if (tid < 80) out_mel[(b*NMEL_ + tid)*T_ + (T_-1)] = v;
      else          out_stop[b*T_ + (T_-1)] = v;
    }
  }
}

extern "C" void kernel_launch(void* const* d_in, const int* in_sizes, int n_in,
                              void* d_out, int out_size, void* d_ws, size_t ws_size,
                              hipStream_t stream) {
  const float* mels  = (const float*)d_in[0];
  const float* enc   = (const float*)d_in[1];
  const int*   tlen  = (const int*)d_in[2];
  const float* Wt    = (const float*)d_in[3];
  const float* Wq    = (const float*)d_in[4];
  const float* wsc   = (const float*)d_in[5];
  const float* conv1 = (const float*)d_in[6];
  const float* conv2 = (const float*)d_in[7];
  const float* pW1   = (const float*)d_in[8];
  const float* pb1   = (const float*)d_in[9];
  const float* pW2   = (const float*)d_in[10];
  const float* pb2   = (const float*)d_in[11];
  const float* Wih0  = (const float*)d_in[12];
  const float* Whh0  = (const float*)d_in[13];
  const float* bih0  = (const float*)d_in[14];
  const float* bhh0  = (const float*)d_in[15];
  const float* Wih1  = (const float*)d_in[16];
  const float* Whh1  = (const float*)d_in[17];
  const float* bih1  = (const float*)d_in[18];
  const float* bhh1  = (const float*)d_in[19];
  const float* h0    = (const float*)d_in[20];
  const float* c0    = (const float*)d_in[21];
  const float* projW = (const float*)d_in[22];
  const float* projb = (const float*)d_in[23];

  float* ws     = (float*)d_ws;
  float* melpre = ws;                   // 1,228,800
  float* lencb  = melpre + 1228800;     //   327,680
  float* weff   = lencb + 327680;       //     4,096
  float* h1buf  = weff + 4096;          // 301*16384 = 4,931,584
  float* albuf  = h1buf + 301*16384;    // 300*8192  = 2,457,600
  float* h0st   = albuf + 300*8192;     // 301*16384 = 4,931,584
  float* g0pre  = h0st + 301*16384;     //     4,096
  float* g1pre  = g0pre + 4096;         //     4,096
  u32*   bar    = (u32*)(g1pre + 4096); // 17,408 words
  u16*   Wih0h  = (u16*)(bar + BARWORDS);   // 4096*768  bf16
  u16*   Whh0h  = Wih0h + 4096*768;         // 4096*1024 bf16
  u16*   Wih1h  = Whh0h + 4096*1024;        // 4096*1024 bf16
  u16*   Whh1h  = Wih1h + 4096*1024;        // 4096*1024 bf16 (~87 MB ws total)

  float* out_mel  = (float*)d_out;
  float* out_stop = out_mel + 384000;
  float* out_attn = out_stop + 4800;

  prenet_kernel<<<dim3(480), dim3(256), 0, stream>>>(mels, pW1, pb1, pW2, pb2, melpre);
  init_kernel<<<dim3(160), dim3(256), 0, stream>>>(h0, conv1, conv2, h1buf, h0st, weff, bar);
  wcvt_kernel<<<dim3(2048), dim3(256), 0, stream>>>(Wih0, Whh0, Wih1, Whh1,
                                                    Wih0h, Whh0h, Wih1h, Whh1h);
  lenc_kernel<<<dim3(640), dim3(256), 0, stream>>>(enc, Wt, lencb);

  void* args[] = {
    (void*)&melpre, (void*)&lencb, (void*)&weff, (void*)&h1buf, (void*)&albuf, (void*)&h0st,
    (void*)&g0pre, (void*)&g1pre, (void*)&bar,
    (void*)&enc, (void*)&tlen, (void*)&Wq, (void*)&wsc,
    (void*)&Wih0h, (void*)&Whh0h, (void*)&Wih1h, (void*)&Whh1h,
    (void*)&bih0, (void*)&bhh0, (void*)&bih1, (void*)&bhh1,
    (void*)&c0, (void*)&projW, (void*)&projb,
    (void*)&out_mel, (void*)&out_stop, (void*)&out_attn
  };
  hipLaunchCooperativeKernel((const void*)decoder_kernel, dim3(256), dim3(512),
                             args, (unsigned int)(XTOT*sizeof(float)), stream);
}

// Round 10
// 41308.289 us; speedup vs baseline: 1.1649x; 1.0099x over previous
//
#include <hip/hip_runtime.h>

#define T_    300
#define B_    16
#define S_    160
#define NMEL_ 80
#define PRE_  256
#define ENC_  512
#define ATT_  128
#define DIM_  1024

#define XST1  1288     // P1 tile stride (mel 256 + h0 1024 + pad 8); rows end at 20600
#define XST2  520      // P2 align tile stride (ends 8320)
#define XST3  1032     // P3 h0 tile stride (ends 16504)
#define AOFF  16512    // attn blocks: persistent arrays (cum_p, projx, wscs) — above staging
#define WLDS  20608    // compute blocks: pinned bf16 Wih1+Whh1 (2 x 16 rows x 1024 = 64 KB)
#define XTOT  36992    // dynamic LDS floats (148 KB)
#define BARWORDS 17408

// rotation depths: every step writes a FRESH slot so consumer L2/L1 lines are
// cold -> plain cached reads pull fresh data from LLC (where sc1 stores land);
// blocks on one XCD then share one L2 copy / merged miss.
#define HSLOT (B_*DIM_)   // 16384 floats / slot (h0st, h1buf)
#define ASLOT (B_*ENC_)   // 8192 floats / slot (albuf)

typedef unsigned int u32;
typedef unsigned short u16;

__device__ __forceinline__ float fexp2f(float x) { return __builtin_amdgcn_exp2f(x); }
__device__ __forceinline__ float fsigf(float x)  { return 1.0f / (1.0f + fexp2f(-1.442695041f * x)); }
__device__ __forceinline__ float ftanhf(float x) {
  float xc = fminf(fmaxf(x, -15.0f), 15.0f);
  float e = fexp2f(2.885390082f * xc);
  return (e - 1.0f) / (e + 1.0f);
}

// ---- bf16 helpers (weights-only bf16, RNE).
__device__ __forceinline__ u16 f2bf(float f) {
  u32 b = __float_as_uint(f);
  return (u16)((b + 0x7fffu + ((b >> 16) & 1u)) >> 16);
}
__device__ __forceinline__ float4 bf4(const u16* p) {
  const uint2 u = *(const uint2*)p;
  float4 w;
  w.x = __uint_as_float(u.x << 16);
  w.y = __uint_as_float(u.x & 0xffff0000u);
  w.z = __uint_as_float(u.y << 16);
  w.w = __uint_as_float(u.y & 0xffff0000u);
  return w;
}

// ---- system-scope (LLC) accessors: state WRITES are sc1 (LLC-visible for
// other XCDs' cold-miss reads); barrier words sc both ways.
__device__ __forceinline__ float4 ld1q_sys(const float* p) {
  float4 v;
  asm volatile("global_load_dwordx4 %0, %1, off sc0 sc1\n\ts_waitcnt vmcnt(0)"
               : "=v"(v) : "v"(p) : "memory");
  return v;
}
__device__ __forceinline__ void st_sys(float* p, float v) {
  asm volatile("global_store_dword %0, %1, off sc0 sc1" :: "v"(p), "v"(v) : "memory");
}
__device__ __forceinline__ u32 ld_sys_u32(const u32* p) {
  u32 r;
  asm volatile("global_load_dword %0, %1, off sc0 sc1\n\ts_waitcnt vmcnt(0)"
               : "=v"(r) : "v"(p) : "memory");
  return r;
}
__device__ __forceinline__ void st_sys_u32(u32* p, u32 v) {
  asm volatile("global_store_dword %0, %1, off sc0 sc1" :: "v"(p), "v"(v) : "memory");
}

// ---- tree-arrival / wide-release barrier: 16 groups x 16 blocks arrival;
// top releaser writes 16 per-group release words (<=16 pollers per line).
__device__ __forceinline__ void gridbar(u32* bar, int tid, int blk, u32 ep) {
  asm volatile("s_waitcnt vmcnt(0)" ::: "memory");   // drain this wave's sc stores
  __syncthreads();
  if (tid == 0) {
    const int g = blk & 15;
    u32* cnt  = bar + g*1024;
    u32* grel = bar + g*1024 + 64;
    u32* tcnt = bar + 16384;
    const u32 tgt = ep*16u + 15u;
    u32 old = __hip_atomic_fetch_add(cnt, 1u, __ATOMIC_RELAXED, __HIP_MEMORY_SCOPE_AGENT);
    if (old == tgt) {
      u32 told = __hip_atomic_fetch_add(tcnt, 1u, __ATOMIC_RELAXED, __HIP_MEMORY_SCOPE_AGENT);
      if (told == tgt) {
        #pragma unroll
        for (int g2 = 0; g2 < 16; ++g2) st_sys_u32(bar + g2*1024 + 64, ep + 1u);
      } else {
        while (ld_sys_u32(grel) != ep + 1u) __builtin_amdgcn_s_sleep(1);
      }
    } else {
      while (ld_sys_u32(grel) != ep + 1u) __builtin_amdgcn_s_sleep(1);
    }
  }
  __syncthreads();
}

// ---- wave-64 sum via DPP (VALU pipe, zero DS ops).
#define DPP_ADD(v, ctrl, rmask) do { \
  int _t = __builtin_amdgcn_update_dpp(0, __float_as_int(v), (ctrl), (rmask), 0xf, false); \
  (v) += __int_as_float(_t); } while (0)

#define REDUCE64(v) do { \
  DPP_ADD(v, 0x111, 0xf); \
  DPP_ADD(v, 0x112, 0xf); \
  DPP_ADD(v, 0x114, 0xf); \
  DPP_ADD(v, 0x118, 0xf); \
  DPP_ADD(v, 0x142, 0xa); \
  DPP_ADD(v, 0x143, 0x8); } while (0)

// ---------------- prenet
__launch_bounds__(256)
__global__ void prenet_kernel(const float* __restrict__ mels,
                              const float* __restrict__ pW1, const float* __restrict__ pb1,
                              const float* __restrict__ pW2, const float* __restrict__ pb2,
                              float* __restrict__ melpre) {
  __shared__ float mcol[NMEL_];
  __shared__ float pcol[PRE_];
  const int b = blockIdx.x / 30;
  const int tbase = (blockIdx.x % 30) * 10;
  const int tid = threadIdx.x;
  for (int f = 0; f < 10; ++f) {
    const int t = tbase + f;
    if (tid < NMEL_) mcol[tid] = (t == 0) ? 0.0f : mels[(b*NMEL_ + tid)*T_ + (t-1)];
    __syncthreads();
    {
      float a1 = pb1[tid];
      const float* w1 = pW1 + tid*NMEL_;
      for (int m = 0; m < NMEL_; ++m) a1 += w1[m]*mcol[m];
      pcol[tid] = fmaxf(a1, 0.0f);
    }
    __syncthreads();
    {
      float a2 = pb2[tid];
      const float* w2 = pW2 + tid*PRE_;
      for (int d = 0; d < PRE_; d += 4) {
        const float4 wv = *(const float4*)(w2 + d);
        a2 += wv.x*pcol[d] + wv.y*pcol[d+1] + wv.z*pcol[d+2] + wv.w*pcol[d+3];
      }
      melpre[(t*B_ + b)*PRE_ + tid] = fmaxf(a2, 0.0f);
    }
    __syncthreads();
  }
}

// ---------------- init: h states (slot 0), Weff, barrier region
__launch_bounds__(256)
__global__ void init_kernel(const float* __restrict__ h0,
                            const float* __restrict__ conv1, const float* __restrict__ conv2,
                            float* __restrict__ h1buf, float* __restrict__ h0st,
                            float* __restrict__ weff, u32* __restrict__ bar) {
  const int idx = blockIdx.x*256 + threadIdx.x;
  if (idx < B_*DIM_) {
    const int j = idx & (DIM_-1);
    h0st[idx]  = h0[j];
    h1buf[idx] = h0[DIM_ + j];
  } else if (idx < B_*DIM_ + ATT_*32) {
    const int r = idx - B_*DIM_;
    const int a = r >> 5, k = r & 31;
    float acc = 0.0f;
    if (k < 31) {
      for (int l = 0; l < 32; ++l) acc += conv2[a*32 + l]*conv1[l*31 + k];
    }
    weff[r] = acc;   // row tap 31 stays exactly 0 (used as padded FMA tap)
  } else if (idx < B_*DIM_ + ATT_*32 + BARWORDS) {
    bar[idx - (B_*DIM_ + ATT_*32)] = 0u;
  }
}

// ---------------- weight conversion fp32 -> bf16 (RNE); now also Wq.
__launch_bounds__(256)
__global__ void wcvt_kernel(const float* __restrict__ Wih0, const float* __restrict__ Whh0,
                            const float* __restrict__ Wih1, const float* __restrict__ Whh1,
                            const float* __restrict__ Wq,
                            u16* __restrict__ Wih0h, u16* __restrict__ Whh0h,
                            u16* __restrict__ Wih1h, u16* __restrict__ Whh1h,
                            u16* __restrict__ Wqh) {
  const int n0 = 4096*768, n1 = 4096*1024, nq = ATT_*DIM_;
  const int stride = gridDim.x*256;
  for (int i = blockIdx.x*256 + threadIdx.x; i < n0; i += stride) Wih0h[i] = f2bf(Wih0[i]);
  for (int i = blockIdx.x*256 + threadIdx.x; i < n1; i += stride) {
    Whh0h[i] = f2bf(Whh0[i]);
    Wih1h[i] = f2bf(Wih1[i]);
    Whh1h[i] = f2bf(Whh1[i]);
  }
  for (int i = blockIdx.x*256 + threadIdx.x; i < nq; i += stride) Wqh[i] = f2bf(Wq[i]);
}

// ---------------- l_enc
__launch_bounds__(256)
__global__ void lenc_kernel(const float* __restrict__ enc, const float* __restrict__ Wt,
                            float* __restrict__ lencb) {
  __shared__ float es[4*ENC_];
  const int b = blockIdx.x / 40;
  const int s0 = (blockIdx.x % 40) * 4;
  const int tid = threadIdx.x;
  for (int idx = tid; idx < 4*ENC_; idx += 256) es[idx] = enc[(b*S_ + s0)*ENC_ + idx];
  __syncthreads();
  const int a = tid & 127, sh = tid >> 7;
  const float* w = Wt + a*ENC_;
  for (int p = 0; p < 2; ++p) {
    const int sl = sh*2 + p;
    const float* e = es + sl*ENC_;
    float acc = 0.0f;
    for (int j = 0; j < ENC_; j += 4) {
      const float4 wv = *(const float4*)(w + j);
      acc += wv.x*e[j] + wv.y*e[j+1] + wv.z*e[j+2] + wv.w*e[j+3];
    }
    lencb[(b*S_ + s0 + sl)*ATT_ + a] = acc;
  }
}

// ---------------- persistent decoder
// r10: Wq in bf16. Per-XCD L2 working set drops from ~4.1 MB (over the 4 MB
// cliff -> everything re-streamed from L3 every step, FETCH 30 MB/step) to
// ~3.2 MB -> attn fp32 Wq stream (8 MB/step) gone AND compute-weight slices
// become L2-resident.
__launch_bounds__(512, 1)
__global__ void decoder_kernel(
    const float* __restrict__ melpre, const float* __restrict__ lencb,
    const float* __restrict__ weff,
    float* __restrict__ h1buf, float* __restrict__ albuf, float* __restrict__ h0st,
    float* __restrict__ g0pre, float* __restrict__ g1pre, u32* __restrict__ bar,
    const float* __restrict__ enc, const int* __restrict__ tlen,
    const u16* __restrict__ Wqh, const float* __restrict__ wsc,
    const u16* __restrict__ Wih0h, const u16* __restrict__ Whh0h,
    const u16* __restrict__ Wih1h, const u16* __restrict__ Whh1h,
    const float* __restrict__ bih0, const float* __restrict__ bhh0,
    const float* __restrict__ bih1, const float* __restrict__ bhh1,
    const float* __restrict__ c0in, const float* __restrict__ projW, const float* __restrict__ projb,
    float* __restrict__ out_mel, float* __restrict__ out_stop, float* __restrict__ out_attn)
{
  extern __shared__ float xt[];
  __shared__ float red_s[1];
  __shared__ float gv[256];    // P2/P3 GEMV reduction
  __shared__ float gv0[256];   // gates0 pre (own rows), persists P1->P2
  __shared__ float gv1[256];   // gates1 pre (own rows), persists P1->P3
  __shared__ float q_s[ATT_];
  __shared__ float spf[S_*4];  // P1 score partials; P3 proj partials
  __shared__ float score_s[S_];
  __shared__ float attn_s[S_];

  // attn-block persistent overlays in dynamic LDS, above P3 staging reach (16504)
  float* const cum_p = xt + AOFF;          // [190]
  float* const projx = xt + AOFF + 192;    // [1536]
  float* const wscs  = xt + AOFF + 1728;   // [128]
  u16* const wl = (u16*)(xt + WLDS);       // compute blocks: 128 chunks x 256 bf16

  const int blk = blockIdx.x;
  const int tid = threadIdx.x;
  const int ks = tid & 63;
  const int bgb = ((tid >> 6) & 1)*8;
  const int rg = tid >> 7;
  const int j0 = blk*4;

  float c0r = 0.0f, c1r = 0.0f;
  if (tid < 64) {
    const int j = j0 + (tid >> 4);
    c0r = c0in[j];
    c1r = c0in[DIM_ + j];
  }
  int mylen = 0;
  if (blk < B_) {
    mylen = tlen[blk];
    for (int i = tid; i < S_ + 30; i += 512) cum_p[i] = 0.0f;
    if (tid < ATT_) wscs[tid] = wsc[tid];
  } else {
    // pin this block's Wih1 (chunks 0..63) and Whh1 (chunks 64..127) rows,
    // bf16, chunked so lane ks reads chunk c at [c*256 + ks*4] (8B).
    for (int i = tid; i < 8192; i += 512) {
      const int c = i >> 6, l = i & 63;
      const int m = c >> 6, cm = c & 63;
      const int ri = cm >> 4, rgw = (cm >> 2) & 3, q = cm & 3;
      const u16* src = (m ? Whh1h : Wih1h) + (ri*1024 + j0 + rgw)*1024 + q*256 + l*4;
      *(uint2*)(wl + c*256 + l*4) = *(const uint2*)src;
    }
  }
  __syncthreads();

  u32 ep = 0;

  for (int t = 0; t < T_; ++t) {
    //====================== P1 ======================
    if (blk < B_) {
      const int b = blk;
      // stage [h1(t) | align(t-1)] into projx (plain cached loads; slots cold)
      if (tid < 256) {
        *(float4*)(projx + tid*4) =
            *(const float4*)(h1buf + t*HSLOT + b*DIM_ + tid*4);
      } else if (tid < 384) {
        const int j = tid - 256;
        const int ap = (t > 0) ? (t-1) : 0;   // t=0 value unused (proj guarded)
        *(float4*)(projx + 1024 + j*4) =
            *(const float4*)(albuf + ap*ASLOT + b*ENC_ + j*4);
      }
      __syncthreads();
      // q = h1prev @ Wq^T (bf16 weights)
      {
        const int a = tid & 127, part = tid >> 7;
        const float* hp = projx + part*256;
        const u16* wq = Wqh + a*DIM_ + part*256;
        float acc = 0.0f;
        for (int j = 0; j < 256; j += 4) {
          const float4 wv = bf4(wq + j);
          const float4 hv = *(const float4*)(hp + j);
          acc += wv.x*hv.x + wv.y*hv.y + wv.z*hv.z + wv.w*hv.w;
        }
        spf[a*4 + part] = acc;
      }
      __syncthreads();
      if (tid < ATT_) q_s[tid] = spf[tid*4] + spf[tid*4+1] + spf[tid*4+2] + spf[tid*4+3];
      __syncthreads();
      // scores: loc-conv taps from GLOBAL weff (L1-resident, wave-uniform)
      {
        const int sl = tid & 127, ag = tid >> 7;
        const int a0 = ag*32;
        #pragma unroll
        for (int p = 0; p < 2; ++p) {
          const int s = sl + p*128;
          if (s < S_) {
            float cw[32];
            #pragma unroll
            for (int k = 0; k < 31; ++k) cw[k] = cum_p[s + k];
            cw[31] = 0.0f;
            const float* le = lencb + (b*S_ + s)*ATT_ + a0;
            const float* wr = weff + a0*32;
            float ps = 0.0f;
            for (int i4 = 0; i4 < 8; ++i4) {
              const float4 lev = *(const float4*)(le + i4*4);
              #pragma unroll
              for (int ii = 0; ii < 4; ++ii) {
                const int i = i4*4 + ii;
                const float4* wk4 = (const float4*)(wr + i*32);
                float loc = 0.0f;
                #pragma unroll
                for (int kq = 0; kq < 8; ++kq) {
                  const float4 wv = wk4[kq];
                  loc += wv.x*cw[kq*4+0] + wv.y*cw[kq*4+1] + wv.z*cw[kq*4+2] + wv.w*cw[kq*4+3];
                }
                const float lef = (ii==0)?lev.x:(ii==1)?lev.y:(ii==2)?lev.z:lev.w;
                ps += wscs[a0 + i]*ftanhf(q_s[a0 + i] + lef + loc);
              }
            }
            spf[s*4 + ag] = ps;
          }
        }
      }
      __syncthreads();
      if (tid < S_) {
        float sc = spf[tid*4] + spf[tid*4+1] + spf[tid*4+2] + spf[tid*4+3];
        if (tid >= mylen) sc = -1.0e30f;
        score_s[tid] = sc;
      }
      __syncthreads();
      if (tid < 64) {
        float m = -1.0e30f;
        for (int i = tid; i < S_; i += 64) m = fmaxf(m, score_s[i]);
        #pragma unroll
        for (int o = 32; o > 0; o >>= 1) m = fmaxf(m, __shfl_xor(m, o, 64));
        float sum = 0.0f;
        for (int i = tid; i < S_; i += 64) {
          const float e = fexp2f(1.442695041f*(score_s[i] - m));
          score_s[i] = e;
          sum += e;
        }
        #pragma unroll
        for (int o = 32; o > 0; o >>= 1) sum += __shfl_xor(sum, o, 64);
        if (tid == 0) red_s[0] = sum;
      }
      __syncthreads();
      {
        const float inv = 1.0f / red_s[0];
        if (tid < S_) {
          const float av = score_s[tid]*inv;
          attn_s[tid] = av;
          cum_p[15 + tid] += av;
          out_attn[(b*S_ + tid)*T_ + t] = av;
        }
      }
      __syncthreads();
      // align = attn @ enc -> albuf slot t (sc1 write)
      {
        const float* eb = enc + (b*S_)*ENC_ + tid;
        float acc = 0.0f;
        for (int s = 0; s < S_; ++s) acc += attn_s[s]*eb[s*ENC_];
        st_sys(albuf + t*ASLOT + b*ENC_ + tid, acc);
      }
    } else {
      const bool hg0 = (blk >= 16 && blk < 80);
      const bool hg1 = (blk >= 80 && blk < 144);
      const int jx0 = blk - 16;
      const int jx1 = blk - 80;
      // ---- stage [mel | h0(t-1)=slot t] tile (plain loads)
      for (int i = tid; i < 1024; i += 512) {
        float4 v = *(const float4*)(melpre + t*4096 + i*4);
        *(float4*)(xt + (i>>6)*XST1 + (i&63)*4) = v;
      }
      {
        const float* src = h0st + t*HSLOT;
        float4 r[8];
        #pragma unroll
        for (int u = 0; u < 8; ++u) r[u] = *(const float4*)(src + (tid + u*512)*4);
        #pragma unroll
        for (int u = 0; u < 8; ++u) {
          const int i = tid + u*512;
          *(float4*)(xt + (i>>8)*XST1 + 256 + (i&255)*4) = r[u];
        }
      }
      __syncthreads();
      // ---- GEMV-a: gates0 pre = Wih0[:, :256]@mel + Whh0@h0prev (+biases)
      // batch-split into 2 halves of 4 to stay under 128 VGPR (no spills).
      {
        const int nr = hg0 ? 5 : 4;
        int nrow[5];
        #pragma unroll
        for (int ri = 0; ri < 4; ++ri) nrow[ri] = ri*1024 + j0 + rg;
        nrow[4] = rg*1024 + ((jx0 < 64) ? jx0 : 0);
        #pragma unroll
        for (int hf = 0; hf < 2; ++hf) {
          const int b0 = bgb + hf*4;
          float acc[5][4];
          #pragma unroll
          for (int ri = 0; ri < 5; ++ri)
            #pragma unroll
            for (int bi = 0; bi < 4; ++bi) acc[ri][bi] = 0.0f;
          { // mel chunk
            const int j = ks*4;
            float4 w4[5];
            #pragma unroll
            for (int ri = 0; ri < 5; ++ri)
              if (ri < nr) w4[ri] = bf4(Wih0h + nrow[ri]*768 + j);
            #pragma unroll
            for (int bi = 0; bi < 4; ++bi) {
              const float4 xv = *(const float4*)(xt + (b0+bi)*XST1 + j);
              #pragma unroll
              for (int ri = 0; ri < 5; ++ri)
                if (ri < nr)
                  acc[ri][bi] += w4[ri].x*xv.x + w4[ri].y*xv.y + w4[ri].z*xv.z + w4[ri].w*xv.w;
            }
          }
          #pragma unroll
          for (int q = 0; q < 4; ++q) { // h0 chunks
            const int j = q*256 + ks*4;
            float4 w4[5];
            #pragma unroll
            for (int ri = 0; ri < 5; ++ri)
              if (ri < nr) w4[ri] = bf4(Whh0h + nrow[ri]*1024 + j);
            #pragma unroll
            for (int bi = 0; bi < 4; ++bi) {
              const float4 xv = *(const float4*)(xt + (b0+bi)*XST1 + 256 + j);
              #pragma unroll
              for (int ri = 0; ri < 5; ++ri)
                if (ri < nr)
                  acc[ri][bi] += w4[ri].x*xv.x + w4[ri].y*xv.y + w4[ri].z*xv.z + w4[ri].w*xv.w;
            }
          }
          #pragma unroll
          for (int ri = 0; ri < 5; ++ri)
            if (ri < nr)
              #pragma unroll
              for (int bi = 0; bi < 4; ++bi) {
                float v = acc[ri][bi];
                REDUCE64(v);
                if (ks == 63) {
                  const int n = nrow[ri];
                  v += bih0[n] + bhh0[n];
                  if (ri < 4) gv0[(ri*4 + rg)*16 + (b0+bi)] = v;
                  else        st_sys(g0pre + (b0+bi)*256 + jx0*4 + rg, v);
                }
              }
        }
      }
      __syncthreads();
      // ---- stage h1(t) = slot t (plain loads)
      {
        const float* src = h1buf + t*HSLOT;
        float4 r[8];
        #pragma unroll
        for (int u = 0; u < 8; ++u) r[u] = *(const float4*)(src + (tid + u*512)*4);
        #pragma unroll
        for (int u = 0; u < 8; ++u) {
          const int i = tid + u*512;
          *(float4*)(xt + (i>>8)*XST1 + (i&255)*4) = r[u];
        }
      }
      __syncthreads();
      // ---- GEMV-b: gates1 pre = Whh1@h1prev (+biases); rows 0..3 from LDS bf16
      {
        const int nr = hg1 ? 5 : 4;
        const int nprox = rg*1024 + (hg1 ? jx1 : 0);
        #pragma unroll
        for (int hf = 0; hf < 2; ++hf) {
          const int b0 = bgb + hf*4;
          float acc[5][4];
          #pragma unroll
          for (int ri = 0; ri < 5; ++ri)
            #pragma unroll
            for (int bi = 0; bi < 4; ++bi) acc[ri][bi] = 0.0f;
          #pragma unroll
          for (int q = 0; q < 4; ++q) {
            const int j = q*256 + ks*4;
            float4 w4[5];
            #pragma unroll
            for (int ri = 0; ri < 4; ++ri)
              w4[ri] = bf4(wl + (64 + (ri*4 + rg)*4 + q)*256 + ks*4);
            if (nr == 5) w4[4] = bf4(Whh1h + nprox*1024 + j);
            #pragma unroll
            for (int bi = 0; bi < 4; ++bi) {
              const float4 xv = *(const float4*)(xt + (b0+bi)*XST1 + j);
              #pragma unroll
              for (int ri = 0; ri < 5; ++ri)
                if (ri < nr)
                  acc[ri][bi] += w4[ri].x*xv.x + w4[ri].y*xv.y + w4[ri].z*xv.z + w4[ri].w*xv.w;
            }
          }
          #pragma unroll
          for (int ri = 0; ri < 5; ++ri)
            if (ri < nr)
              #pragma unroll
              for (int bi = 0; bi < 4; ++bi) {
                float v = acc[ri][bi];
                REDUCE64(v);
                if (ks == 63) {
                  const int n = (ri < 4) ? (ri*1024 + j0 + rg) : nprox;
                  v += bih1[n] + bhh1[n];
                  if (ri < 4) gv1[(ri*4 + rg)*16 + (b0+bi)] = v;
                  else        st_sys(g1pre + (b0+bi)*256 + jx1*4 + rg, v);
                }
              }
        }
      }
    }
    gridbar(bar, tid, blk, ep); ++ep;

    //====================== P2: gates0 align part + LSTM0 ======================
    {
      { // stage align slot t (plain loads)
        const float* src = albuf + t*ASLOT;
        float4 r[4];
        #pragma unroll
        for (int u = 0; u < 4; ++u) r[u] = *(const float4*)(src + (tid + u*512)*4);
        #pragma unroll
        for (int u = 0; u < 4; ++u) {
          const int i = tid + u*512;
          *(float4*)(xt + (i>>7)*XST2 + (i&127)*4) = r[u];
        }
      }
      __syncthreads();
      float acc[4][8];
      #pragma unroll
      for (int ri = 0; ri < 4; ++ri)
        #pragma unroll
        for (int bi = 0; bi < 8; ++bi) acc[ri][bi] = 0.0f;
      #pragma unroll
      for (int q = 0; q < 2; ++q) {
        const int j = q*256 + ks*4;
        float4 w4[4];
        #pragma unroll
        for (int ri = 0; ri < 4; ++ri)
          w4[ri] = bf4(Wih0h + (ri*1024 + j0 + rg)*768 + 256 + j);
        #pragma unroll
        for (int bi = 0; bi < 8; ++bi) {
          const float4 xv = *(const float4*)(xt + (bgb+bi)*XST2 + j);
          #pragma unroll
          for (int ri = 0; ri < 4; ++ri)
            acc[ri][bi] += w4[ri].x*xv.x + w4[ri].y*xv.y + w4[ri].z*xv.z + w4[ri].w*xv.w;
        }
      }
      #pragma unroll
      for (int ri = 0; ri < 4; ++ri)
        #pragma unroll
        for (int bi = 0; bi < 8; ++bi) {
          float v = acc[ri][bi];
          REDUCE64(v);
          if (ks == 63) gv[(rg*4 + ri)*16 + (bgb+bi)] = v;
        }
      __syncthreads();
      if (tid < 64) {
        const int jl = tid >> 4, bb = tid & 15;
        const int j = j0 + jl;
        float pi, pf, pg, po;
        if (blk < B_) {
          const float4 g4 = ld1q_sys(g0pre + bb*256 + j*4);
          pi = g4.x; pf = g4.y; pg = g4.z; po = g4.w;
        } else {
          pi = gv0[(0*4 + jl)*16 + bb];
          pf = gv0[(1*4 + jl)*16 + bb];
          pg = gv0[(2*4 + jl)*16 + bb];
          po = gv0[(3*4 + jl)*16 + bb];
        }
        const float gi = gv[(jl*4+0)*16 + bb] + pi;
        const float gf = gv[(jl*4+1)*16 + bb] + pf;
        const float gg = gv[(jl*4+2)*16 + bb] + pg;
        const float go = gv[(jl*4+3)*16 + bb] + po;
        const float cn = fsigf(gf)*c0r + fsigf(gi)*ftanhf(gg);
        const float hn = fsigf(go)*ftanhf(cn);
        c0r = cn;
        st_sys(h0st + (t+1)*HSLOT + bb*DIM_ + j, hn);   // h0(t) -> slot t+1
      }
    }
    gridbar(bar, tid, blk, ep); ++ep;

    //====================== P3: gates1 Wih1@h0 + LSTM1 (+proj for attn blocks) ======================
    {
      { // stage h0(t) = slot t+1 (plain loads)
        const float* src = h0st + (t+1)*HSLOT;
        float4 r[8];
        #pragma unroll
        for (int u = 0; u < 8; ++u) r[u] = *(const float4*)(src + (tid + u*512)*4);
        #pragma unroll
        for (int u = 0; u < 8; ++u) {
          const int i = tid + u*512;
          *(float4*)(xt + (i>>8)*XST3 + (i&255)*4) = r[u];
        }
      }
      __syncthreads();
      float acc[4][8];
      #pragma unroll
      for (int ri = 0; ri < 4; ++ri)
        #pragma unroll
        for (int bi = 0; bi < 8; ++bi) acc[ri][bi] = 0.0f;
      #pragma unroll
      for (int q = 0; q < 4; ++q) {
        const int j = q*256 + ks*4;
        float4 w4[4];
        if (blk < B_) {
          #pragma unroll
          for (int ri = 0; ri < 4; ++ri)
            w4[ri] = bf4(Wih1h + (ri*1024 + j0 + rg)*1024 + j);
        } else {
          #pragma unroll
          for (int ri = 0; ri < 4; ++ri)
            w4[ri] = bf4(wl + (((ri*4 + rg)*4 + q) << 8) + ks*4);
        }
        #pragma unroll
        for (int bi = 0; bi < 8; ++bi) {
          const float4 xv = *(const float4*)(xt + (bgb+bi)*XST3 + j);
          #pragma unroll
          for (int ri = 0; ri < 4; ++ri)
            acc[ri][bi] += w4[ri].x*xv.x + w4[ri].y*xv.y + w4[ri].z*xv.z + w4[ri].w*xv.w;
        }
      }
      #pragma unroll
      for (int ri = 0; ri < 4; ++ri)
        #pragma unroll
        for (int bi = 0; bi < 8; ++bi) {
          float v = acc[ri][bi];
          REDUCE64(v);
          if (ks == 63) gv[(rg*4 + ri)*16 + (bgb+bi)] = v;
        }
      __syncthreads();
      if (tid < 64) {
        const int jl = tid >> 4, bb = tid & 15;
        const int j = j0 + jl;
        float pi, pf, pg, po;
        if (blk < B_) {
          const float4 g4 = ld1q_sys(g1pre + bb*256 + j*4);
          pi = g4.x; pf = g4.y; pg = g4.z; po = g4.w;
        } else {
          pi = gv1[(0*4 + jl)*16 + bb];
          pf = gv1[(1*4 + jl)*16 + bb];
          pg = gv1[(2*4 + jl)*16 + bb];
          po = gv1[(3*4 + jl)*16 + bb];
        }
        const float gi = gv[(jl*4+0)*16 + bb] + pi;
        const float gf = gv[(jl*4+1)*16 + bb] + pf;
        const float gg = gv[(jl*4+2)*16 + bb] + pg;
        const float go = gv[(jl*4+3)*16 + bb] + po;
        const float cn = fsigf(gf)*c1r + fsigf(gi)*ftanhf(gg);
        const float hn = fsigf(go)*ftanhf(cn);
        c1r = cn;
        st_sys(h1buf + (t+1)*HSLOT + bb*DIM_ + j, hn);  // h1(t) -> slot t+1
      }
      // projection of step t-1 (attn blocks; inputs staged in projx during P1)
      if (blk < B_ && t > 0) {
        const int b = blk;
        const int o = tid >> 2, part = tid & 3;
        if (o < 81) {
          const float* w = projW + o*1536;
          const int jb = part*384;
          float acc2 = 0.0f;
          for (int j = jb; j < jb + 384; j += 4) {
            const float4 wv = *(const float4*)(w + j);
            const float4 xv = *(const float4*)(projx + j);
            acc2 += wv.x*xv.x + wv.y*xv.y + wv.z*xv.z + wv.w*xv.w;
          }
          spf[o*4 + part] = acc2;
        }
        __syncthreads();
        if (tid < 81) {
          const float v = projb[tid] + spf[tid*4] + spf[tid*4+1] + spf[tid*4+2] + spf[tid*4+3];
          if (tid < 80) out_mel[(b*NMEL_ + tid)*T_ + (t-1)] = v;
          else          out_stop[b*T_ + (t-1)] = v;
        }
      }
    }
    gridbar(bar, tid, blk, ep); ++ep;
  }

  // ---- tail projection for t = T_-1 (h1 slot 300, align slot 299)
  if (blk < B_) {
    const int b = blk;
    if (tid < 256) {
      *(float4*)(projx + tid*4) =
          *(const float4*)(h1buf + 300*HSLOT + b*DIM_ + tid*4);
    } else if (tid < 384) {
      const int j = tid - 256;
      *(float4*)(projx + 1024 + j*4) =
          *(const float4*)(albuf + 299*ASLOT + b*ENC_ + j*4);
    }
    __syncthreads();
    const int o = tid >> 2, part = tid & 3;
    if (o < 81) {
      const float* w = projW + o*1536;
      const int jb = part*384;
      float acc = 0.0f;
      for (int j = jb; j < jb + 384; j += 4) {
        const float4 wv = *(const float4*)(w + j);
        const float4 xv = *(const float4*)(projx + j);
        acc += wv.x*xv.x + wv.y*xv.y + wv.z*xv.z + wv.w*xv.w;
      }
      spf[o*4 + part] = acc;
    }
    __syncthreads();
    if (tid < 81) {
      const float v = projb[tid] + spf[tid*4] + spf[tid*4+1] + spf[tid*4+2] + spf[tid*4+3];
      if (tid < 80) out_mel[(b*NMEL_ + tid)*T_ + (T_-1)] = v;
      else          out_stop[b*T_ + (T_-1)] = v;
    }
  }
}

extern "C" void kernel_launch(void* const* d_in, const int* in_sizes, int n_in,
                              void* d_out, int out_size, void* d_ws, size_t ws_size,
                              hipStream_t stream) {
  const float* mels  = (const float*)d_in[0];
  const float* enc   = (const float*)d_in[1];
  const int*   tlen  = (const int*)d_in[2];
  const float* Wt    = (const float*)d_in[3];
  const float* Wq    = (const float*)d_in[4];
  const float* wsc   = (const float*)d_in[5];
  const float* conv1 = (const float*)d_in[6];
  const float* conv2 = (const float*)d_in[7];
  const float* pW1   = (const float*)d_in[8];
  const float* pb1   = (const float*)d_in[9];
  const float* pW2   = (const float*)d_in[10];
  const float* pb2   = (const float*)d_in[11];
  const float* Wih0  = (const float*)d_in[12];
  const float* Whh0  = (const float*)d_in[13];
  const float* bih0  = (const float*)d_in[14];
  const float* bhh0  = (const float*)d_in[15];
  const float* Wih1  = (const float*)d_in[16];
  const float* Whh1  = (const float*)d_in[17];
  const float* bih1  = (const float*)d_in[18];
  const float* bhh1  = (const float*)d_in[19];
  const float* h0    = (const float*)d_in[20];
  const float* c0    = (const float*)d_in[21];
  const float* projW = (const float*)d_in[22];
  const float* projb = (const float*)d_in[23];

  float* ws     = (float*)d_ws;
  float* melpre = ws;                   // 1,228,800
  float* lencb  = melpre + 1228800;     //   327,680
  float* weff   = lencb + 327680;       //     4,096
  float* h1buf  = weff + 4096;          // 301*16384 = 4,931,584
  float* albuf  = h1buf + 301*16384;    // 300*8192  = 2,457,600
  float* h0st   = albuf + 300*8192;     // 301*16384 = 4,931,584
  float* g0pre  = h0st + 301*16384;     //     4,096
  float* g1pre  = g0pre + 4096;         //     4,096
  u32*   bar    = (u32*)(g1pre + 4096); // 17,408 words
  u16*   Wih0h  = (u16*)(bar + BARWORDS);   // 4096*768  bf16
  u16*   Whh0h  = Wih0h + 4096*768;         // 4096*1024 bf16
  u16*   Wih1h  = Whh0h + 4096*1024;        // 4096*1024 bf16
  u16*   Whh1h  = Wih1h + 4096*1024;        // 4096*1024 bf16
  u16*   Wqh    = Whh1h + 4096*1024;        // 128*1024  bf16 (~88 MB ws total)

  float* out_mel  = (float*)d_out;
  float* out_stop = out_mel + 384000;
  float* out_attn = out_stop + 4800;

  prenet_kernel<<<dim3(480), dim3(256), 0, stream>>>(mels, pW1, pb1, pW2, pb2, melpre);
  init_kernel<<<dim3(160), dim3(256), 0, stream>>>(h0, conv1, conv2, h1buf, h0st, weff, bar);
  wcvt_kernel<<<dim3(2048), dim3(256), 0, stream>>>(Wih0, Whh0, Wih1, Whh1, Wq,
                                                    Wih0h, Whh0h, Wih1h, Whh1h, Wqh);
  lenc_kernel<<<dim3(640), dim3(256), 0, stream>>>(enc, Wt, lencb);

  void* args[] = {
    (void*)&melpre, (void*)&lencb, (void*)&weff, (void*)&h1buf, (void*)&albuf, (void*)&h0st,
    (void*)&g0pre, (void*)&g1pre, (void*)&bar,
    (void*)&enc, (void*)&tlen, (void*)&Wqh, (void*)&wsc,
    (void*)&Wih0h, (void*)&Whh0h, (void*)&Wih1h, (void*)&Whh1h,
    (void*)&bih0, (void*)&bhh0, (void*)&bih1, (void*)&bhh1,
    (void*)&c0, (void*)&projW, (void*)&projb,
    (void*)&out_mel, (void*)&out_stop, (void*)&out_attn
  };
  hipLaunchCooperativeKernel((const void*)decoder_kernel, dim3(256), dim3(512),
                             args, (unsigned int)(XTOT*sizeof(float)), stream);
}

// Round 11
// 30539.056 us; speedup vs baseline: 1.5757x; 1.3526x over previous
//
#include <hip/hip_runtime.h>

#define T_    300
#define B_    16
#define S_    160
#define NMEL_ 80
#define PRE_  256
#define ENC_  512
#define ATT_  128
#define DIM_  1024

#define XST1  1288     // P1 tile stride (mel 256 + h0 1024 + pad 8); rows end at 20600
#define XST2  520      // P2 align tile stride (ends 8320)
#define XST3  1032     // P3 h0 tile stride (ends 16504)
#define AOFF  16512    // attn blocks: persistent arrays (cum_p, projx, wscs) — above staging
#define WLDS  20608    // compute blocks: pinned bf16 Wih1+Whh1 (2 x 16 rows x 1024 = 64 KB)
#define XTOT  36992    // dynamic LDS floats (148 KB)
#define BARWORDS 17408

// rotation depths: every step writes a FRESH slot so consumer L2/L1 lines are
// cold -> plain cached reads pull fresh data from LLC (where sc1 stores land).
#define HSLOT (B_*DIM_)   // 16384 floats / slot (h0st, h1buf)
#define ASLOT (B_*ENC_)   // 8192 floats / slot (albuf)
#define GSLOT (B_*256)    // 4096 floats / slot (g0pre, g1pre)

typedef unsigned int u32;
typedef unsigned short u16;

__device__ __forceinline__ float fexp2f(float x) { return __builtin_amdgcn_exp2f(x); }
__device__ __forceinline__ float fsigf(float x)  { return 1.0f / (1.0f + fexp2f(-1.442695041f * x)); }
__device__ __forceinline__ float ftanhf(float x) {
  float xc = fminf(fmaxf(x, -15.0f), 15.0f);
  float e = fexp2f(2.885390082f * xc);
  return (e - 1.0f) / (e + 1.0f);
}

// ---- bf16 helpers (weights-only bf16, RNE).
__device__ __forceinline__ u16 f2bf(float f) {
  u32 b = __float_as_uint(f);
  return (u16)((b + 0x7fffu + ((b >> 16) & 1u)) >> 16);
}
__device__ __forceinline__ float4 bf4(const u16* p) {
  const uint2 u = *(const uint2*)p;
  float4 w;
  w.x = __uint_as_float(u.x << 16);
  w.y = __uint_as_float(u.x & 0xffff0000u);
  w.z = __uint_as_float(u.y << 16);
  w.w = __uint_as_float(u.y & 0xffff0000u);
  return w;
}

// ---- system-scope (LLC) accessors: state WRITES are sc1 (LLC-visible for
// other XCDs' cold-miss reads); barrier words sc both ways.
__device__ __forceinline__ float4 ld1q_sys(const float* p) {
  float4 v;
  asm volatile("global_load_dwordx4 %0, %1, off sc0 sc1\n\ts_waitcnt vmcnt(0)"
               : "=v"(v) : "v"(p) : "memory");
  return v;
}
__device__ __forceinline__ void st_sys(float* p, float v) {
  asm volatile("global_store_dword %0, %1, off sc0 sc1" :: "v"(p), "v"(v) : "memory");
}
__device__ __forceinline__ u32 ld_sys_u32(const u32* p) {
  u32 r;
  asm volatile("global_load_dword %0, %1, off sc0 sc1\n\ts_waitcnt vmcnt(0)"
               : "=v"(r) : "v"(p) : "memory");
  return r;
}
__device__ __forceinline__ void st_sys_u32(u32* p, u32 v) {
  asm volatile("global_store_dword %0, %1, off sc0 sc1" :: "v"(p), "v"(v) : "memory");
}

// ---- tree-arrival / wide-release barrier: 16 groups x 16 blocks arrival;
// top releaser writes 16 per-group release words (<=16 pollers per line).
__device__ __forceinline__ void gridbar(u32* bar, int tid, int blk, u32 ep) {
  asm volatile("s_waitcnt vmcnt(0)" ::: "memory");   // drain this wave's sc stores
  __syncthreads();
  if (tid == 0) {
    const int g = blk & 15;
    u32* cnt  = bar + g*1024;
    u32* grel = bar + g*1024 + 64;
    u32* tcnt = bar + 16384;
    const u32 tgt = ep*16u + 15u;
    u32 old = __hip_atomic_fetch_add(cnt, 1u, __ATOMIC_RELAXED, __HIP_MEMORY_SCOPE_AGENT);
    if (old == tgt) {
      u32 told = __hip_atomic_fetch_add(tcnt, 1u, __ATOMIC_RELAXED, __HIP_MEMORY_SCOPE_AGENT);
      if (told == tgt) {
        #pragma unroll
        for (int g2 = 0; g2 < 16; ++g2) st_sys_u32(bar + g2*1024 + 64, ep + 1u);
      } else {
        while (ld_sys_u32(grel) != ep + 1u) __builtin_amdgcn_s_sleep(1);
      }
    } else {
      while (ld_sys_u32(grel) != ep + 1u) __builtin_amdgcn_s_sleep(1);
    }
  }
  __syncthreads();
}

// ---- wave-64 sum via DPP (VALU pipe, zero DS ops).
#define DPP_ADD(v, ctrl, rmask) do { \
  int _t = __builtin_amdgcn_update_dpp(0, __float_as_int(v), (ctrl), (rmask), 0xf, false); \
  (v) += __int_as_float(_t); } while (0)

#define REDUCE64(v) do { \
  DPP_ADD(v, 0x111, 0xf); \
  DPP_ADD(v, 0x112, 0xf); \
  DPP_ADD(v, 0x114, 0xf); \
  DPP_ADD(v, 0x118, 0xf); \
  DPP_ADD(v, 0x142, 0xa); \
  DPP_ADD(v, 0x143, 0x8); } while (0)

// ---------------- prenet
__launch_bounds__(256)
__global__ void prenet_kernel(const float* __restrict__ mels,
                              const float* __restrict__ pW1, const float* __restrict__ pb1,
                              const float* __restrict__ pW2, const float* __restrict__ pb2,
                              float* __restrict__ melpre) {
  __shared__ float mcol[NMEL_];
  __shared__ float pcol[PRE_];
  const int b = blockIdx.x / 30;
  const int tbase = (blockIdx.x % 30) * 10;
  const int tid = threadIdx.x;
  for (int f = 0; f < 10; ++f) {
    const int t = tbase + f;
    if (tid < NMEL_) mcol[tid] = (t == 0) ? 0.0f : mels[(b*NMEL_ + tid)*T_ + (t-1)];
    __syncthreads();
    {
      float a1 = pb1[tid];
      const float* w1 = pW1 + tid*NMEL_;
      for (int m = 0; m < NMEL_; ++m) a1 += w1[m]*mcol[m];
      pcol[tid] = fmaxf(a1, 0.0f);
    }
    __syncthreads();
    {
      float a2 = pb2[tid];
      const float* w2 = pW2 + tid*PRE_;
      for (int d = 0; d < PRE_; d += 4) {
        const float4 wv = *(const float4*)(w2 + d);
        a2 += wv.x*pcol[d] + wv.y*pcol[d+1] + wv.z*pcol[d+2] + wv.w*pcol[d+3];
      }
      melpre[(t*B_ + b)*PRE_ + tid] = fmaxf(a2, 0.0f);
    }
    __syncthreads();
  }
}

// ---------------- init: h states (slot 0), Weff, barrier region
__launch_bounds__(256)
__global__ void init_kernel(const float* __restrict__ h0,
                            const float* __restrict__ conv1, const float* __restrict__ conv2,
                            float* __restrict__ h1buf, float* __restrict__ h0st,
                            float* __restrict__ weff, u32* __restrict__ bar) {
  const int idx = blockIdx.x*256 + threadIdx.x;
  if (idx < B_*DIM_) {
    const int j = idx & (DIM_-1);
    h0st[idx]  = h0[j];
    h1buf[idx] = h0[DIM_ + j];
  } else if (idx < B_*DIM_ + ATT_*32) {
    const int r = idx - B_*DIM_;
    const int a = r >> 5, k = r & 31;
    float acc = 0.0f;
    if (k < 31) {
      for (int l = 0; l < 32; ++l) acc += conv2[a*32 + l]*conv1[l*31 + k];
    }
    weff[r] = acc;   // row tap 31 stays exactly 0 (used as padded FMA tap)
  } else if (idx < B_*DIM_ + ATT_*32 + BARWORDS) {
    bar[idx - (B_*DIM_ + ATT_*32)] = 0u;
  }
}

// ---------------- weight conversion fp32 -> bf16 (RNE); incl. Wq.
__launch_bounds__(256)
__global__ void wcvt_kernel(const float* __restrict__ Wih0, const float* __restrict__ Whh0,
                            const float* __restrict__ Wih1, const float* __restrict__ Whh1,
                            const float* __restrict__ Wq,
                            u16* __restrict__ Wih0h, u16* __restrict__ Whh0h,
                            u16* __restrict__ Wih1h, u16* __restrict__ Whh1h,
                            u16* __restrict__ Wqh) {
  const int n0 = 4096*768, n1 = 4096*1024, nq = ATT_*DIM_;
  const int stride = gridDim.x*256;
  for (int i = blockIdx.x*256 + threadIdx.x; i < n0; i += stride) Wih0h[i] = f2bf(Wih0[i]);
  for (int i = blockIdx.x*256 + threadIdx.x; i < n1; i += stride) {
    Whh0h[i] = f2bf(Whh0[i]);
    Wih1h[i] = f2bf(Wih1[i]);
    Whh1h[i] = f2bf(Whh1[i]);
  }
  for (int i = blockIdx.x*256 + threadIdx.x; i < nq; i += stride) Wqh[i] = f2bf(Wq[i]);
}

// ---------------- l_enc
__launch_bounds__(256)
__global__ void lenc_kernel(const float* __restrict__ enc, const float* __restrict__ Wt,
                            float* __restrict__ lencb) {
  __shared__ float es[4*ENC_];
  const int b = blockIdx.x / 40;
  const int s0 = (blockIdx.x % 40) * 4;
  const int tid = threadIdx.x;
  for (int idx = tid; idx < 4*ENC_; idx += 256) es[idx] = enc[(b*S_ + s0)*ENC_ + idx];
  __syncthreads();
  const int a = tid & 127, sh = tid >> 7;
  const float* w = Wt + a*ENC_;
  for (int p = 0; p < 2; ++p) {
    const int sl = sh*2 + p;
    const float* e = es + sl*ENC_;
    float acc = 0.0f;
    for (int j = 0; j < ENC_; j += 4) {
      const float4 wv = *(const float4*)(w + j);
      acc += wv.x*e[j] + wv.y*e[j+1] + wv.z*e[j+2] + wv.w*e[j+3];
    }
    lencb[(b*S_ + s0 + sl)*ATT_ + a] = acc;
  }
}

// ---------------- persistent decoder
// r11 surgical cuts to the serial-latency chain (cold==warm dispatch timing
// proved the critical path is fixed latency, not bandwidth):
//  - bias sums hoisted to LDS (bsum_s) once: the GEMV reduce epilogues lose
//    ~80 divergent global bias loads per block-step.
//  - g0pre/g1pre rotate (fresh slot per step): attn blocks' P2/P3 LSTM
//    assembly reads become plain cached loads instead of waited sc LLC RTs.
__launch_bounds__(512, 1)
__global__ void decoder_kernel(
    const float* __restrict__ melpre, const float* __restrict__ lencb,
    const float* __restrict__ weff,
    float* __restrict__ h1buf, float* __restrict__ albuf, float* __restrict__ h0st,
    float* __restrict__ g0pre, float* __restrict__ g1pre, u32* __restrict__ bar,
    const float* __restrict__ enc, const int* __restrict__ tlen,
    const u16* __restrict__ Wqh, const float* __restrict__ wsc,
    const u16* __restrict__ Wih0h, const u16* __restrict__ Whh0h,
    const u16* __restrict__ Wih1h, const u16* __restrict__ Whh1h,
    const float* __restrict__ bih0, const float* __restrict__ bhh0,
    const float* __restrict__ bih1, const float* __restrict__ bhh1,
    const float* __restrict__ c0in, const float* __restrict__ projW, const float* __restrict__ projb,
    float* __restrict__ out_mel, float* __restrict__ out_stop, float* __restrict__ out_attn)
{
  extern __shared__ float xt[];
  __shared__ float red_s[1];
  __shared__ float gv[256];    // P2/P3 GEMV reduction
  __shared__ float gv0[256];   // gates0 pre (own rows), persists P1->P2
  __shared__ float gv1[256];   // gates1 pre (own rows), persists P1->P3
  __shared__ float q_s[ATT_];
  __shared__ float spf[S_*4];  // P1 score partials; P3 proj partials
  __shared__ float score_s[S_];
  __shared__ float attn_s[S_];
  __shared__ float bsum_s[2][20];  // bias sums: [g][ri*4+rg] rows, [g][16+rg] proxy

  // attn-block persistent overlays in dynamic LDS, above P3 staging reach (16504)
  float* const cum_p = xt + AOFF;          // [190]
  float* const projx = xt + AOFF + 192;    // [1536]
  float* const wscs  = xt + AOFF + 1728;   // [128]
  u16* const wl = (u16*)(xt + WLDS);       // compute blocks: 128 chunks x 256 bf16

  const int blk = blockIdx.x;
  const int tid = threadIdx.x;
  const int ks = tid & 63;
  const int bgb = ((tid >> 6) & 1)*8;
  const int rg = tid >> 7;
  const int j0 = blk*4;
  const bool hg0 = (blk >= 16 && blk < 80);
  const bool hg1 = (blk >= 80 && blk < 144);
  const int jx0 = blk - 16;
  const int jx1 = blk - 80;

  float c0r = 0.0f, c1r = 0.0f;
  if (tid < 64) {
    const int j = j0 + (tid >> 4);
    c0r = c0in[j];
    c1r = c0in[DIM_ + j];
  }
  int mylen = 0;
  if (blk < B_) {
    mylen = tlen[blk];
    for (int i = tid; i < S_ + 30; i += 512) cum_p[i] = 0.0f;
    if (tid < ATT_) wscs[tid] = wsc[tid];
  } else {
    // pin this block's Wih1 (chunks 0..63) and Whh1 (chunks 64..127) rows,
    // bf16, chunked so lane ks reads chunk c at [c*256 + ks*4] (8B).
    for (int i = tid; i < 8192; i += 512) {
      const int c = i >> 6, l = i & 63;
      const int m = c >> 6, cm = c & 63;
      const int ri = cm >> 4, rgw = (cm >> 2) & 3, q = cm & 3;
      const u16* src = (m ? Whh1h : Wih1h) + (ri*1024 + j0 + rgw)*1024 + q*256 + l*4;
      *(uint2*)(wl + c*256 + l*4) = *(const uint2*)src;
    }
    // bias sums once (LDS, zero VGPR cost; epilogues read via broadcast)
    if (tid < 16) {
      const int ri = tid >> 2, rgw = tid & 3;
      const int n = ri*1024 + j0 + rgw;
      bsum_s[0][tid] = bih0[n] + bhh0[n];
      bsum_s[1][tid] = bih1[n] + bhh1[n];
    } else if (tid < 20) {
      const int rgw = tid - 16;
      const int n0 = rgw*1024 + ((jx0 < 64) ? jx0 : 0);
      const int n1 = rgw*1024 + (hg1 ? jx1 : 0);
      bsum_s[0][16 + rgw] = bih0[n0] + bhh0[n0];
      bsum_s[1][16 + rgw] = bih1[n1] + bhh1[n1];
    }
  }
  __syncthreads();

  u32 ep = 0;

  for (int t = 0; t < T_; ++t) {
    //====================== P1 ======================
    if (blk < B_) {
      const int b = blk;
      // stage [h1(t) | align(t-1)] into projx (plain cached loads; slots cold)
      if (tid < 256) {
        *(float4*)(projx + tid*4) =
            *(const float4*)(h1buf + t*HSLOT + b*DIM_ + tid*4);
      } else if (tid < 384) {
        const int j = tid - 256;
        const int ap = (t > 0) ? (t-1) : 0;   // t=0 value unused (proj guarded)
        *(float4*)(projx + 1024 + j*4) =
            *(const float4*)(albuf + ap*ASLOT + b*ENC_ + j*4);
      }
      __syncthreads();
      // q = h1prev @ Wq^T (bf16 weights)
      {
        const int a = tid & 127, part = tid >> 7;
        const float* hp = projx + part*256;
        const u16* wq = Wqh + a*DIM_ + part*256;
        float acc = 0.0f;
        for (int j = 0; j < 256; j += 4) {
          const float4 wv = bf4(wq + j);
          const float4 hv = *(const float4*)(hp + j);
          acc += wv.x*hv.x + wv.y*hv.y + wv.z*hv.z + wv.w*hv.w;
        }
        spf[a*4 + part] = acc;
      }
      __syncthreads();
      if (tid < ATT_) q_s[tid] = spf[tid*4] + spf[tid*4+1] + spf[tid*4+2] + spf[tid*4+3];
      __syncthreads();
      // scores: loc-conv taps from GLOBAL weff (L1-resident, wave-uniform)
      {
        const int sl = tid & 127, ag = tid >> 7;
        const int a0 = ag*32;
        #pragma unroll
        for (int p = 0; p < 2; ++p) {
          const int s = sl + p*128;
          if (s < S_) {
            float cw[32];
            #pragma unroll
            for (int k = 0; k < 31; ++k) cw[k] = cum_p[s + k];
            cw[31] = 0.0f;
            const float* le = lencb + (b*S_ + s)*ATT_ + a0;
            const float* wr = weff + a0*32;
            float ps = 0.0f;
            for (int i4 = 0; i4 < 8; ++i4) {
              const float4 lev = *(const float4*)(le + i4*4);
              #pragma unroll
              for (int ii = 0; ii < 4; ++ii) {
                const int i = i4*4 + ii;
                const float4* wk4 = (const float4*)(wr + i*32);
                float loc = 0.0f;
                #pragma unroll
                for (int kq = 0; kq < 8; ++kq) {
                  const float4 wv = wk4[kq];
                  loc += wv.x*cw[kq*4+0] + wv.y*cw[kq*4+1] + wv.z*cw[kq*4+2] + wv.w*cw[kq*4+3];
                }
                const float lef = (ii==0)?lev.x:(ii==1)?lev.y:(ii==2)?lev.z:lev.w;
                ps += wscs[a0 + i]*ftanhf(q_s[a0 + i] + lef + loc);
              }
            }
            spf[s*4 + ag] = ps;
          }
        }
      }
      __syncthreads();
      if (tid < S_) {
        float sc = spf[tid*4] + spf[tid*4+1] + spf[tid*4+2] + spf[tid*4+3];
        if (tid >= mylen) sc = -1.0e30f;
        score_s[tid] = sc;
      }
      __syncthreads();
      if (tid < 64) {
        float m = -1.0e30f;
        for (int i = tid; i < S_; i += 64) m = fmaxf(m, score_s[i]);
        #pragma unroll
        for (int o = 32; o > 0; o >>= 1) m = fmaxf(m, __shfl_xor(m, o, 64));
        float sum = 0.0f;
        for (int i = tid; i < S_; i += 64) {
          const float e = fexp2f(1.442695041f*(score_s[i] - m));
          score_s[i] = e;
          sum += e;
        }
        #pragma unroll
        for (int o = 32; o > 0; o >>= 1) sum += __shfl_xor(sum, o, 64);
        if (tid == 0) red_s[0] = sum;
      }
      __syncthreads();
      {
        const float inv = 1.0f / red_s[0];
        if (tid < S_) {
          const float av = score_s[tid]*inv;
          attn_s[tid] = av;
          cum_p[15 + tid] += av;
          out_attn[(b*S_ + tid)*T_ + t] = av;
        }
      }
      __syncthreads();
      // align = attn @ enc -> albuf slot t (sc1 write)
      {
        const float* eb = enc + (b*S_)*ENC_ + tid;
        float acc = 0.0f;
        for (int s = 0; s < S_; ++s) acc += attn_s[s]*eb[s*ENC_];
        st_sys(albuf + t*ASLOT + b*ENC_ + tid, acc);
      }
    } else {
      // ---- stage [mel | h0(t-1)=slot t] tile (plain loads)
      for (int i = tid; i < 1024; i += 512) {
        float4 v = *(const float4*)(melpre + t*4096 + i*4);
        *(float4*)(xt + (i>>6)*XST1 + (i&63)*4) = v;
      }
      {
        const float* src = h0st + t*HSLOT;
        float4 r[8];
        #pragma unroll
        for (int u = 0; u < 8; ++u) r[u] = *(const float4*)(src + (tid + u*512)*4);
        #pragma unroll
        for (int u = 0; u < 8; ++u) {
          const int i = tid + u*512;
          *(float4*)(xt + (i>>8)*XST1 + 256 + (i&255)*4) = r[u];
        }
      }
      __syncthreads();
      // ---- GEMV-a: gates0 pre = Wih0[:, :256]@mel + Whh0@h0prev (+biases)
      // batch-split into 2 halves of 4 to stay under 128 VGPR (no spills).
      {
        const int nr = hg0 ? 5 : 4;
        int nrow[5];
        #pragma unroll
        for (int ri = 0; ri < 4; ++ri) nrow[ri] = ri*1024 + j0 + rg;
        nrow[4] = rg*1024 + ((jx0 < 64) ? jx0 : 0);
        #pragma unroll
        for (int hf = 0; hf < 2; ++hf) {
          const int b0 = bgb + hf*4;
          float acc[5][4];
          #pragma unroll
          for (int ri = 0; ri < 5; ++ri)
            #pragma unroll
            for (int bi = 0; bi < 4; ++bi) acc[ri][bi] = 0.0f;
          { // mel chunk
            const int j = ks*4;
            float4 w4[5];
            #pragma unroll
            for (int ri = 0; ri < 5; ++ri)
              if (ri < nr) w4[ri] = bf4(Wih0h + nrow[ri]*768 + j);
            #pragma unroll
            for (int bi = 0; bi < 4; ++bi) {
              const float4 xv = *(const float4*)(xt + (b0+bi)*XST1 + j);
              #pragma unroll
              for (int ri = 0; ri < 5; ++ri)
                if (ri < nr)
                  acc[ri][bi] += w4[ri].x*xv.x + w4[ri].y*xv.y + w4[ri].z*xv.z + w4[ri].w*xv.w;
            }
          }
          #pragma unroll
          for (int q = 0; q < 4; ++q) { // h0 chunks
            const int j = q*256 + ks*4;
            float4 w4[5];
            #pragma unroll
            for (int ri = 0; ri < 5; ++ri)
              if (ri < nr) w4[ri] = bf4(Whh0h + nrow[ri]*1024 + j);
            #pragma unroll
            for (int bi = 0; bi < 4; ++bi) {
              const float4 xv = *(const float4*)(xt + (b0+bi)*XST1 + 256 + j);
              #pragma unroll
              for (int ri = 0; ri < 5; ++ri)
                if (ri < nr)
                  acc[ri][bi] += w4[ri].x*xv.x + w4[ri].y*xv.y + w4[ri].z*xv.z + w4[ri].w*xv.w;
            }
          }
          #pragma unroll
          for (int ri = 0; ri < 5; ++ri)
            if (ri < nr)
              #pragma unroll
              for (int bi = 0; bi < 4; ++bi) {
                float v = acc[ri][bi];
                REDUCE64(v);
                if (ks == 63) {
                  v += (ri < 4) ? bsum_s[0][ri*4 + rg] : bsum_s[0][16 + rg];
                  if (ri < 4) gv0[(ri*4 + rg)*16 + (b0+bi)] = v;
                  else        st_sys(g0pre + t*GSLOT + (b0+bi)*256 + jx0*4 + rg, v);
                }
              }
        }
      }
      __syncthreads();
      // ---- stage h1(t) = slot t (plain loads)
      {
        const float* src = h1buf + t*HSLOT;
        float4 r[8];
        #pragma unroll
        for (int u = 0; u < 8; ++u) r[u] = *(const float4*)(src + (tid + u*512)*4);
        #pragma unroll
        for (int u = 0; u < 8; ++u) {
          const int i = tid + u*512;
          *(float4*)(xt + (i>>8)*XST1 + (i&255)*4) = r[u];
        }
      }
      __syncthreads();
      // ---- GEMV-b: gates1 pre = Whh1@h1prev (+biases); rows 0..3 from LDS bf16
      {
        const int nr = hg1 ? 5 : 4;
        const int nprox = rg*1024 + (hg1 ? jx1 : 0);
        #pragma unroll
        for (int hf = 0; hf < 2; ++hf) {
          const int b0 = bgb + hf*4;
          float acc[5][4];
          #pragma unroll
          for (int ri = 0; ri < 5; ++ri)
            #pragma unroll
            for (int bi = 0; bi < 4; ++bi) acc[ri][bi] = 0.0f;
          #pragma unroll
          for (int q = 0; q < 4; ++q) {
            const int j = q*256 + ks*4;
            float4 w4[5];
            #pragma unroll
            for (int ri = 0; ri < 4; ++ri)
              w4[ri] = bf4(wl + (64 + (ri*4 + rg)*4 + q)*256 + ks*4);
            if (nr == 5) w4[4] = bf4(Whh1h + nprox*1024 + j);
            #pragma unroll
            for (int bi = 0; bi < 4; ++bi) {
              const float4 xv = *(const float4*)(xt + (b0+bi)*XST1 + j);
              #pragma unroll
              for (int ri = 0; ri < 5; ++ri)
                if (ri < nr)
                  acc[ri][bi] += w4[ri].x*xv.x + w4[ri].y*xv.y + w4[ri].z*xv.z + w4[ri].w*xv.w;
            }
          }
          #pragma unroll
          for (int ri = 0; ri < 5; ++ri)
            if (ri < nr)
              #pragma unroll
              for (int bi = 0; bi < 4; ++bi) {
                float v = acc[ri][bi];
                REDUCE64(v);
                if (ks == 63) {
                  v += (ri < 4) ? bsum_s[1][ri*4 + rg] : bsum_s[1][16 + rg];
                  if (ri < 4) gv1[(ri*4 + rg)*16 + (b0+bi)] = v;
                  else        st_sys(g1pre + t*GSLOT + (b0+bi)*256 + jx1*4 + rg, v);
                }
              }
        }
      }
    }
    gridbar(bar, tid, blk, ep); ++ep;

    //====================== P2: gates0 align part + LSTM0 ======================
    {
      { // stage align slot t (plain loads)
        const float* src = albuf + t*ASLOT;
        float4 r[4];
        #pragma unroll
        for (int u = 0; u < 4; ++u) r[u] = *(const float4*)(src + (tid + u*512)*4);
        #pragma unroll
        for (int u = 0; u < 4; ++u) {
          const int i = tid + u*512;
          *(float4*)(xt + (i>>7)*XST2 + (i&127)*4) = r[u];
        }
      }
      __syncthreads();
      float acc[4][8];
      #pragma unroll
      for (int ri = 0; ri < 4; ++ri)
        #pragma unroll
        for (int bi = 0; bi < 8; ++bi) acc[ri][bi] = 0.0f;
      #pragma unroll
      for (int q = 0; q < 2; ++q) {
        const int j = q*256 + ks*4;
        float4 w4[4];
        #pragma unroll
        for (int ri = 0; ri < 4; ++ri)
          w4[ri] = bf4(Wih0h + (ri*1024 + j0 + rg)*768 + 256 + j);
        #pragma unroll
        for (int bi = 0; bi < 8; ++bi) {
          const float4 xv = *(const float4*)(xt + (bgb+bi)*XST2 + j);
          #pragma unroll
          for (int ri = 0; ri < 4; ++ri)
            acc[ri][bi] += w4[ri].x*xv.x + w4[ri].y*xv.y + w4[ri].z*xv.z + w4[ri].w*xv.w;
        }
      }
      #pragma unroll
      for (int ri = 0; ri < 4; ++ri)
        #pragma unroll
        for (int bi = 0; bi < 8; ++bi) {
          float v = acc[ri][bi];
          REDUCE64(v);
          if (ks == 63) gv[(rg*4 + ri)*16 + (bgb+bi)] = v;
        }
      __syncthreads();
      if (tid < 64) {
        const int jl = tid >> 4, bb = tid & 15;
        const int j = j0 + jl;
        float pi, pf, pg, po;
        if (blk < B_) {
          const float4 g4 = *(const float4*)(g0pre + t*GSLOT + bb*256 + j*4);
          pi = g4.x; pf = g4.y; pg = g4.z; po = g4.w;
        } else {
          pi = gv0[(0*4 + jl)*16 + bb];
          pf = gv0[(1*4 + jl)*16 + bb];
          pg = gv0[(2*4 + jl)*16 + bb];
          po = gv0[(3*4 + jl)*16 + bb];
        }
        const float gi = gv[(jl*4+0)*16 + bb] + pi;
        const float gf = gv[(jl*4+1)*16 + bb] + pf;
        const float gg = gv[(jl*4+2)*16 + bb] + pg;
        const float go = gv[(jl*4+3)*16 + bb] + po;
        const float cn = fsigf(gf)*c0r + fsigf(gi)*ftanhf(gg);
        const float hn = fsigf(go)*ftanhf(cn);
        c0r = cn;
        st_sys(h0st + (t+1)*HSLOT + bb*DIM_ + j, hn);   // h0(t) -> slot t+1
      }
    }
    gridbar(bar, tid, blk, ep); ++ep;

    //====================== P3: gates1 Wih1@h0 + LSTM1 (+proj for attn blocks) ======================
    {
      { // stage h0(t) = slot t+1 (plain loads)
        const float* src = h0st + (t+1)*HSLOT;
        float4 r[8];
        #pragma unroll
        for (int u = 0; u < 8; ++u) r[u] = *(const float4*)(src + (tid + u*512)*4);
        #pragma unroll
        for (int u = 0; u < 8; ++u) {
          const int i = tid + u*512;
          *(float4*)(xt + (i>>8)*XST3 + (i&255)*4) = r[u];
        }
      }
      __syncthreads();
      float acc[4][8];
      #pragma unroll
      for (int ri = 0; ri < 4; ++ri)
        #pragma unroll
        for (int bi = 0; bi < 8; ++bi) acc[ri][bi] = 0.0f;
      #pragma unroll
      for (int q = 0; q < 4; ++q) {
        const int j = q*256 + ks*4;
        float4 w4[4];
        if (blk < B_) {
          #pragma unroll
          for (int ri = 0; ri < 4; ++ri)
            w4[ri] = bf4(Wih1h + (ri*1024 + j0 + rg)*1024 + j);
        } else {
          #pragma unroll
          for (int ri = 0; ri < 4; ++ri)
            w4[ri] = bf4(wl + (((ri*4 + rg)*4 + q) << 8) + ks*4);
        }
        #pragma unroll
        for (int bi = 0; bi < 8; ++bi) {
          const float4 xv = *(const float4*)(xt + (bgb+bi)*XST3 + j);
          #pragma unroll
          for (int ri = 0; ri < 4; ++ri)
            acc[ri][bi] += w4[ri].x*xv.x + w4[ri].y*xv.y + w4[ri].z*xv.z + w4[ri].w*xv.w;
        }
      }
      #pragma unroll
      for (int ri = 0; ri < 4; ++ri)
        #pragma unroll
        for (int bi = 0; bi < 8; ++bi) {
          float v = acc[ri][bi];
          REDUCE64(v);
          if (ks == 63) gv[(rg*4 + ri)*16 + (bgb+bi)] = v;
        }
      __syncthreads();
      if (tid < 64) {
        const int jl = tid >> 4, bb = tid & 15;
        const int j = j0 + jl;
        float pi, pf, pg, po;
        if (blk < B_) {
          const float4 g4 = *(const float4*)(g1pre + t*GSLOT + bb*256 + j*4);
          pi = g4.x; pf = g4.y; pg = g4.z; po = g4.w;
        } else {
          pi = gv1[(0*4 + jl)*16 + bb];
          pf = gv1[(1*4 + jl)*16 + bb];
          pg = gv1[(2*4 + jl)*16 + bb];
          po = gv1[(3*4 + jl)*16 + bb];
        }
        const float gi = gv[(jl*4+0)*16 + bb] + pi;
        const float gf = gv[(jl*4+1)*16 + bb] + pf;
        const float gg = gv[(jl*4+2)*16 + bb] + pg;
        const float go = gv[(jl*4+3)*16 + bb] + po;
        const float cn = fsigf(gf)*c1r + fsigf(gi)*ftanhf(gg);
        const float hn = fsigf(go)*ftanhf(cn);
        c1r = cn;
        st_sys(h1buf + (t+1)*HSLOT + bb*DIM_ + j, hn);  // h1(t) -> slot t+1
      }
      // projection of step t-1 (attn blocks; inputs staged in projx during P1)
      if (blk < B_ && t > 0) {
        const int b = blk;
        const int o = tid >> 2, part = tid & 3;
        if (o < 81) {
          const float* w = projW + o*1536;
          const int jb = part*384;
          float acc2 = 0.0f;
          for (int j = jb; j < jb + 384; j += 4) {
            const float4 wv = *(const float4*)(w + j);
            const float4 xv = *(const float4*)(projx + j);
            acc2 += wv.x*xv.x + wv.y*xv.y + wv.z*xv.z + wv.w*xv.w;
          }
          spf[o*4 + part] = acc2;
        }
        __syncthreads();
        if (tid < 81) {
          const float v = projb[tid] + spf[tid*4] + spf[tid*4+1] + spf[tid*4+2] + spf[tid*4+3];
          if (tid < 80) out_mel[(b*NMEL_ + tid)*T_ + (t-1)] = v;
          else          out_stop[b*T_ + (t-1)] = v;
        }
      }
    }
    gridbar(bar, tid, blk, ep); ++ep;
  }

  // ---- tail projection for t = T_-1 (h1 slot 300, align slot 299)
  if (blk < B_) {
    const int b = blk;
    if (tid < 256) {
      *(float4*)(projx + tid*4) =
          *(const float4*)(h1buf + 300*HSLOT + b*DIM_ + tid*4);
    } else if (tid < 384) {
      const int j = tid - 256;
      *(float4*)(projx + 1024 + j*4) =
          *(const float4*)(albuf + 299*ASLOT + b*ENC_ + j*4);
    }
    __syncthreads();
    const int o = tid >> 2, part = tid & 3;
    if (o < 81) {
      const float* w = projW + o*1536;
      const int jb = part*384;
      float acc = 0.0f;
      for (int j = jb; j < jb + 384; j += 4) {
        const float4 wv = *(const float4*)(w + j);
        const float4 xv = *(const float4*)(projx + j);
        acc += wv.x*xv.x + wv.y*xv.y + wv.z*xv.z + wv.w*xv.w;
      }
      spf[o*4 + part] = acc;
    }
    __syncthreads();
    if (tid < 81) {
      const float v = projb[tid] + spf[tid*4] + spf[tid*4+1] + spf[tid*4+2] + spf[tid*4+3];
      if (tid < 80) out_mel[(b*NMEL_ + tid)*T_ + (T_-1)] = v;
      else          out_stop[b*T_ + (T_-1)] = v;
    }
  }
}

extern "C" void kernel_launch(void* const* d_in, const int* in_sizes, int n_in,
                              void* d_out, int out_size, void* d_ws, size_t ws_size,
                              hipStream_t stream) {
  const float* mels  = (const float*)d_in[0];
  const float* enc   = (const float*)d_in[1];
  const int*   tlen  = (const int*)d_in[2];
  const float* Wt    = (const float*)d_in[3];
  const float* Wq    = (const float*)d_in[4];
  const float* wsc   = (const float*)d_in[5];
  const float* conv1 = (const float*)d_in[6];
  const float* conv2 = (const float*)d_in[7];
  const float* pW1   = (const float*)d_in[8];
  const float* pb1   = (const float*)d_in[9];
  const float* pW2   = (const float*)d_in[10];
  const float* pb2   = (const float*)d_in[11];
  const float* Wih0  = (const float*)d_in[12];
  const float* Whh0  = (const float*)d_in[13];
  const float* bih0  = (const float*)d_in[14];
  const float* bhh0  = (const float*)d_in[15];
  const float* Wih1  = (const float*)d_in[16];
  const float* Whh1  = (const float*)d_in[17];
  const float* bih1  = (const float*)d_in[18];
  const float* bhh1  = (const float*)d_in[19];
  const float* h0    = (const float*)d_in[20];
  const float* c0    = (const float*)d_in[21];
  const float* projW = (const float*)d_in[22];
  const float* projb = (const float*)d_in[23];

  float* ws     = (float*)d_ws;
  float* melpre = ws;                   // 1,228,800
  float* lencb  = melpre + 1228800;     //   327,680
  float* weff   = lencb + 327680;       //     4,096
  float* h1buf  = weff + 4096;          // 301*16384 = 4,931,584
  float* albuf  = h1buf + 301*16384;    // 300*8192  = 2,457,600
  float* h0st   = albuf + 300*8192;     // 301*16384 = 4,931,584
  float* g0pre  = h0st + 301*16384;     // 300*4096  = 1,228,800
  float* g1pre  = g0pre + 300*4096;     // 300*4096  = 1,228,800
  u32*   bar    = (u32*)(g1pre + 300*4096); // 17,408 words
  u16*   Wih0h  = (u16*)(bar + BARWORDS);   // 4096*768  bf16
  u16*   Whh0h  = Wih0h + 4096*768;         // 4096*1024 bf16
  u16*   Wih1h  = Whh0h + 4096*1024;        // 4096*1024 bf16
  u16*   Whh1h  = Wih1h + 4096*1024;        // 4096*1024 bf16
  u16*   Wqh    = Whh1h + 4096*1024;        // 128*1024  bf16 (~97 MB ws total)

  float* out_mel  = (float*)d_out;
  float* out_stop = out_mel + 384000;
  float* out_attn = out_stop + 4800;

  prenet_kernel<<<dim3(480), dim3(256), 0, stream>>>(mels, pW1, pb1, pW2, pb2, melpre);
  init_kernel<<<dim3(160), dim3(256), 0, stream>>>(h0, conv1, conv2, h1buf, h0st, weff, bar);
  wcvt_kernel<<<dim3(2048), dim3(256), 0, stream>>>(Wih0, Whh0, Wih1, Whh1, Wq,
                                                    Wih0h, Whh0h, Wih1h, Whh1h, Wqh);
  lenc_kernel<<<dim3(640), dim3(256), 0, stream>>>(enc, Wt, lencb);

  void* args[] = {
    (void*)&melpre, (void*)&lencb, (void*)&weff, (void*)&h1buf, (void*)&albuf, (void*)&h0st,
    (void*)&g0pre, (void*)&g1pre, (void*)&bar,
    (void*)&enc, (void*)&tlen, (void*)&Wqh, (void*)&wsc,
    (void*)&Wih0h, (void*)&Whh0h, (void*)&Wih1h, (void*)&Whh1h,
    (void*)&bih0, (void*)&bhh0, (void*)&bih1, (void*)&bhh1,
    (void*)&c0, (void*)&projW, (void*)&projb,
    (void*)&out_mel, (void*)&out_stop, (void*)&out_attn
  };
  hipLaunchCooperativeKernel((const void*)decoder_kernel, dim3(256), dim3(512),
                             args, (unsigned int)(XTOT*sizeof(float)), stream);
}

// Round 12
// 30139.438 us; speedup vs baseline: 1.5966x; 1.0133x over previous
//
#include <hip/hip_runtime.h>

#define T_    300
#define B_    16
#define S_    160
#define NMEL_ 80
#define PRE_  256
#define ENC_  512
#define ATT_  128
#define DIM_  1024

#define XST1  1288     // P1 tile stride (mel 256 + h0 1024 + pad 8); rows end at 20600
#define XST2  520      // P2 align tile stride (ends 8320)
#define XST3  1032     // P3 h0 tile stride (ends 16504)
#define AOFF  16512    // attn blocks: persistent arrays (cum_p, projx, wscs) — above staging
#define WLDS  20608    // compute blocks: pinned bf16 Wih1+Whh1 (2 x 16 rows x 1024 = 64 KB)
#define XTOT  36992    // dynamic LDS floats (148 KB)
#define BARWORDS 17408

#define HSLOT (B_*DIM_)   // 16384 floats / slot (h0st, h1buf)
#define ASLOT (B_*ENC_)   // 8192 floats / slot (albuf)
#define GSLOT (B_*256)    // 4096 floats / slot (g0pre, g1pre)

typedef unsigned int u32;
typedef unsigned short u16;

__device__ __forceinline__ float fexp2f(float x) { return __builtin_amdgcn_exp2f(x); }
__device__ __forceinline__ float fsigf(float x)  { return 1.0f / (1.0f + fexp2f(-1.442695041f * x)); }
__device__ __forceinline__ float ftanhf(float x) {
  float xc = fminf(fmaxf(x, -15.0f), 15.0f);
  float e = fexp2f(2.885390082f * xc);
  return (e - 1.0f) / (e + 1.0f);
}

__device__ __forceinline__ u16 f2bf(float f) {
  u32 b = __float_as_uint(f);
  return (u16)((b + 0x7fffu + ((b >> 16) & 1u)) >> 16);
}
__device__ __forceinline__ float4 bf4(const u16* p) {
  const uint2 u = *(const uint2*)p;
  float4 w;
  w.x = __uint_as_float(u.x << 16);
  w.y = __uint_as_float(u.x & 0xffff0000u);
  w.z = __uint_as_float(u.y << 16);
  w.w = __uint_as_float(u.y & 0xffff0000u);
  return w;
}

__device__ __forceinline__ float4 ld1q_sys(const float* p) {
  float4 v;
  asm volatile("global_load_dwordx4 %0, %1, off sc0 sc1\n\ts_waitcnt vmcnt(0)"
               : "=v"(v) : "v"(p) : "memory");
  return v;
}
__device__ __forceinline__ void st_sys(float* p, float v) {
  asm volatile("global_store_dword %0, %1, off sc0 sc1" :: "v"(p), "v"(v) : "memory");
}
__device__ __forceinline__ u32 ld_sys_u32(const u32* p) {
  u32 r;
  asm volatile("global_load_dword %0, %1, off sc0 sc1\n\ts_waitcnt vmcnt(0)"
               : "=v"(r) : "v"(p) : "memory");
  return r;
}
__device__ __forceinline__ void st_sys_u32(u32* p, u32 v) {
  asm volatile("global_store_dword %0, %1, off sc0 sc1" :: "v"(p), "v"(v) : "memory");
}

// monotone counter poll: proceed when *p >= tgt
__device__ __forceinline__ void poll_ge(const u32* p, u32 tgt) {
  while ((int)(ld_sys_u32(p) - tgt) < 0) __builtin_amdgcn_s_sleep(1);
}

// ---- split-phase grid barrier (16x16 tree arrival, wide 16-line release).
// arrive: drain + syncthreads + tid0 signals (and possibly writes releases).
// wait:   tid0 polls its group's release word, then syncthreads.
// Independent per-block work may run between arrive and wait.
__device__ __forceinline__ void gb_arrive(u32* bar, int tid, int blk, u32 ep) {
  asm volatile("s_waitcnt vmcnt(0)" ::: "memory");
  __syncthreads();
  if (tid == 0) {
    const int g = blk & 15;
    u32* cnt  = bar + g*1024;
    u32* tcnt = bar + 16384;
    const u32 tgt = ep*16u + 15u;
    u32 old = __hip_atomic_fetch_add(cnt, 1u, __ATOMIC_RELAXED, __HIP_MEMORY_SCOPE_AGENT);
    if (old == tgt) {
      u32 told = __hip_atomic_fetch_add(tcnt, 1u, __ATOMIC_RELAXED, __HIP_MEMORY_SCOPE_AGENT);
      if (told == tgt) {
        #pragma unroll
        for (int g2 = 0; g2 < 16; ++g2) st_sys_u32(bar + g2*1024 + 64, ep + 1u);
      }
    }
  }
}
__device__ __forceinline__ void gb_wait(u32* bar, int tid, int blk, u32 ep) {
  if (tid == 0) {
    const u32* grel = bar + (blk & 15)*1024 + 64;
    poll_ge(grel, ep + 1u);
  }
  __syncthreads();
}

// ---- wave-64 sum via DPP
#define DPP_ADD(v, ctrl, rmask) do { \
  int _t = __builtin_amdgcn_update_dpp(0, __float_as_int(v), (ctrl), (rmask), 0xf, false); \
  (v) += __int_as_float(_t); } while (0)

#define REDUCE64(v) do { \
  DPP_ADD(v, 0x111, 0xf); \
  DPP_ADD(v, 0x112, 0xf); \
  DPP_ADD(v, 0x114, 0xf); \
  DPP_ADD(v, 0x118, 0xf); \
  DPP_ADD(v, 0x142, 0xa); \
  DPP_ADD(v, 0x143, 0x8); } while (0)

// ---------------- prenet
__launch_bounds__(256)
__global__ void prenet_kernel(const float* __restrict__ mels,
                              const float* __restrict__ pW1, const float* __restrict__ pb1,
                              const float* __restrict__ pW2, const float* __restrict__ pb2,
                              float* __restrict__ melpre) {
  __shared__ float mcol[NMEL_];
  __shared__ float pcol[PRE_];
  const int b = blockIdx.x / 30;
  const int tbase = (blockIdx.x % 30) * 10;
  const int tid = threadIdx.x;
  for (int f = 0; f < 10; ++f) {
    const int t = tbase + f;
    if (tid < NMEL_) mcol[tid] = (t == 0) ? 0.0f : mels[(b*NMEL_ + tid)*T_ + (t-1)];
    __syncthreads();
    {
      float a1 = pb1[tid];
      const float* w1 = pW1 + tid*NMEL_;
      for (int m = 0; m < NMEL_; ++m) a1 += w1[m]*mcol[m];
      pcol[tid] = fmaxf(a1, 0.0f);
    }
    __syncthreads();
    {
      float a2 = pb2[tid];
      const float* w2 = pW2 + tid*PRE_;
      for (int d = 0; d < PRE_; d += 4) {
        const float4 wv = *(const float4*)(w2 + d);
        a2 += wv.x*pcol[d] + wv.y*pcol[d+1] + wv.z*pcol[d+2] + wv.w*pcol[d+3];
      }
      melpre[(t*B_ + b)*PRE_ + tid] = fmaxf(a2, 0.0f);
    }
    __syncthreads();
  }
}

// ---------------- init
__launch_bounds__(256)
__global__ void init_kernel(const float* __restrict__ h0,
                            const float* __restrict__ conv1, const float* __restrict__ conv2,
                            float* __restrict__ h1buf, float* __restrict__ h0st,
                            float* __restrict__ weff, u32* __restrict__ bar) {
  const int idx = blockIdx.x*256 + threadIdx.x;
  if (idx < B_*DIM_) {
    const int j = idx & (DIM_-1);
    h0st[idx]  = h0[j];
    h1buf[idx] = h0[DIM_ + j];
  } else if (idx < B_*DIM_ + ATT_*32) {
    const int r = idx - B_*DIM_;
    const int a = r >> 5, k = r & 31;
    float acc = 0.0f;
    if (k < 31) {
      for (int l = 0; l < 32; ++l) acc += conv2[a*32 + l]*conv1[l*31 + k];
    }
    weff[r] = acc;
  } else if (idx < B_*DIM_ + ATT_*32 + BARWORDS) {
    bar[idx - (B_*DIM_ + ATT_*32)] = 0u;
  }
}

// ---------------- weight conversion fp32 -> bf16 (RNE)
__launch_bounds__(256)
__global__ void wcvt_kernel(const float* __restrict__ Wih0, const float* __restrict__ Whh0,
                            const float* __restrict__ Wih1, const float* __restrict__ Whh1,
                            const float* __restrict__ Wq,
                            u16* __restrict__ Wih0h, u16* __restrict__ Whh0h,
                            u16* __restrict__ Wih1h, u16* __restrict__ Whh1h,
                            u16* __restrict__ Wqh) {
  const int n0 = 4096*768, n1 = 4096*1024, nq = ATT_*DIM_;
  const int stride = gridDim.x*256;
  for (int i = blockIdx.x*256 + threadIdx.x; i < n0; i += stride) Wih0h[i] = f2bf(Wih0[i]);
  for (int i = blockIdx.x*256 + threadIdx.x; i < n1; i += stride) {
    Whh0h[i] = f2bf(Whh0[i]);
    Wih1h[i] = f2bf(Wih1[i]);
    Whh1h[i] = f2bf(Whh1[i]);
  }
  for (int i = blockIdx.x*256 + threadIdx.x; i < nq; i += stride) Wqh[i] = f2bf(Wq[i]);
}

// ---------------- l_enc
__launch_bounds__(256)
__global__ void lenc_kernel(const float* __restrict__ enc, const float* __restrict__ Wt,
                            float* __restrict__ lencb) {
  __shared__ float es[4*ENC_];
  const int b = blockIdx.x / 40;
  const int s0 = (blockIdx.x % 40) * 4;
  const int tid = threadIdx.x;
  for (int idx = tid; idx < 4*ENC_; idx += 256) es[idx] = enc[(b*S_ + s0)*ENC_ + idx];
  __syncthreads();
  const int a = tid & 127, sh = tid >> 7;
  const float* w = Wt + a*ENC_;
  for (int p = 0; p < 2; ++p) {
    const int sl = sh*2 + p;
    const float* e = es + sl*ENC_;
    float acc = 0.0f;
    for (int j = 0; j < ENC_; j += 4) {
      const float4 wv = *(const float4*)(w + j);
      acc += wv.x*e[j] + wv.y*e[j+1] + wv.z*e[j+2] + wv.w*e[j+3];
    }
    lencb[(b*S_ + s0 + sl)*ATT_ + a] = acc;
  }
}

// ---------------- persistent decoder
// r12 sync-graph restructure (critical path = serial LLC RTs, proven by
// cold==warm deterministic timing):
//  - bar1 (P1->P2) replaced by: attn-done counter (16 arrivals, wide 16-line
//    release; P2 only needs the attn blocks' albuf) + hg0-done counter waited
//    ONLY by attn blocks late in P2 (g0pre; signaled right after GEMV-a,
//    off-critical). g1pre needs no counter: bar2-full orders it for P3.
//  - bar2/bar3 are split-phase (arrive || window || wait):
//    bar2 window (attn): projection(t-1) + out_attn(t) stores — off P1/P3.
//    bar3 window: compute pre-stage mel(t+1)+h0 slot t+1 (safe: written in
//    P2(t), ordered by bar2(t)); attn pre-stage albuf slot t into projx
//    (own data). P1 loses its staging stalls.
__launch_bounds__(512, 1)
__global__ void decoder_kernel(
    const float* __restrict__ melpre, const float* __restrict__ lencb,
    const float* __restrict__ weff,
    float* __restrict__ h1buf, float* __restrict__ albuf, float* __restrict__ h0st,
    float* __restrict__ g0pre, float* __restrict__ g1pre, u32* __restrict__ bar,
    const float* __restrict__ enc, const int* __restrict__ tlen,
    const u16* __restrict__ Wqh, const float* __restrict__ wsc,
    const u16* __restrict__ Wih0h, const u16* __restrict__ Whh0h,
    const u16* __restrict__ Wih1h, const u16* __restrict__ Whh1h,
    const float* __restrict__ bih0, const float* __restrict__ bhh0,
    const float* __restrict__ bih1, const float* __restrict__ bhh1,
    const float* __restrict__ c0in, const float* __restrict__ projW, const float* __restrict__ projb,
    float* __restrict__ out_mel, float* __restrict__ out_stop, float* __restrict__ out_attn)
{
  extern __shared__ float xt[];
  __shared__ float red_s[1];
  __shared__ float gv[256];
  __shared__ float gv0[256];
  __shared__ float gv1[256];
  __shared__ float q_s[ATT_];
  __shared__ float spf[S_*4];
  __shared__ float score_s[S_];
  __shared__ float attn_s[S_];
  __shared__ float bsum_s[2][20];

  float* const cum_p = xt + AOFF;          // [190]
  float* const projx = xt + AOFF + 192;    // [1536]
  float* const wscs  = xt + AOFF + 1728;   // [128]
  u16* const wl = (u16*)(xt + WLDS);

  const int blk = blockIdx.x;
  const int tid = threadIdx.x;
  const int ks = tid & 63;
  const int bgb = ((tid >> 6) & 1)*8;
  const int rg = tid >> 7;
  const int j0 = blk*4;
  const bool hg0 = (blk >= 16 && blk < 80);
  const bool hg1 = (blk >= 80 && blk < 144);
  const int jx0 = blk - 16;
  const int jx1 = blk - 80;

  // sync words (all inside the zeroed BARWORDS region)
  u32* const attn_cnt = bar + 16384 + 128;
  u32* const hg0_cnt  = bar + 16384 + 192;
  u32* const hg0rel   = bar + 16384 + 256;
  // per-group attn release words at bar + g*1024 + 128

  float c0r = 0.0f, c1r = 0.0f;
  if (tid < 64) {
    const int j = j0 + (tid >> 4);
    c0r = c0in[j];
    c1r = c0in[DIM_ + j];
  }
  int mylen = 0;
  if (blk < B_) {
    mylen = tlen[blk];
    for (int i = tid; i < S_ + 30; i += 512) cum_p[i] = 0.0f;
    if (tid < ATT_) wscs[tid] = wsc[tid];
  } else {
    for (int i = tid; i < 8192; i += 512) {
      const int c = i >> 6, l = i & 63;
      const int m = c >> 6, cm = c & 63;
      const int ri = cm >> 4, rgw = (cm >> 2) & 3, q = cm & 3;
      const u16* src = (m ? Whh1h : Wih1h) + (ri*1024 + j0 + rgw)*1024 + q*256 + l*4;
      *(uint2*)(wl + c*256 + l*4) = *(const uint2*)src;
    }
    if (tid < 16) {
      const int ri = tid >> 2, rgw = tid & 3;
      const int n = ri*1024 + j0 + rgw;
      bsum_s[0][tid] = bih0[n] + bhh0[n];
      bsum_s[1][tid] = bih1[n] + bhh1[n];
    } else if (tid < 20) {
      const int rgw = tid - 16;
      const int n0 = rgw*1024 + ((jx0 < 64) ? jx0 : 0);
      const int n1 = rgw*1024 + (hg1 ? jx1 : 0);
      bsum_s[0][16 + rgw] = bih0[n0] + bhh0[n0];
      bsum_s[1][16 + rgw] = bih1[n1] + bhh1[n1];
    }
    // prologue staging for P1(t=0): mel(0) + h0 slot 0
    for (int i = tid; i < 1024; i += 512) {
      float4 v = *(const float4*)(melpre + i*4);
      *(float4*)(xt + (i>>6)*XST1 + (i&63)*4) = v;
    }
    for (int u = 0; u < 8; ++u) {
      const int i = tid + u*512;
      *(float4*)(xt + (i>>8)*XST1 + 256 + (i&255)*4) = *(const float4*)(h0st + i*4);
    }
  }
  __syncthreads();

  u32 ep = 0;

  for (int t = 0; t < T_; ++t) {
    //====================== P1 ======================
    if (blk < B_) {
      const int b = blk;
      // stage h1(t) into projx[0..1024) (align part pre-staged in bar3 window)
      if (tid < 256) {
        *(float4*)(projx + tid*4) =
            *(const float4*)(h1buf + t*HSLOT + b*DIM_ + tid*4);
      }
      __syncthreads();
      // q = h1prev @ Wq^T (bf16)
      {
        const int a = tid & 127, part = tid >> 7;
        const float* hp = projx + part*256;
        const u16* wq = Wqh + a*DIM_ + part*256;
        float acc = 0.0f;
        for (int j = 0; j < 256; j += 4) {
          const float4 wv = bf4(wq + j);
          const float4 hv = *(const float4*)(hp + j);
          acc += wv.x*hv.x + wv.y*hv.y + wv.z*hv.z + wv.w*hv.w;
        }
        spf[a*4 + part] = acc;
      }
      __syncthreads();
      if (tid < ATT_) q_s[tid] = spf[tid*4] + spf[tid*4+1] + spf[tid*4+2] + spf[tid*4+3];
      __syncthreads();
      // scores
      {
        const int sl = tid & 127, ag = tid >> 7;
        const int a0 = ag*32;
        #pragma unroll
        for (int p = 0; p < 2; ++p) {
          const int s = sl + p*128;
          if (s < S_) {
            float cw[32];
            #pragma unroll
            for (int k = 0; k < 31; ++k) cw[k] = cum_p[s + k];
            cw[31] = 0.0f;
            const float* le = lencb + (b*S_ + s)*ATT_ + a0;
            const float* wr = weff + a0*32;
            float ps = 0.0f;
            for (int i4 = 0; i4 < 8; ++i4) {
              const float4 lev = *(const float4*)(le + i4*4);
              #pragma unroll
              for (int ii = 0; ii < 4; ++ii) {
                const int i = i4*4 + ii;
                const float4* wk4 = (const float4*)(wr + i*32);
                float loc = 0.0f;
                #pragma unroll
                for (int kq = 0; kq < 8; ++kq) {
                  const float4 wv = wk4[kq];
                  loc += wv.x*cw[kq*4+0] + wv.y*cw[kq*4+1] + wv.z*cw[kq*4+2] + wv.w*cw[kq*4+3];
                }
                const float lef = (ii==0)?lev.x:(ii==1)?lev.y:(ii==2)?lev.z:lev.w;
                ps += wscs[a0 + i]*ftanhf(q_s[a0 + i] + lef + loc);
              }
            }
            spf[s*4 + ag] = ps;
          }
        }
      }
      __syncthreads();
      if (tid < S_) {
        float sc = spf[tid*4] + spf[tid*4+1] + spf[tid*4+2] + spf[tid*4+3];
        if (tid >= mylen) sc = -1.0e30f;
        score_s[tid] = sc;
      }
      __syncthreads();
      if (tid < 64) {
        float m = -1.0e30f;
        for (int i = tid; i < S_; i += 64) m = fmaxf(m, score_s[i]);
        #pragma unroll
        for (int o = 32; o > 0; o >>= 1) m = fmaxf(m, __shfl_xor(m, o, 64));
        float sum = 0.0f;
        for (int i = tid; i < S_; i += 64) {
          const float e = fexp2f(1.442695041f*(score_s[i] - m));
          score_s[i] = e;
          sum += e;
        }
        #pragma unroll
        for (int o = 32; o > 0; o >>= 1) sum += __shfl_xor(sum, o, 64);
        if (tid == 0) red_s[0] = sum;
      }
      __syncthreads();
      {
        const float inv = 1.0f / red_s[0];
        if (tid < S_) {
          const float av = score_s[tid]*inv;
          attn_s[tid] = av;
          cum_p[15 + tid] += av;   // out_attn store moved to bar2 window
        }
      }
      __syncthreads();
      // align = attn @ enc -> albuf slot t (sc1)
      {
        const float* eb = enc + (b*S_)*ENC_ + tid;
        float acc = 0.0f;
        for (int s = 0; s < S_; ++s) acc += attn_s[s]*eb[s*ENC_];
        st_sys(albuf + t*ASLOT + b*ENC_ + tid, acc);
      }
      // signal attn-done (wide release over 16 group lines)
      asm volatile("s_waitcnt vmcnt(0)" ::: "memory");
      __syncthreads();
      if (tid == 0) {
        u32 old = __hip_atomic_fetch_add(attn_cnt, 1u, __ATOMIC_RELAXED, __HIP_MEMORY_SCOPE_AGENT);
        if (old == (u32)t*16u + 15u) {
          #pragma unroll
          for (int g2 = 0; g2 < 16; ++g2) st_sys_u32(bar + g2*1024 + 128, (u32)(t+1));
        }
      }
    } else {
      // (mel/h0 tile pre-staged in previous bar3 window / prologue)
      // ---- GEMV-a
      {
        const int nr = hg0 ? 5 : 4;
        int nrow[5];
        #pragma unroll
        for (int ri = 0; ri < 4; ++ri) nrow[ri] = ri*1024 + j0 + rg;
        nrow[4] = rg*1024 + ((jx0 < 64) ? jx0 : 0);
        #pragma unroll
        for (int hf = 0; hf < 2; ++hf) {
          const int b0 = bgb + hf*4;
          float acc[5][4];
          #pragma unroll
          for (int ri = 0; ri < 5; ++ri)
            #pragma unroll
            for (int bi = 0; bi < 4; ++bi) acc[ri][bi] = 0.0f;
          {
            const int j = ks*4;
            float4 w4[5];
            #pragma unroll
            for (int ri = 0; ri < 5; ++ri)
              if (ri < nr) w4[ri] = bf4(Wih0h + nrow[ri]*768 + j);
            #pragma unroll
            for (int bi = 0; bi < 4; ++bi) {
              const float4 xv = *(const float4*)(xt + (b0+bi)*XST1 + j);
              #pragma unroll
              for (int ri = 0; ri < 5; ++ri)
                if (ri < nr)
                  acc[ri][bi] += w4[ri].x*xv.x + w4[ri].y*xv.y + w4[ri].z*xv.z + w4[ri].w*xv.w;
            }
          }
          #pragma unroll
          for (int q = 0; q < 4; ++q) {
            const int j = q*256 + ks*4;
            float4 w4[5];
            #pragma unroll
            for (int ri = 0; ri < 5; ++ri)
              if (ri < nr) w4[ri] = bf4(Whh0h + nrow[ri]*1024 + j);
            #pragma unroll
            for (int bi = 0; bi < 4; ++bi) {
              const float4 xv = *(const float4*)(xt + (b0+bi)*XST1 + 256 + j);
              #pragma unroll
              for (int ri = 0; ri < 5; ++ri)
                if (ri < nr)
                  acc[ri][bi] += w4[ri].x*xv.x + w4[ri].y*xv.y + w4[ri].z*xv.z + w4[ri].w*xv.w;
            }
          }
          #pragma unroll
          for (int ri = 0; ri < 5; ++ri)
            if (ri < nr)
              #pragma unroll
              for (int bi = 0; bi < 4; ++bi) {
                float v = acc[ri][bi];
                REDUCE64(v);
                if (ks == 63) {
                  v += (ri < 4) ? bsum_s[0][ri*4 + rg] : bsum_s[0][16 + rg];
                  if (ri < 4) gv0[(ri*4 + rg)*16 + (b0+bi)] = v;
                  else        st_sys(g0pre + t*GSLOT + (b0+bi)*256 + jx0*4 + rg, v);
                }
              }
        }
      }
      asm volatile("s_waitcnt vmcnt(0)" ::: "memory");
      __syncthreads();
      // hg0 signal (g0pre slot t globally visible; waited only by attn in P2)
      if (hg0 && tid == 0) {
        u32 old = __hip_atomic_fetch_add(hg0_cnt, 1u, __ATOMIC_RELAXED, __HIP_MEMORY_SCOPE_AGENT);
        if (old == (u32)t*64u + 63u) st_sys_u32(hg0rel, (u32)(t+1));
      }
      // ---- stage h1(t) = slot t
      {
        const float* src = h1buf + t*HSLOT;
        float4 r[8];
        #pragma unroll
        for (int u = 0; u < 8; ++u) r[u] = *(const float4*)(src + (tid + u*512)*4);
        #pragma unroll
        for (int u = 0; u < 8; ++u) {
          const int i = tid + u*512;
          *(float4*)(xt + (i>>8)*XST1 + (i&255)*4) = r[u];
        }
      }
      __syncthreads();
      // ---- GEMV-b
      {
        const int nr = hg1 ? 5 : 4;
        const int nprox = rg*1024 + (hg1 ? jx1 : 0);
        #pragma unroll
        for (int hf = 0; hf < 2; ++hf) {
          const int b0 = bgb + hf*4;
          float acc[5][4];
          #pragma unroll
          for (int ri = 0; ri < 5; ++ri)
            #pragma unroll
            for (int bi = 0; bi < 4; ++bi) acc[ri][bi] = 0.0f;
          #pragma unroll
          for (int q = 0; q < 4; ++q) {
            const int j = q*256 + ks*4;
            float4 w4[5];
            #pragma unroll
            for (int ri = 0; ri < 4; ++ri)
              w4[ri] = bf4(wl + (64 + (ri*4 + rg)*4 + q)*256 + ks*4);
            if (nr == 5) w4[4] = bf4(Whh1h + nprox*1024 + j);
            #pragma unroll
            for (int bi = 0; bi < 4; ++bi) {
              const float4 xv = *(const float4*)(xt + (b0+bi)*XST1 + j);
              #pragma unroll
              for (int ri = 0; ri < 5; ++ri)
                if (ri < nr)
                  acc[ri][bi] += w4[ri].x*xv.x + w4[ri].y*xv.y + w4[ri].z*xv.z + w4[ri].w*xv.w;
            }
          }
          #pragma unroll
          for (int ri = 0; ri < 5; ++ri)
            if (ri < nr)
              #pragma unroll
              for (int bi = 0; bi < 4; ++bi) {
                float v = acc[ri][bi];
                REDUCE64(v);
                if (ks == 63) {
                  v += (ri < 4) ? bsum_s[1][ri*4 + rg] : bsum_s[1][16 + rg];
                  if (ri < 4) gv1[(ri*4 + rg)*16 + (b0+bi)] = v;
                  else        st_sys(g1pre + t*GSLOT + (b0+bi)*256 + jx1*4 + rg, v);
                }
              }
        }
      }
    }
    // ---- wait attn-done (everyone; P2 only needs the 16 attn blocks' albuf)
    if (tid == 0) poll_ge(bar + (blk & 15)*1024 + 128, (u32)(t+1));
    __syncthreads();

    //====================== P2 ======================
    {
      {
        const float* src = albuf + t*ASLOT;
        float4 r[4];
        #pragma unroll
        for (int u = 0; u < 4; ++u) r[u] = *(const float4*)(src + (tid + u*512)*4);
        #pragma unroll
        for (int u = 0; u < 4; ++u) {
          const int i = tid + u*512;
          *(float4*)(xt + (i>>7)*XST2 + (i&127)*4) = r[u];
        }
      }
      __syncthreads();
      float acc[4][8];
      #pragma unroll
      for (int ri = 0; ri < 4; ++ri)
        #pragma unroll
        for (int bi = 0; bi < 8; ++bi) acc[ri][bi] = 0.0f;
      #pragma unroll
      for (int q = 0; q < 2; ++q) {
        const int j = q*256 + ks*4;
        float4 w4[4];
        #pragma unroll
        for (int ri = 0; ri < 4; ++ri)
          w4[ri] = bf4(Wih0h + (ri*1024 + j0 + rg)*768 + 256 + j);
        #pragma unroll
        for (int bi = 0; bi < 8; ++bi) {
          const float4 xv = *(const float4*)(xt + (bgb+bi)*XST2 + j);
          #pragma unroll
          for (int ri = 0; ri < 4; ++ri)
            acc[ri][bi] += w4[ri].x*xv.x + w4[ri].y*xv.y + w4[ri].z*xv.z + w4[ri].w*xv.w;
        }
      }
      #pragma unroll
      for (int ri = 0; ri < 4; ++ri)
        #pragma unroll
        for (int bi = 0; bi < 8; ++bi) {
          float v = acc[ri][bi];
          REDUCE64(v);
          if (ks == 63) gv[(rg*4 + ri)*16 + (bgb+bi)] = v;
        }
      // attn blocks: ensure g0pre slot t is complete before assembly
      if (blk < B_ && tid == 0) poll_ge(hg0rel, (u32)(t+1));
      __syncthreads();
      if (tid < 64) {
        const int jl = tid >> 4, bb = tid & 15;
        const int j = j0 + jl;
        float pi, pf, pg, po;
        if (blk < B_) {
          const float4 g4 = *(const float4*)(g0pre + t*GSLOT + bb*256 + j*4);
          pi = g4.x; pf = g4.y; pg = g4.z; po = g4.w;
        } else {
          pi = gv0[(0*4 + jl)*16 + bb];
          pf = gv0[(1*4 + jl)*16 + bb];
          pg = gv0[(2*4 + jl)*16 + bb];
          po = gv0[(3*4 + jl)*16 + bb];
        }
        const float gi = gv[(jl*4+0)*16 + bb] + pi;
        const float gf = gv[(jl*4+1)*16 + bb] + pf;
        const float gg = gv[(jl*4+2)*16 + bb] + pg;
        const float go = gv[(jl*4+3)*16 + bb] + po;
        const float cn = fsigf(gf)*c0r + fsigf(gi)*ftanhf(gg);
        const float hn = fsigf(go)*ftanhf(cn);
        c0r = cn;
        st_sys(h0st + (t+1)*HSLOT + bb*DIM_ + j, hn);
      }
    }
    gb_arrive(bar, tid, blk, ep);
    // ---- bar2 window: attn blocks do proj(t-1) + out_attn(t)
    if (blk < B_) {
      const int b = blk;
      if (tid < S_) out_attn[(b*S_ + tid)*T_ + t] = attn_s[tid];
      if (t > 0) {
        const int o = tid >> 2, part = tid & 3;
        if (o < 81) {
          const float* w = projW + o*1536;
          const int jb = part*384;
          float acc2 = 0.0f;
          for (int j = jb; j < jb + 384; j += 4) {
            const float4 wv = *(const float4*)(w + j);
            const float4 xv = *(const float4*)(projx + j);
            acc2 += wv.x*xv.x + wv.y*xv.y + wv.z*xv.z + wv.w*xv.w;
          }
          spf[o*4 + part] = acc2;
        }
        __syncthreads();
        if (tid < 81) {
          const float v = projb[tid] + spf[tid*4] + spf[tid*4+1] + spf[tid*4+2] + spf[tid*4+3];
          if (tid < 80) out_mel[(b*NMEL_ + tid)*T_ + (t-1)] = v;
          else          out_stop[b*T_ + (t-1)] = v;
        }
      }
    }
    gb_wait(bar, tid, blk, ep); ++ep;

    //====================== P3 ======================
    {
      {
        const float* src = h0st + (t+1)*HSLOT;
        float4 r[8];
        #pragma unroll
        for (int u = 0; u < 8; ++u) r[u] = *(const float4*)(src + (tid + u*512)*4);
        #pragma unroll
        for (int u = 0; u < 8; ++u) {
          const int i = tid + u*512;
          *(float4*)(xt + (i>>8)*XST3 + (i&255)*4) = r[u];
        }
      }
      __syncthreads();
      float acc[4][8];
      #pragma unroll
      for (int ri = 0; ri < 4; ++ri)
        #pragma unroll
        for (int bi = 0; bi < 8; ++bi) acc[ri][bi] = 0.0f;
      #pragma unroll
      for (int q = 0; q < 4; ++q) {
        const int j = q*256 + ks*4;
        float4 w4[4];
        if (blk < B_) {
          #pragma unroll
          for (int ri = 0; ri < 4; ++ri)
            w4[ri] = bf4(Wih1h + (ri*1024 + j0 + rg)*1024 + j);
        } else {
          #pragma unroll
          for (int ri = 0; ri < 4; ++ri)
            w4[ri] = bf4(wl + (((ri*4 + rg)*4 + q) << 8) + ks*4);
        }
        #pragma unroll
        for (int bi = 0; bi < 8; ++bi) {
          const float4 xv = *(const float4*)(xt + (bgb+bi)*XST3 + j);
          #pragma unroll
          for (int ri = 0; ri < 4; ++ri)
            acc[ri][bi] += w4[ri].x*xv.x + w4[ri].y*xv.y + w4[ri].z*xv.z + w4[ri].w*xv.w;
        }
      }
      #pragma unroll
      for (int ri = 0; ri < 4; ++ri)
        #pragma unroll
        for (int bi = 0; bi < 8; ++bi) {
          float v = acc[ri][bi];
          REDUCE64(v);
          if (ks == 63) gv[(rg*4 + ri)*16 + (bgb+bi)] = v;
        }
      __syncthreads();
      if (tid < 64) {
        const int jl = tid >> 4, bb = tid & 15;
        const int j = j0 + jl;
        float pi, pf, pg, po;
        if (blk < B_) {
          const float4 g4 = *(const float4*)(g1pre + t*GSLOT + bb*256 + j*4);
          pi = g4.x; pf = g4.y; pg = g4.z; po = g4.w;
        } else {
          pi = gv1[(0*4 + jl)*16 + bb];
          pf = gv1[(1*4 + jl)*16 + bb];
          pg = gv1[(2*4 + jl)*16 + bb];
          po = gv1[(3*4 + jl)*16 + bb];
        }
        const float gi = gv[(jl*4+0)*16 + bb] + pi;
        const float gf = gv[(jl*4+1)*16 + bb] + pf;
        const float gg = gv[(jl*4+2)*16 + bb] + pg;
        const float go = gv[(jl*4+3)*16 + bb] + po;
        const float cn = fsigf(gf)*c1r + fsigf(gi)*ftanhf(gg);
        const float hn = fsigf(go)*ftanhf(cn);
        c1r = cn;
        st_sys(h1buf + (t+1)*HSLOT + bb*DIM_ + j, hn);
      }
    }
    gb_arrive(bar, tid, blk, ep);
    // ---- bar3 window: pre-stage step t+1 inputs that bar2(t) already ordered
    if (t + 1 < T_) {
      if (blk >= B_) {
        for (int i = tid; i < 1024; i += 512) {
          float4 v = *(const float4*)(melpre + (t+1)*4096 + i*4);
          *(float4*)(xt + (i>>6)*XST1 + (i&63)*4) = v;
        }
        const float* src = h0st + (t+1)*HSLOT;   // h0(t), written P2(t)
        float4 r[8];
        #pragma unroll
        for (int u = 0; u < 8; ++u) r[u] = *(const float4*)(src + (tid + u*512)*4);
        #pragma unroll
        for (int u = 0; u < 8; ++u) {
          const int i = tid + u*512;
          *(float4*)(xt + (i>>8)*XST1 + 256 + (i&255)*4) = r[u];
        }
      } else {
        // align(t) -> projx[1024..1536) for proj(t) in bar2(t+1) window (own data)
        if (tid < 128) {
          *(float4*)(projx + 1024 + tid*4) =
              *(const float4*)(albuf + t*ASLOT + blk*ENC_ + tid*4);
        }
      }
    }
    gb_wait(bar, tid, blk, ep); ++ep;
  }

  // ---- tail projection for t = T_-1 (h1 slot 300, align slot 299)
  if (blk < B_) {
    const int b = blk;
    if (tid < 256) {
      *(float4*)(projx + tid*4) =
          *(const float4*)(h1buf + 300*HSLOT + b*DIM_ + tid*4);
    } else if (tid < 384) {
      const int j = tid - 256;
      *(float4*)(projx + 1024 + j*4) =
          *(const float4*)(albuf + 299*ASLOT + b*ENC_ + j*4);
    }
    __syncthreads();
    const int o = tid >> 2, part = tid & 3;
    if (o < 81) {
      const float* w = projW + o*1536;
      const int jb = part*384;
      float acc = 0.0f;
      for (int j = jb; j < jb + 384; j += 4) {
        const float4 wv = *(const float4*)(w + j);
        const float4 xv = *(const float4*)(projx + j);
        acc += wv.x*xv.x + wv.y*xv.y + wv.z*xv.z + wv.w*xv.w;
      }
      spf[o*4 + part] = acc;
    }
    __syncthreads();
    if (tid < 81) {
      const float v = projb[tid] + spf[tid*4] + spf[tid*4+1] + spf[tid*4+2] + spf[tid*4+3];
      if (tid < 80) out_mel[(b*NMEL_ + tid)*T_ + (T_-1)] = v;
      else          out_stop[b*T_ + (T_-1)] = v;
    }
  }
}

extern "C" void kernel_launch(void* const* d_in, const int* in_sizes, int n_in,
                              void* d_out, int out_size, void* d_ws, size_t ws_size,
                              hipStream_t stream) {
  const float* mels  = (const float*)d_in[0];
  const float* enc   = (const float*)d_in[1];
  const int*   tlen  = (const int*)d_in[2];
  const float* Wt    = (const float*)d_in[3];
  const float* Wq    = (const float*)d_in[4];
  const float* wsc   = (const float*)d_in[5];
  const float* conv1 = (const float*)d_in[6];
  const float* conv2 = (const float*)d_in[7];
  const float* pW1   = (const float*)d_in[8];
  const float* pb1   = (const float*)d_in[9];
  const float* pW2   = (const float*)d_in[10];
  const float* pb2   = (const float*)d_in[11];
  const float* Wih0  = (const float*)d_in[12];
  const float* Whh0  = (const float*)d_in[13];
  const float* bih0  = (const float*)d_in[14];
  const float* bhh0  = (const float*)d_in[15];
  const float* Wih1  = (const float*)d_in[16];
  const float* Whh1  = (const float*)d_in[17];
  const float* bih1  = (const float*)d_in[18];
  const float* bhh1  = (const float*)d_in[19];
  const float* h0    = (const float*)d_in[20];
  const float* c0    = (const float*)d_in[21];
  const float* projW = (const float*)d_in[22];
  const float* projb = (const float*)d_in[23];

  float* ws     = (float*)d_ws;
  float* melpre = ws;                   // 1,228,800
  float* lencb  = melpre + 1228800;     //   327,680
  float* weff   = lencb + 327680;       //     4,096
  float* h1buf  = weff + 4096;          // 301*16384
  float* albuf  = h1buf + 301*16384;    // 300*8192
  float* h0st   = albuf + 300*8192;     // 301*16384
  float* g0pre  = h0st + 301*16384;     // 300*4096
  float* g1pre  = g0pre + 300*4096;     // 300*4096
  u32*   bar    = (u32*)(g1pre + 300*4096); // 17,408 words
  u16*   Wih0h  = (u16*)(bar + BARWORDS);
  u16*   Whh0h  = Wih0h + 4096*768;
  u16*   Wih1h  = Whh0h + 4096*1024;
  u16*   Whh1h  = Wih1h + 4096*1024;
  u16*   Wqh    = Whh1h + 4096*1024;

  float* out_mel  = (float*)d_out;
  float* out_stop = out_mel + 384000;
  float* out_attn = out_stop + 4800;

  prenet_kernel<<<dim3(480), dim3(256), 0, stream>>>(mels, pW1, pb1, pW2, pb2, melpre);
  init_kernel<<<dim3(160), dim3(256), 0, stream>>>(h0, conv1, conv2, h1buf, h0st, weff, bar);
  wcvt_kernel<<<dim3(2048), dim3(256), 0, stream>>>(Wih0, Whh0, Wih1, Whh1, Wq,
                                                    Wih0h, Whh0h, Wih1h, Whh1h, Wqh);
  lenc_kernel<<<dim3(640), dim3(256), 0, stream>>>(enc, Wt, lencb);

  void* args[] = {
    (void*)&melpre, (void*)&lencb, (void*)&weff, (void*)&h1buf, (void*)&albuf, (void*)&h0st,
    (void*)&g0pre, (void*)&g1pre, (void*)&bar,
    (void*)&enc, (void*)&tlen, (void*)&Wqh, (void*)&wsc,
    (void*)&Wih0h, (void*)&Whh0h, (void*)&Wih1h, (void*)&Whh1h,
    (void*)&bih0, (void*)&bhh0, (void*)&bih1, (void*)&bhh1,
    (void*)&c0, (void*)&projW, (void*)&projb,
    (void*)&out_mel, (void*)&out_stop, (void*)&out_attn
  };
  hipLaunchCooperativeKernel((const void*)decoder_kernel, dim3(256), dim3(512),
                             args, (unsigned int)(XTOT*sizeof(float)), stream);
}